// Round 9
// baseline (524.938 us; speedup 1.0000x reference)
//
#include <hip/hip_runtime.h>
#include <hip/hip_bf16.h>
#include <math.h>

#define BSHIFT 3   // bucket = 8 consecutive destination nodes

// Fast device transcendentals: native v_exp_f32 + v_rcp_f32.
// sigmoid(x) = 1 - 1/(1+e^x)   (safe for x -> +/-inf: rcp(inf)=0)
// tanh(x)    = 1 - 2/(1+e^2x)  (safe both ends)
__device__ __forceinline__ float fast_sigmoid(float x) {
    float t = __expf(x);
    return 1.0f - __builtin_amdgcn_rcpf(1.0f + t);
}
__device__ __forceinline__ float fast_tanh(float x) {
    float t = __expf(2.0f * x);
    return 1.0f - 2.0f * __builtin_amdgcn_rcpf(1.0f + t);
}

// ---------------------------------------------------------------------------
// Degree histogram over col (destination) indices. deg must be zeroed first.
// ---------------------------------------------------------------------------
__global__ void k_deg(const int* __restrict__ col, int* __restrict__ deg, int E) {
    int e = blockIdx.x * 256 + threadIdx.x;
    if (e < E) atomicAdd(&deg[col[e]], 1);
}

// dinv[n] = 1/sqrt(deg[n] + 1)   (+1 for the self loop; always > 0)
__global__ void k_dinv(const int* __restrict__ deg, float* __restrict__ dinv, int n) {
    int i = blockIdx.x * 256 + threadIdx.x;
    if (i < n) dinv[i] = 1.0f / sqrtf((float)(deg[i] + 1));
}

// ---------------------------------------------------------------------------
// Hierarchical exclusive scan of deg -> off (CSR row offsets).
// ---------------------------------------------------------------------------
__global__ __launch_bounds__(256) void k_scan1(const int* __restrict__ deg,
        int* __restrict__ off, int* __restrict__ bsum, int n) {
    __shared__ int tmp[256];
    int tid = threadIdx.x;
    int i = blockIdx.x * 256 + tid;
    int v = (i < n) ? deg[i] : 0;
    tmp[tid] = v;
    __syncthreads();
#pragma unroll
    for (int s = 1; s < 256; s <<= 1) {
        int t = (tid >= s) ? tmp[tid - s] : 0;
        __syncthreads();
        tmp[tid] += t;
        __syncthreads();
    }
    if (i < n) off[i] = tmp[tid] - v;             // block-local exclusive
    if (tid == 255) bsum[blockIdx.x] = tmp[255];  // block total
}

__global__ __launch_bounds__(1024) void k_scan2(const int* __restrict__ bsum,
        int* __restrict__ bscan, int nb) {
    __shared__ int tmp[1024];
    int tid = threadIdx.x;
    int v = (tid < nb) ? bsum[tid] : 0;
    tmp[tid] = v;
    __syncthreads();
#pragma unroll
    for (int s = 1; s < 1024; s <<= 1) {
        int t = (tid >= s) ? tmp[tid - s] : 0;
        __syncthreads();
        tmp[tid] += t;
        __syncthreads();
    }
    if (tid < nb) bscan[tid] = tmp[tid] - v;
}

__global__ __launch_bounds__(256) void k_scan3(int* __restrict__ off,
        const int* __restrict__ bscan, const int* __restrict__ deg,
        int* __restrict__ cur, int n) {
    int i = blockIdx.x * 256 + threadIdx.x;
    if (i >= n) return;
    int o = off[i] + bscan[blockIdx.x];
    off[i] = o;
    cur[i] = o;
    if (i == n - 1) off[n] = o + deg[i];
}

// Bucket cursors: bucket b covers cols [b<<BSHIFT, (b+1)<<BSHIFT); its region
// in the bucket-grouped edge array is [off[b<<BSHIFT], ...) -- free from CSR off.
__global__ void k_bcur(const int* __restrict__ off, int* __restrict__ bcur, int nbuk) {
    int b = blockIdx.x * 256 + threadIdx.x;
    if (b < nbuk) bcur[b] = off[b << BSHIFT];
}

// ---------------------------------------------------------------------------
// Pass B: partition edges into destination buckets (8 nodes each).
// Cursor-adjacent slots are claimed at temporally-close instants, so each 64B
// ebuf line fills fast and writes back ONCE (k_fill's 16x write-amp killer).
// ---------------------------------------------------------------------------
__global__ void k_part(const int* __restrict__ row, const int* __restrict__ col,
                       int* __restrict__ bcur, int2* __restrict__ ebuf, int E) {
    int e = blockIdx.x * 256 + threadIdx.x;
    if (e < E) {
        int c = col[e];
        int p = atomicAdd(&bcur[c >> BSHIFT], 1);
        ebuf[p] = make_int2(row[e], c);
    }
}

// ---------------------------------------------------------------------------
// Pass C: final CSR fill from bucket-grouped edges. Each node's nbr slots are
// written within one block's lifetime (512B window per bucket) -> no re-evict.
// ---------------------------------------------------------------------------
__global__ void k_fill2(const int2* __restrict__ ebuf, int* __restrict__ cur,
                        int* __restrict__ nbr, int E) {
    int e = blockIdx.x * 256 + threadIdx.x;
    if (e < E) {
        int2 rc = ebuf[e];
        int p = atomicAdd(&cur[rc.y], 1);
        nbr[p] = rc.x;
    }
}

// ---------------------------------------------------------------------------
// One-time weight transpose for coalesced phase-1 loads:
//   WT[k*192 + g*64 + j] = Wih[row(g,j)*64 + k],  g: 0->i (row j),
//   1->g (row 128+j), 2->o (row 192+j).  f-gate rows are dead (c0=0).
// ---------------------------------------------------------------------------
__global__ void k_tr(const float* __restrict__ Wih, float* __restrict__ WT) {
    int t = blockIdx.x * 256 + threadIdx.x;
    if (t >= 64 * 192) return;
    int k = t / 192, c = t % 192;
    int g = c >> 6, j = c & 63;
    int rowb = (g == 0) ? j : (g == 1) ? (128 + j) : (192 + j);
    WT[t] = Wih[rowb * 64 + k];
}

// ---------------------------------------------------------------------------
// Fused LSTM step + (h @ W1), GEMV-broadcast form.
// Wave owns 8 nodes; lane = output column.
// ---------------------------------------------------------------------------
__global__ __launch_bounds__(256) void k_lstm_mm1(
    const float* __restrict__ x, const float* __restrict__ WT,
    const float* __restrict__ bih, const float* __restrict__ bhh,
    const float* __restrict__ W1, float* __restrict__ hw1, int n)
{
    __shared__ float4 xs[4][128];          // per-wave 2KB: [k][8 nodes] as 2xfloat4
    int wv   = threadIdx.x >> 6;
    int lane = threadIdx.x & 63;
    int nbase = (blockIdx.x * 4 + wv) * 8;
    if (nbase >= n) return;                // wave-uniform

    int ni[8];
#pragma unroll
    for (int m = 0; m < 8; m++) {
        int t = nbase + m;
        ni[m] = (t < n) ? t : (n - 1);     // clamp for safe loads
    }

    // stage x rows (coalesced global reads, per-wave LDS region)
    float xv[8];
#pragma unroll
    for (int m = 0; m < 8; m++) xv[m] = x[(size_t)ni[m] * 64 + lane];
    xs[wv][lane * 2 + 0] = make_float4(xv[0], xv[1], xv[2], xv[3]);
    xs[wv][lane * 2 + 1] = make_float4(xv[4], xv[5], xv[6], xv[7]);

    float gi[8], gg[8], go[8];
#pragma unroll
    for (int m = 0; m < 8; m++) { gi[m] = 0.f; gg[m] = 0.f; go[m] = 0.f; }

#pragma unroll 8
    for (int k = 0; k < 64; k++) {
        float4 xa = xs[wv][k * 2 + 0];     // broadcast
        float4 xb = xs[wv][k * 2 + 1];
        float wi = WT[k * 192 + lane];     // coalesced 256B
        float wg = WT[k * 192 + 64 + lane];
        float wo = WT[k * 192 + 128 + lane];
        gi[0] = fmaf(xa.x, wi, gi[0]); gi[1] = fmaf(xa.y, wi, gi[1]);
        gi[2] = fmaf(xa.z, wi, gi[2]); gi[3] = fmaf(xa.w, wi, gi[3]);
        gi[4] = fmaf(xb.x, wi, gi[4]); gi[5] = fmaf(xb.y, wi, gi[5]);
        gi[6] = fmaf(xb.z, wi, gi[6]); gi[7] = fmaf(xb.w, wi, gi[7]);
        gg[0] = fmaf(xa.x, wg, gg[0]); gg[1] = fmaf(xa.y, wg, gg[1]);
        gg[2] = fmaf(xa.z, wg, gg[2]); gg[3] = fmaf(xa.w, wg, gg[3]);
        gg[4] = fmaf(xb.x, wg, gg[4]); gg[5] = fmaf(xb.y, wg, gg[5]);
        gg[6] = fmaf(xb.z, wg, gg[6]); gg[7] = fmaf(xb.w, wg, gg[7]);
        go[0] = fmaf(xa.x, wo, go[0]); go[1] = fmaf(xa.y, wo, go[1]);
        go[2] = fmaf(xa.z, wo, go[2]); go[3] = fmaf(xa.w, wo, go[3]);
        go[4] = fmaf(xb.x, wo, go[4]); go[5] = fmaf(xb.y, wo, go[5]);
        go[6] = fmaf(xb.z, wo, go[6]); go[7] = fmaf(xb.w, wo, go[7]);
    }

    float bi = bih[lane]       + bhh[lane];
    float bg = bih[128 + lane] + bhh[128 + lane];
    float bo = bih[192 + lane] + bhh[192 + lane];

    float h[8];
#pragma unroll
    for (int m = 0; m < 8; m++) {
        float c = fast_sigmoid(gi[m] + bi) * fast_tanh(gg[m] + bg);
        h[m] = fast_sigmoid(go[m] + bo) * fast_tanh(c);
    }

    // reuse the same per-wave LDS region for h (same-wave DS order is safe)
    xs[wv][lane * 2 + 0] = make_float4(h[0], h[1], h[2], h[3]);
    xs[wv][lane * 2 + 1] = make_float4(h[4], h[5], h[6], h[7]);

    float acc[8];
#pragma unroll
    for (int m = 0; m < 8; m++) acc[m] = 0.f;

#pragma unroll 8
    for (int j = 0; j < 64; j++) {
        float4 ha = xs[wv][j * 2 + 0];     // broadcast
        float4 hb = xs[wv][j * 2 + 1];
        float w = W1[j * 64 + lane];       // coalesced 256B
        acc[0] = fmaf(ha.x, w, acc[0]); acc[1] = fmaf(ha.y, w, acc[1]);
        acc[2] = fmaf(ha.z, w, acc[2]); acc[3] = fmaf(ha.w, w, acc[3]);
        acc[4] = fmaf(hb.x, w, acc[4]); acc[5] = fmaf(hb.y, w, acc[5]);
        acc[6] = fmaf(hb.z, w, acc[6]); acc[7] = fmaf(hb.w, w, acc[7]);
    }

#pragma unroll
    for (int m = 0; m < 8; m++)
        if (nbase + m < n)
            hw1[(size_t)(nbase + m) * 64 + lane] = acc[m];
}

// ---------------------------------------------------------------------------
// Pull aggregation, F=64. One wave per node, lane = feature.
// Fused epilogue 1: h1 = relu(agg*dc + hw1[node]*dc^2 + b1)
// ---------------------------------------------------------------------------
__global__ __launch_bounds__(256) void k_pull64(
    const float* __restrict__ hw, const int* __restrict__ off,
    const int* __restrict__ nbr, const float* __restrict__ dinv,
    const float* __restrict__ b1, float* __restrict__ h1, int n)
{
    int node = (blockIdx.x * 256 + threadIdx.x) >> 6;
    int lane = threadIdx.x & 63;
    if (node >= n) return;
    int s = off[node], e = off[node + 1];
    float a0 = 0.0f, a1 = 0.0f;
    int j = s;
    for (; j + 2 <= e; j += 2) {           // 2 neighbors in flight
        int r0 = nbr[j], r1 = nbr[j + 1];
        float w0 = dinv[r0], w1 = dinv[r1];
        a0 = fmaf(hw[(size_t)r0 * 64 + lane], w0, a0);
        a1 = fmaf(hw[(size_t)r1 * 64 + lane], w1, a1);
    }
    if (j < e) {
        int r0 = nbr[j];
        a0 = fmaf(hw[(size_t)r0 * 64 + lane], dinv[r0], a0);
    }
    float dc   = dinv[node];
    float self = hw[(size_t)node * 64 + lane];
    float v = (a0 + a1) * dc + self * dc * dc + b1[lane];
    h1[(size_t)node * 64 + lane] = fmaxf(v, 0.0f);
}

// ---------------------------------------------------------------------------
// Pull aggregation, F=32. One wave per node; lanes 0-31 even neighbors,
// lanes 32-63 odd neighbors; halves combined via shfl_xor 32.
// Fused epilogue 2: z = agg*dc + hw2[node]*dc^2 + b2  (no relu)
// ---------------------------------------------------------------------------
__global__ __launch_bounds__(256) void k_pull32(
    const float* __restrict__ hw, const int* __restrict__ off,
    const int* __restrict__ nbr, const float* __restrict__ dinv,
    const float* __restrict__ b2, float* __restrict__ z, int n)
{
    int node = (blockIdx.x * 256 + threadIdx.x) >> 6;
    int lane = threadIdx.x & 63;
    int feat = lane & 31;
    int half = lane >> 5;
    if (node >= n) return;
    int s = off[node], e = off[node + 1];
    float acc = 0.0f;
    for (int j = s + half; j < e; j += 2) {
        int r = nbr[j];
        acc = fmaf(hw[(size_t)r * 32 + feat], dinv[r], acc);
    }
    acc += __shfl_xor(acc, 32, 64);        // combine even/odd halves
    float dc = dinv[node];
    float v = acc * dc + hw[(size_t)node * 32 + feat] * dc * dc + b2[feat];
    if (half == 0) z[(size_t)node * 32 + feat] = v;
}

// ---------------------------------------------------------------------------
// hw2 = h1 @ W2  ([n,64] x [64,32]). Block = 128 nodes, h1 tile in LDS (pad 65).
// ---------------------------------------------------------------------------
__global__ __launch_bounds__(128) void k_mm2(
    const float* __restrict__ h1, const float* __restrict__ W2,
    float* __restrict__ hw2, int n)
{
    __shared__ float tile[128 * 65];
    int base  = blockIdx.x * 128;
    int nrows = n - base; if (nrows > 128) nrows = 128;

    for (int idx = threadIdx.x; idx < nrows * 64; idx += 128) {
        int r = idx >> 6, c = idx & 63;
        tile[r * 65 + c] = h1[(size_t)base * 64 + idx];
    }
    __syncthreads();

    int node = base + threadIdx.x;
    if (node >= n) return;

    const float* hrow = &tile[threadIdx.x * 65];
    float acc[32];
#pragma unroll
    for (int s = 0; s < 32; s++) acc[s] = 0.0f;

    for (int k = 0; k < 64; k++) {
        float hk = hrow[k];
        const float* w = W2 + (size_t)k * 32;
#pragma unroll
        for (int s = 0; s < 32; s++) acc[s] = fmaf(hk, w[s], acc[s]);
    }

    float4* op = reinterpret_cast<float4*>(hw2 + (size_t)node * 32);
#pragma unroll
    for (int q = 0; q < 8; q++)
        op[q] = make_float4(acc[4*q], acc[4*q+1], acc[4*q+2], acc[4*q+3]);
}

// ---------------------------------------------------------------------------
// out[e] = dot(z[src[e]], z[dst[e]]) over 32 features
// ---------------------------------------------------------------------------
__global__ void k_dot(const float* __restrict__ z, const int* __restrict__ src,
                      const int* __restrict__ dst, float* __restrict__ out, int EL)
{
    int e = blockIdx.x * 256 + threadIdx.x;
    if (e >= EL) return;
    const float4* a = reinterpret_cast<const float4*>(z + (size_t)src[e] * 32);
    const float4* b = reinterpret_cast<const float4*>(z + (size_t)dst[e] * 32);
    float s = 0.0f;
#pragma unroll
    for (int q = 0; q < 8; q++) {
        float4 av = a[q], bv = b[q];
        s = fmaf(av.x, bv.x, s);
        s = fmaf(av.y, bv.y, s);
        s = fmaf(av.z, bv.z, s);
        s = fmaf(av.w, bv.w, s);
    }
    out[e] = s;
}

extern "C" void kernel_launch(void* const* d_in, const int* in_sizes, int n_in,
                              void* d_out, int out_size, void* d_ws, size_t ws_size,
                              hipStream_t stream)
{
    const float* x   = (const float*)d_in[0];
    const int*   ei  = (const int*)d_in[1];
    const int*   eli = (const int*)d_in[2];
    const float* Wih = (const float*)d_in[3];
    // d_in[4] = W_hh: mathematically dead (h0 = c0 = 0)
    const float* bih = (const float*)d_in[5];
    const float* bhh = (const float*)d_in[6];
    const float* W1  = (const float*)d_in[7];
    const float* b1  = (const float*)d_in[8];
    const float* W2  = (const float*)d_in[9];
    const float* b2  = (const float*)d_in[10];

    int n  = in_sizes[0] / 64;
    int E  = in_sizes[1] / 2;
    int EL = in_sizes[2] / 2;

    const int* row  = ei;          // source
    const int* col  = ei + E;      // destination
    const int* lsrc = eli;
    const int* ldst = eli + EL;
    float* out = (float*)d_out;

    // Workspace layout (4B units), liveness-aliased:
    //   bufA [n*64]: ebuf (part..fill2, as int2), hw1 (lstm..pull64),
    //                then hw2 in first n*32 (mm2..pull32)
    //   bufB [n*64]: h1 (pull64..mm2), then z in first n*32 (pull32..dot)
    //   dinv [n] | off [n+1] | deg [n] | cur [n] | bsum [1024] | bscan [1024]
    //   nbr [E] | WT [64*192] | bcur [nbuk]   (~59.4 MB total)
    float* bufA  = (float*)d_ws;
    float* bufB  = bufA + (size_t)n * 64;
    float* dinv  = bufB + (size_t)n * 64;
    int*   off   = (int*)(dinv + n);
    int*   deg   = off + (n + 1);
    int*   cur   = deg + n;
    int*   bsum  = cur + n;
    int*   bscan = bsum + 1024;
    int*   nbr   = bscan + 1024;
    float* WT    = (float*)(nbr + E);
    int*   bcur  = (int*)(WT + 64 * 192);
    int2*  ebuf  = (int2*)bufA;    // dead until k_lstm_mm1 writes hw1

    int nb   = (n + 255) / 256;    // 391 for n=100000; k_scan2 handles nb<=1024
    int nbuk = (n + (1 << BSHIFT) - 1) >> BSHIFT;   // 12500 buckets
    dim3 blk(256);

    // --- weight transpose for LSTM phase-1 (tiny, one-time per call) ---
    k_tr<<<dim3((64 * 192 + 255) / 256), blk, 0, stream>>>(Wih, WT);

    // --- CSR build: counting sort by destination, bucket-staged fill ---
    hipMemsetAsync(deg, 0, (size_t)n * sizeof(int), stream);
    k_deg  <<<dim3((E + 255) / 256), blk, 0, stream>>>(col, deg, E);
    k_dinv <<<dim3(nb), blk, 0, stream>>>(deg, dinv, n);
    k_scan1<<<dim3(nb), blk, 0, stream>>>(deg, off, bsum, n);
    k_scan2<<<dim3(1), dim3(1024), 0, stream>>>(bsum, bscan, nb);
    k_scan3<<<dim3(nb), blk, 0, stream>>>(off, bscan, deg, cur, n);
    k_bcur <<<dim3((nbuk + 255) / 256), blk, 0, stream>>>(off, bcur, nbuk);
    k_part <<<dim3((E + 255) / 256), blk, 0, stream>>>(row, col, bcur, ebuf, E);
    k_fill2<<<dim3((E + 255) / 256), blk, 0, stream>>>(ebuf, cur, nbr, E);

    // --- LSTM + first matmul: hw1 -> bufA (8 nodes/wave, 32 nodes/block) ---
    {
        int blocks = (n + 31) / 32;
        k_lstm_mm1<<<dim3(blocks), blk, 0, stream>>>(x, WT, bih, bhh, W1, bufA, n);
    }

    // --- GCN1: pull + fused epilogue (relu) : h1 -> bufB ---
    {
        int blocks = (int)(((size_t)n * 64 + 255) / 256);
        k_pull64<<<dim3(blocks), blk, 0, stream>>>(bufA, off, nbr, dinv, b1, bufB, n);
    }

    // --- second matmul: hw2 -> bufA (hw1 dead) ---
    k_mm2<<<dim3((n + 127) / 128), dim3(128), 0, stream>>>(bufB, W2, bufA, n);

    // --- GCN2: pull + fused epilogue : z -> bufB (h1 dead) ---
    {
        int blocks = (int)(((size_t)n * 64 + 255) / 256);
        k_pull32<<<dim3(blocks), blk, 0, stream>>>(bufA, off, nbr, dinv, b2, bufB, n);
    }

    // --- edge dot products ---
    k_dot<<<dim3((EL + 255) / 256), blk, 0, stream>>>(bufB, lsrc, ldst, out, EL);
}

// Round 10
// 390.710 us; speedup vs baseline: 1.3435x; 1.3435x over previous
//
#include <hip/hip_runtime.h>
#include <hip/hip_bf16.h>
#include <math.h>

// Fast device transcendentals: native v_exp_f32 + v_rcp_f32.
// sigmoid(x) = 1 - 1/(1+e^x)   (safe for x -> +/-inf: rcp(inf)=0)
// tanh(x)    = 1 - 2/(1+e^2x)  (safe both ends)
__device__ __forceinline__ float fast_sigmoid(float x) {
    float t = __expf(x);
    return 1.0f - __builtin_amdgcn_rcpf(1.0f + t);
}
__device__ __forceinline__ float fast_tanh(float x) {
    float t = __expf(2.0f * x);
    return 1.0f - 2.0f * __builtin_amdgcn_rcpf(1.0f + t);
}

__device__ __forceinline__ float readlane_f(float v, int l) {
    return __builtin_bit_cast(float,
        __builtin_amdgcn_readlane(__builtin_bit_cast(int, v), l));
}

// ---------------------------------------------------------------------------
// Degree histogram over col (destination) indices. deg must be zeroed first.
// ---------------------------------------------------------------------------
__global__ void k_deg(const int* __restrict__ col, int* __restrict__ deg, int E) {
    int e = blockIdx.x * 256 + threadIdx.x;
    if (e < E) atomicAdd(&deg[col[e]], 1);
}

// dinv[n] = 1/sqrt(deg[n] + 1)   (+1 for the self loop; always > 0)
__global__ void k_dinv(const int* __restrict__ deg, float* __restrict__ dinv, int n) {
    int i = blockIdx.x * 256 + threadIdx.x;
    if (i < n) dinv[i] = 1.0f / sqrtf((float)(deg[i] + 1));
}

// ---------------------------------------------------------------------------
// Hierarchical exclusive scan of deg -> off (CSR row offsets).
// ---------------------------------------------------------------------------
__global__ __launch_bounds__(256) void k_scan1(const int* __restrict__ deg,
        int* __restrict__ off, int* __restrict__ bsum, int n) {
    __shared__ int tmp[256];
    int tid = threadIdx.x;
    int i = blockIdx.x * 256 + tid;
    int v = (i < n) ? deg[i] : 0;
    tmp[tid] = v;
    __syncthreads();
#pragma unroll
    for (int s = 1; s < 256; s <<= 1) {
        int t = (tid >= s) ? tmp[tid - s] : 0;
        __syncthreads();
        tmp[tid] += t;
        __syncthreads();
    }
    if (i < n) off[i] = tmp[tid] - v;             // block-local exclusive
    if (tid == 255) bsum[blockIdx.x] = tmp[255];  // block total
}

__global__ __launch_bounds__(1024) void k_scan2(const int* __restrict__ bsum,
        int* __restrict__ bscan, int nb) {
    __shared__ int tmp[1024];
    int tid = threadIdx.x;
    int v = (tid < nb) ? bsum[tid] : 0;
    tmp[tid] = v;
    __syncthreads();
#pragma unroll
    for (int s = 1; s < 1024; s <<= 1) {
        int t = (tid >= s) ? tmp[tid - s] : 0;
        __syncthreads();
        tmp[tid] += t;
        __syncthreads();
    }
    if (tid < nb) bscan[tid] = tmp[tid] - v;
}

__global__ __launch_bounds__(256) void k_scan3(int* __restrict__ off,
        const int* __restrict__ bscan, const int* __restrict__ deg,
        int* __restrict__ cur, int n) {
    int i = blockIdx.x * 256 + threadIdx.x;
    if (i >= n) return;
    int o = off[i] + bscan[blockIdx.x];
    off[i] = o;
    cur[i] = o;
    if (i == n - 1) off[n] = o + deg[i];
}

// ---------------------------------------------------------------------------
// XCD-partitioned CSR fill. Cols are split into 8 contiguous ranges; block
// group g = blockIdx.x & 7 (default round-robin block->XCD mapping) handles
// only cols in range g. Every nbr/cur line is then written by ONE XCD ->
// dirty lines stay in that XCD's L2 and write back once (kills the 16x
// write-amp measured on k_fill/k_part: cross-XCD scattered stores).
// Cost: col chunk re-read by 8 groups (L3-resident, cheap).
// ---------------------------------------------------------------------------
__global__ __launch_bounds__(256) void k_fillx(const int* __restrict__ row,
        const int* __restrict__ col, int* __restrict__ cur,
        int* __restrict__ nbr, int E, int gdiv) {
    int g  = blockIdx.x & 7;
    int lo = g * gdiv;
    int hi = lo + gdiv;
    int base = (blockIdx.x >> 3) * 2048;
    int end  = base + 2048; if (end > E) end = E;
    for (int t = base + threadIdx.x; t < end; t += 256) {
        int c = col[t];
        if (c >= lo && c < hi) {
            int p = atomicAdd(&cur[c], 1);
            nbr[p] = row[t];
        }
    }
}

// ---------------------------------------------------------------------------
// One-time weight transpose for coalesced phase-1 loads:
//   WT[k*192 + g*64 + j] = Wih[row(g,j)*64 + k],  g: 0->i (row j),
//   1->g (row 128+j), 2->o (row 192+j).  f-gate rows are dead (c0=0).
// ---------------------------------------------------------------------------
__global__ void k_tr(const float* __restrict__ Wih, float* __restrict__ WT) {
    int t = blockIdx.x * 256 + threadIdx.x;
    if (t >= 64 * 192) return;
    int k = t / 192, c = t % 192;
    int g = c >> 6, j = c & 63;
    int rowb = (g == 0) ? j : (g == 1) ? (128 + j) : (192 + j);
    WT[t] = Wih[rowb * 64 + k];
}

// ---------------------------------------------------------------------------
// Fused LSTM step + (h @ W1), GEMV-broadcast form.
// Wave owns 8 nodes; lane = output column.
// ---------------------------------------------------------------------------
__global__ __launch_bounds__(256) void k_lstm_mm1(
    const float* __restrict__ x, const float* __restrict__ WT,
    const float* __restrict__ bih, const float* __restrict__ bhh,
    const float* __restrict__ W1, float* __restrict__ hw1, int n)
{
    __shared__ float4 xs[4][128];          // per-wave 2KB: [k][8 nodes] as 2xfloat4
    int wv   = threadIdx.x >> 6;
    int lane = threadIdx.x & 63;
    int nbase = (blockIdx.x * 4 + wv) * 8;
    if (nbase >= n) return;                // wave-uniform

    int ni[8];
#pragma unroll
    for (int m = 0; m < 8; m++) {
        int t = nbase + m;
        ni[m] = (t < n) ? t : (n - 1);     // clamp for safe loads
    }

    // stage x rows (coalesced global reads, per-wave LDS region)
    float xv[8];
#pragma unroll
    for (int m = 0; m < 8; m++) xv[m] = x[(size_t)ni[m] * 64 + lane];
    xs[wv][lane * 2 + 0] = make_float4(xv[0], xv[1], xv[2], xv[3]);
    xs[wv][lane * 2 + 1] = make_float4(xv[4], xv[5], xv[6], xv[7]);

    float gi[8], gg[8], go[8];
#pragma unroll
    for (int m = 0; m < 8; m++) { gi[m] = 0.f; gg[m] = 0.f; go[m] = 0.f; }

#pragma unroll 8
    for (int k = 0; k < 64; k++) {
        float4 xa = xs[wv][k * 2 + 0];     // broadcast
        float4 xb = xs[wv][k * 2 + 1];
        float wi = WT[k * 192 + lane];     // coalesced 256B
        float wg = WT[k * 192 + 64 + lane];
        float wo = WT[k * 192 + 128 + lane];
        gi[0] = fmaf(xa.x, wi, gi[0]); gi[1] = fmaf(xa.y, wi, gi[1]);
        gi[2] = fmaf(xa.z, wi, gi[2]); gi[3] = fmaf(xa.w, wi, gi[3]);
        gi[4] = fmaf(xb.x, wi, gi[4]); gi[5] = fmaf(xb.y, wi, gi[5]);
        gi[6] = fmaf(xb.z, wi, gi[6]); gi[7] = fmaf(xb.w, wi, gi[7]);
        gg[0] = fmaf(xa.x, wg, gg[0]); gg[1] = fmaf(xa.y, wg, gg[1]);
        gg[2] = fmaf(xa.z, wg, gg[2]); gg[3] = fmaf(xa.w, wg, gg[3]);
        gg[4] = fmaf(xb.x, wg, gg[4]); gg[5] = fmaf(xb.y, wg, gg[5]);
        gg[6] = fmaf(xb.z, wg, gg[6]); gg[7] = fmaf(xb.w, wg, gg[7]);
        go[0] = fmaf(xa.x, wo, go[0]); go[1] = fmaf(xa.y, wo, go[1]);
        go[2] = fmaf(xa.z, wo, go[2]); go[3] = fmaf(xa.w, wo, go[3]);
        go[4] = fmaf(xb.x, wo, go[4]); go[5] = fmaf(xb.y, wo, go[5]);
        go[6] = fmaf(xb.z, wo, go[6]); go[7] = fmaf(xb.w, wo, go[7]);
    }

    float bi = bih[lane]       + bhh[lane];
    float bg = bih[128 + lane] + bhh[128 + lane];
    float bo = bih[192 + lane] + bhh[192 + lane];

    float h[8];
#pragma unroll
    for (int m = 0; m < 8; m++) {
        float c = fast_sigmoid(gi[m] + bi) * fast_tanh(gg[m] + bg);
        h[m] = fast_sigmoid(go[m] + bo) * fast_tanh(c);
    }

    // reuse the same per-wave LDS region for h (same-wave DS order is safe)
    xs[wv][lane * 2 + 0] = make_float4(h[0], h[1], h[2], h[3]);
    xs[wv][lane * 2 + 1] = make_float4(h[4], h[5], h[6], h[7]);

    float acc[8];
#pragma unroll
    for (int m = 0; m < 8; m++) acc[m] = 0.f;

#pragma unroll 8
    for (int j = 0; j < 64; j++) {
        float4 ha = xs[wv][j * 2 + 0];     // broadcast
        float4 hb = xs[wv][j * 2 + 1];
        float w = W1[j * 64 + lane];       // coalesced 256B
        acc[0] = fmaf(ha.x, w, acc[0]); acc[1] = fmaf(ha.y, w, acc[1]);
        acc[2] = fmaf(ha.z, w, acc[2]); acc[3] = fmaf(ha.w, w, acc[3]);
        acc[4] = fmaf(hb.x, w, acc[4]); acc[5] = fmaf(hb.y, w, acc[5]);
        acc[6] = fmaf(hb.z, w, acc[6]); acc[7] = fmaf(hb.w, w, acc[7]);
    }

#pragma unroll
    for (int m = 0; m < 8; m++)
        if (nbase + m < n)
            hw1[(size_t)(nbase + m) * 64 + lane] = acc[m];
}

// ---------------------------------------------------------------------------
// Pull aggregation, F=64. One wave per node, lane = feature.
// Chunked: lane l loads nbr id + weight for neighbor l (one coalesced load
// each per 64 neighbors), v_readlane broadcasts -> row loads become
// scalar-base + lane-offset and 4 independent loads stay in flight
// (breaks the nbr[j] -> dinv[r] -> hw[r] pointer chase of the old loop).
// Fused epilogue 1: h1 = relu(agg*dc + hw1[node]*dc^2 + b1)
// ---------------------------------------------------------------------------
__global__ __launch_bounds__(256) void k_pull64(
    const float* __restrict__ hw, const int* __restrict__ off,
    const int* __restrict__ nbr, const float* __restrict__ dinv,
    const float* __restrict__ b1, float* __restrict__ h1, int n)
{
    int node = (blockIdx.x * 256 + threadIdx.x) >> 6;
    int lane = threadIdx.x & 63;
    if (node >= n) return;
    int s = off[node], e = off[node + 1];

    float a0 = 0.f, a1 = 0.f, a2 = 0.f, a3 = 0.f;
    for (int base = s; base < e; base += 64) {
        int t = base + lane;
        int idx = 0; float wv = 0.f;
        if (t < e) { idx = nbr[t]; wv = dinv[idx]; }
        int cnt = e - base; if (cnt > 64) cnt = 64;

        int k = 0;
        for (; k + 4 <= cnt; k += 4) {
            int r0 = __builtin_amdgcn_readlane(idx, k + 0);
            int r1 = __builtin_amdgcn_readlane(idx, k + 1);
            int r2 = __builtin_amdgcn_readlane(idx, k + 2);
            int r3 = __builtin_amdgcn_readlane(idx, k + 3);
            float w0 = readlane_f(wv, k + 0);
            float w1 = readlane_f(wv, k + 1);
            float w2 = readlane_f(wv, k + 2);
            float w3 = readlane_f(wv, k + 3);
            float v0 = hw[(size_t)r0 * 64 + lane];
            float v1 = hw[(size_t)r1 * 64 + lane];
            float v2 = hw[(size_t)r2 * 64 + lane];
            float v3 = hw[(size_t)r3 * 64 + lane];
            a0 = fmaf(v0, w0, a0);
            a1 = fmaf(v1, w1, a1);
            a2 = fmaf(v2, w2, a2);
            a3 = fmaf(v3, w3, a3);
        }
        for (; k < cnt; k++) {
            int r = __builtin_amdgcn_readlane(idx, k);
            float w = readlane_f(wv, k);
            a0 = fmaf(hw[(size_t)r * 64 + lane], w, a0);
        }
    }

    float dc   = dinv[node];
    float self = hw[(size_t)node * 64 + lane];
    float v = ((a0 + a1) + (a2 + a3)) * dc + self * dc * dc + b1[lane];
    h1[(size_t)node * 64 + lane] = fmaxf(v, 0.0f);
}

// ---------------------------------------------------------------------------
// Pull aggregation, F=32. One wave per node; feat = lane&31, half = lane>>5;
// halves process alternate neighbors. Same chunked-index scheme (shfl since
// the source lane differs per half); padded lanes hold idx=0,w=0 so an odd
// tail contributes zero. Fused epilogue 2: z = agg*dc + hw2*dc^2 + b2.
// ---------------------------------------------------------------------------
__global__ __launch_bounds__(256) void k_pull32(
    const float* __restrict__ hw, const int* __restrict__ off,
    const int* __restrict__ nbr, const float* __restrict__ dinv,
    const float* __restrict__ b2, float* __restrict__ z, int n)
{
    int node = (blockIdx.x * 256 + threadIdx.x) >> 6;
    int lane = threadIdx.x & 63;
    int feat = lane & 31;
    int half = lane >> 5;
    if (node >= n) return;
    int s = off[node], e = off[node + 1];

    float a0 = 0.f, a1 = 0.f;
    for (int base = s; base < e; base += 64) {
        int t = base + lane;
        int idx = 0; float wv = 0.f;
        if (t < e) { idx = nbr[t]; wv = dinv[idx]; }
        int cnt = e - base; if (cnt > 64) cnt = 64;
        int cntp = (cnt + 1) & ~1;         // pad to even (pad lanes are zero)

        int j = half;
        for (; j + 2 < cntp; j += 4) {     // 2 neighbors per half per iter
            int   ra = __shfl(idx, j, 64);
            int   rb = __shfl(idx, j + 2, 64);
            float wa = __shfl(wv, j, 64);
            float wb = __shfl(wv, j + 2, 64);
            float va = hw[(size_t)ra * 32 + feat];
            float vb = hw[(size_t)rb * 32 + feat];
            a0 = fmaf(va, wa, a0);
            a1 = fmaf(vb, wb, a1);
        }
        for (; j < cntp; j += 2) {
            int   r = __shfl(idx, j, 64);
            float w = __shfl(wv, j, 64);
            a0 = fmaf(hw[(size_t)r * 32 + feat], w, a0);
        }
    }

    float acc = a0 + a1;
    acc += __shfl_xor(acc, 32, 64);        // combine even/odd halves
    float dc = dinv[node];
    float v = acc * dc + hw[(size_t)node * 32 + feat] * dc * dc + b2[feat];
    if (half == 0) z[(size_t)node * 32 + feat] = v;
}

// ---------------------------------------------------------------------------
// hw2 = h1 @ W2  ([n,64] x [64,32]). Block = 128 nodes, h1 tile in LDS (pad 65).
// ---------------------------------------------------------------------------
__global__ __launch_bounds__(128) void k_mm2(
    const float* __restrict__ h1, const float* __restrict__ W2,
    float* __restrict__ hw2, int n)
{
    __shared__ float tile[128 * 65];
    int base  = blockIdx.x * 128;
    int nrows = n - base; if (nrows > 128) nrows = 128;

    for (int idx = threadIdx.x; idx < nrows * 64; idx += 128) {
        int r = idx >> 6, c = idx & 63;
        tile[r * 65 + c] = h1[(size_t)base * 64 + idx];
    }
    __syncthreads();

    int node = base + threadIdx.x;
    if (node >= n) return;

    const float* hrow = &tile[threadIdx.x * 65];
    float acc[32];
#pragma unroll
    for (int s = 0; s < 32; s++) acc[s] = 0.0f;

    for (int k = 0; k < 64; k++) {
        float hk = hrow[k];
        const float* w = W2 + (size_t)k * 32;
#pragma unroll
        for (int s = 0; s < 32; s++) acc[s] = fmaf(hk, w[s], acc[s]);
    }

    float4* op = reinterpret_cast<float4*>(hw2 + (size_t)node * 32);
#pragma unroll
    for (int q = 0; q < 8; q++)
        op[q] = make_float4(acc[4*q], acc[4*q+1], acc[4*q+2], acc[4*q+3]);
}

// ---------------------------------------------------------------------------
// out[e] = dot(z[src[e]], z[dst[e]]) over 32 features
// ---------------------------------------------------------------------------
__global__ void k_dot(const float* __restrict__ z, const int* __restrict__ src,
                      const int* __restrict__ dst, float* __restrict__ out, int EL)
{
    int e = blockIdx.x * 256 + threadIdx.x;
    if (e >= EL) return;
    const float4* a = reinterpret_cast<const float4*>(z + (size_t)src[e] * 32);
    const float4* b = reinterpret_cast<const float4*>(z + (size_t)dst[e] * 32);
    float s = 0.0f;
#pragma unroll
    for (int q = 0; q < 8; q++) {
        float4 av = a[q], bv = b[q];
        s = fmaf(av.x, bv.x, s);
        s = fmaf(av.y, bv.y, s);
        s = fmaf(av.z, bv.z, s);
        s = fmaf(av.w, bv.w, s);
    }
    out[e] = s;
}

extern "C" void kernel_launch(void* const* d_in, const int* in_sizes, int n_in,
                              void* d_out, int out_size, void* d_ws, size_t ws_size,
                              hipStream_t stream)
{
    const float* x   = (const float*)d_in[0];
    const int*   ei  = (const int*)d_in[1];
    const int*   eli = (const int*)d_in[2];
    const float* Wih = (const float*)d_in[3];
    // d_in[4] = W_hh: mathematically dead (h0 = c0 = 0)
    const float* bih = (const float*)d_in[5];
    const float* bhh = (const float*)d_in[6];
    const float* W1  = (const float*)d_in[7];
    const float* b1  = (const float*)d_in[8];
    const float* W2  = (const float*)d_in[9];
    const float* b2  = (const float*)d_in[10];

    int n  = in_sizes[0] / 64;
    int E  = in_sizes[1] / 2;
    int EL = in_sizes[2] / 2;

    const int* row  = ei;          // source
    const int* col  = ei + E;      // destination
    const int* lsrc = eli;
    const int* ldst = eli + EL;
    float* out = (float*)d_out;

    // Workspace layout (4B units), liveness-aliased:
    //   bufA [n*64]: hw1 (lstm..pull64), then hw2 in first n*32 (mm2..pull32)
    //   bufB [n*64]: h1 (pull64..mm2), then z in first n*32 (pull32..dot)
    //   dinv [n] | off [n+1] | deg [n] | cur [n] | bsum [1024] | bscan [1024]
    //   nbr [E] | WT [64*192]   (~59.3 MB total)
    float* bufA  = (float*)d_ws;
    float* bufB  = bufA + (size_t)n * 64;
    float* dinv  = bufB + (size_t)n * 64;
    int*   off   = (int*)(dinv + n);
    int*   deg   = off + (n + 1);
    int*   cur   = deg + n;
    int*   bsum  = cur + n;
    int*   bscan = bsum + 1024;
    int*   nbr   = bscan + 1024;
    float* WT    = (float*)(nbr + E);

    int nb   = (n + 255) / 256;    // 391 for n=100000; k_scan2 handles nb<=1024
    int gdiv = (n + 7) / 8;        // 8 contiguous col ranges (XCD groups)
    dim3 blk(256);

    // --- weight transpose for LSTM phase-1 (tiny, one-time per call) ---
    k_tr<<<dim3((64 * 192 + 255) / 256), blk, 0, stream>>>(Wih, WT);

    // --- CSR build: counting sort by destination, XCD-partitioned fill ---
    hipMemsetAsync(deg, 0, (size_t)n * sizeof(int), stream);
    k_deg  <<<dim3((E + 255) / 256), blk, 0, stream>>>(col, deg, E);
    k_dinv <<<dim3(nb), blk, 0, stream>>>(deg, dinv, n);
    k_scan1<<<dim3(nb), blk, 0, stream>>>(deg, off, bsum, n);
    k_scan2<<<dim3(1), dim3(1024), 0, stream>>>(bsum, bscan, nb);
    k_scan3<<<dim3(nb), blk, 0, stream>>>(off, bscan, deg, cur, n);
    {
        int fblocks = ((E + 2047) / 2048) * 8;
        k_fillx<<<dim3(fblocks), blk, 0, stream>>>(row, col, cur, nbr, E, gdiv);
    }

    // --- LSTM + first matmul: hw1 -> bufA (8 nodes/wave, 32 nodes/block) ---
    {
        int blocks = (n + 31) / 32;
        k_lstm_mm1<<<dim3(blocks), blk, 0, stream>>>(x, WT, bih, bhh, W1, bufA, n);
    }

    // --- GCN1: pull + fused epilogue (relu) : h1 -> bufB ---
    {
        int blocks = (int)(((size_t)n * 64 + 255) / 256);
        k_pull64<<<dim3(blocks), blk, 0, stream>>>(bufA, off, nbr, dinv, b1, bufB, n);
    }

    // --- second matmul: hw2 -> bufA (hw1 dead) ---
    k_mm2<<<dim3((n + 127) / 128), dim3(128), 0, stream>>>(bufB, W2, bufA, n);

    // --- GCN2: pull + fused epilogue : z -> bufB (h1 dead) ---
    {
        int blocks = (int)(((size_t)n * 64 + 255) / 256);
        k_pull32<<<dim3(blocks), blk, 0, stream>>>(bufA, off, nbr, dinv, b2, bufB, n);
    }

    // --- edge dot products ---
    k_dot<<<dim3((EL + 255) / 256), blk, 0, stream>>>(bufB, lsrc, ldst, out, EL);
}

// Round 12
// 358.318 us; speedup vs baseline: 1.4650x; 1.0904x over previous
//
#include <hip/hip_runtime.h>
#include <hip/hip_bf16.h>
#include <hip/hip_fp16.h>
#include <math.h>

// Fast device transcendentals: native v_exp_f32 + v_rcp_f32.
// sigmoid(x) = 1 - 1/(1+e^x)   (safe for x -> +/-inf: rcp(inf)=0)
// tanh(x)    = 1 - 2/(1+e^2x)  (safe both ends)
__device__ __forceinline__ float fast_sigmoid(float x) {
    float t = __expf(x);
    return 1.0f - __builtin_amdgcn_rcpf(1.0f + t);
}
__device__ __forceinline__ float fast_tanh(float x) {
    float t = __expf(2.0f * x);
    return 1.0f - 2.0f * __builtin_amdgcn_rcpf(1.0f + t);
}

__device__ __forceinline__ float readlane_f(float v, int l) {
    return __builtin_bit_cast(float,
        __builtin_amdgcn_readlane(__builtin_bit_cast(int, v), l));
}

// ---------------------------------------------------------------------------
// Degree histogram over col (destination) indices. deg must be zeroed first.
// ---------------------------------------------------------------------------
__global__ void k_deg(const int* __restrict__ col, int* __restrict__ deg, int E) {
    int e = blockIdx.x * 256 + threadIdx.x;
    if (e < E) atomicAdd(&deg[col[e]], 1);
}

// dinv[n] = 1/sqrt(deg[n] + 1)   (+1 for the self loop; always > 0)
__global__ void k_dinv(const int* __restrict__ deg, float* __restrict__ dinv, int n) {
    int i = blockIdx.x * 256 + threadIdx.x;
    if (i < n) dinv[i] = 1.0f / sqrtf((float)(deg[i] + 1));
}

// ---------------------------------------------------------------------------
// Hierarchical exclusive scan of deg -> off (CSR row offsets).
// ---------------------------------------------------------------------------
__global__ __launch_bounds__(256) void k_scan1(const int* __restrict__ deg,
        int* __restrict__ off, int* __restrict__ bsum, int n) {
    __shared__ int tmp[256];
    int tid = threadIdx.x;
    int i = blockIdx.x * 256 + tid;
    int v = (i < n) ? deg[i] : 0;
    tmp[tid] = v;
    __syncthreads();
#pragma unroll
    for (int s = 1; s < 256; s <<= 1) {
        int t = (tid >= s) ? tmp[tid - s] : 0;
        __syncthreads();
        tmp[tid] += t;
        __syncthreads();
    }
    if (i < n) off[i] = tmp[tid] - v;             // block-local exclusive
    if (tid == 255) bsum[blockIdx.x] = tmp[255];  // block total
}

__global__ __launch_bounds__(1024) void k_scan2(const int* __restrict__ bsum,
        int* __restrict__ bscan, int nb) {
    __shared__ int tmp[1024];
    int tid = threadIdx.x;
    int v = (tid < nb) ? bsum[tid] : 0;
    tmp[tid] = v;
    __syncthreads();
#pragma unroll
    for (int s = 1; s < 1024; s <<= 1) {
        int t = (tid >= s) ? tmp[tid - s] : 0;
        __syncthreads();
        tmp[tid] += t;
        __syncthreads();
    }
    if (tid < nb) bscan[tid] = tmp[tid] - v;
}

__global__ __launch_bounds__(256) void k_scan3(int* __restrict__ off,
        const int* __restrict__ bscan, const int* __restrict__ deg,
        int* __restrict__ cur, int n) {
    int i = blockIdx.x * 256 + threadIdx.x;
    if (i >= n) return;
    int o = off[i] + bscan[blockIdx.x];
    off[i] = o;
    cur[i] = o;
    if (i == n - 1) off[n] = o + deg[i];
}

// ---------------------------------------------------------------------------
// XCD-partitioned CSR fill (see round-10 notes): block group g = blockIdx&7
// handles only cols in range g, so nbr/cur lines are single-XCD.
// ---------------------------------------------------------------------------
__global__ __launch_bounds__(256) void k_fillx(const int* __restrict__ row,
        const int* __restrict__ col, int* __restrict__ cur,
        int* __restrict__ nbr, int E, int gdiv) {
    int g  = blockIdx.x & 7;
    int lo = g * gdiv;
    int hi = lo + gdiv;
    int base = (blockIdx.x >> 3) * 2048;
    int end  = base + 2048; if (end > E) end = E;
    for (int t = base + threadIdx.x; t < end; t += 256) {
        int c = col[t];
        if (c >= lo && c < hi) {
            int p = atomicAdd(&cur[c], 1);
            nbr[p] = row[t];
        }
    }
}

// ---------------------------------------------------------------------------
// One-time weight transpose for coalesced phase-1 loads:
//   WT[k*192 + g*64 + j] = Wih[row(g,j)*64 + k]
// ---------------------------------------------------------------------------
__global__ void k_tr(const float* __restrict__ Wih, float* __restrict__ WT) {
    int t = blockIdx.x * 256 + threadIdx.x;
    if (t >= 64 * 192) return;
    int k = t / 192, c = t % 192;
    int g = c >> 6, j = c & 63;
    int rowb = (g == 0) ? j : (g == 1) ? (128 + j) : (192 + j);
    WT[t] = Wih[rowb * 64 + k];
}

// ---------------------------------------------------------------------------
// Fused LSTM step + (h @ W1), GEMV-broadcast form.
// Wave owns 8 nodes; lane = output column. Output hw1 stored as FP16
// (gather-table compression: pull64's 256B rows become 128B).
// ---------------------------------------------------------------------------
__global__ __launch_bounds__(256) void k_lstm_mm1(
    const float* __restrict__ x, const float* __restrict__ WT,
    const float* __restrict__ bih, const float* __restrict__ bhh,
    const float* __restrict__ W1, __half* __restrict__ hw1, int n)
{
    __shared__ float4 xs[4][128];          // per-wave 2KB: [k][8 nodes] as 2xfloat4
    int wv   = threadIdx.x >> 6;
    int lane = threadIdx.x & 63;
    int nbase = (blockIdx.x * 4 + wv) * 8;
    if (nbase >= n) return;                // wave-uniform

    int ni[8];
#pragma unroll
    for (int m = 0; m < 8; m++) {
        int t = nbase + m;
        ni[m] = (t < n) ? t : (n - 1);     // clamp for safe loads
    }

    // stage x rows (coalesced global reads, per-wave LDS region)
    float xv[8];
#pragma unroll
    for (int m = 0; m < 8; m++) xv[m] = x[(size_t)ni[m] * 64 + lane];
    xs[wv][lane * 2 + 0] = make_float4(xv[0], xv[1], xv[2], xv[3]);
    xs[wv][lane * 2 + 1] = make_float4(xv[4], xv[5], xv[6], xv[7]);

    float gi[8], gg[8], go[8];
#pragma unroll
    for (int m = 0; m < 8; m++) { gi[m] = 0.f; gg[m] = 0.f; go[m] = 0.f; }

#pragma unroll 8
    for (int k = 0; k < 64; k++) {
        float4 xa = xs[wv][k * 2 + 0];     // broadcast
        float4 xb = xs[wv][k * 2 + 1];
        float wi = WT[k * 192 + lane];     // coalesced 256B
        float wg = WT[k * 192 + 64 + lane];
        float wo = WT[k * 192 + 128 + lane];
        gi[0] = fmaf(xa.x, wi, gi[0]); gi[1] = fmaf(xa.y, wi, gi[1]);
        gi[2] = fmaf(xa.z, wi, gi[2]); gi[3] = fmaf(xa.w, wi, gi[3]);
        gi[4] = fmaf(xb.x, wi, gi[4]); gi[5] = fmaf(xb.y, wi, gi[5]);
        gi[6] = fmaf(xb.z, wi, gi[6]); gi[7] = fmaf(xb.w, wi, gi[7]);
        gg[0] = fmaf(xa.x, wg, gg[0]); gg[1] = fmaf(xa.y, wg, gg[1]);
        gg[2] = fmaf(xa.z, wg, gg[2]); gg[3] = fmaf(xa.w, wg, gg[3]);
        gg[4] = fmaf(xb.x, wg, gg[4]); gg[5] = fmaf(xb.y, wg, gg[5]);
        gg[6] = fmaf(xb.z, wg, gg[6]); gg[7] = fmaf(xb.w, wg, gg[7]);
        go[0] = fmaf(xa.x, wo, go[0]); go[1] = fmaf(xa.y, wo, go[1]);
        go[2] = fmaf(xa.z, wo, go[2]); go[3] = fmaf(xa.w, wo, go[3]);
        go[4] = fmaf(xb.x, wo, go[4]); go[5] = fmaf(xb.y, wo, go[5]);
        go[6] = fmaf(xb.z, wo, go[6]); go[7] = fmaf(xb.w, wo, go[7]);
    }

    float bi = bih[lane]       + bhh[lane];
    float bg = bih[128 + lane] + bhh[128 + lane];
    float bo = bih[192 + lane] + bhh[192 + lane];

    float h[8];
#pragma unroll
    for (int m = 0; m < 8; m++) {
        float c = fast_sigmoid(gi[m] + bi) * fast_tanh(gg[m] + bg);
        h[m] = fast_sigmoid(go[m] + bo) * fast_tanh(c);
    }

    // reuse the same per-wave LDS region for h (same-wave DS order is safe)
    xs[wv][lane * 2 + 0] = make_float4(h[0], h[1], h[2], h[3]);
    xs[wv][lane * 2 + 1] = make_float4(h[4], h[5], h[6], h[7]);

    float acc[8];
#pragma unroll
    for (int m = 0; m < 8; m++) acc[m] = 0.f;

#pragma unroll 8
    for (int j = 0; j < 64; j++) {
        float4 ha = xs[wv][j * 2 + 0];     // broadcast
        float4 hb = xs[wv][j * 2 + 1];
        float w = W1[j * 64 + lane];       // coalesced 256B
        acc[0] = fmaf(ha.x, w, acc[0]); acc[1] = fmaf(ha.y, w, acc[1]);
        acc[2] = fmaf(ha.z, w, acc[2]); acc[3] = fmaf(ha.w, w, acc[3]);
        acc[4] = fmaf(hb.x, w, acc[4]); acc[5] = fmaf(hb.y, w, acc[5]);
        acc[6] = fmaf(hb.z, w, acc[6]); acc[7] = fmaf(hb.w, w, acc[7]);
    }

#pragma unroll
    for (int m = 0; m < 8; m++)
        if (nbase + m < n)
            hw1[(size_t)(nbase + m) * 64 + lane] = __float2half(acc[m]);
}

// ---------------------------------------------------------------------------
// Pull aggregation, F=64. One wave per node, lane = feature. FP16 source
// rows (128B/row), f32 accumulation. Chunked readlane scheme: 4 independent
// row loads in flight (no nbr->dinv->hw pointer chase).
// Fused epilogue 1: h1 = relu(agg*dc + hw1[node]*dc^2 + b1)   (h1 stays f32)
// ---------------------------------------------------------------------------
__global__ __launch_bounds__(256) void k_pull64(
    const __half* __restrict__ hw, const int* __restrict__ off,
    const int* __restrict__ nbr, const float* __restrict__ dinv,
    const float* __restrict__ b1, float* __restrict__ h1, int n)
{
    int node = (blockIdx.x * 256 + threadIdx.x) >> 6;
    int lane = threadIdx.x & 63;
    if (node >= n) return;
    int s = off[node], e = off[node + 1];

    float a0 = 0.f, a1 = 0.f, a2 = 0.f, a3 = 0.f;
    for (int base = s; base < e; base += 64) {
        int t = base + lane;
        int idx = 0; float wv = 0.f;
        if (t < e) { idx = nbr[t]; wv = dinv[idx]; }
        int cnt = e - base; if (cnt > 64) cnt = 64;

        int k = 0;
        for (; k + 4 <= cnt; k += 4) {
            int r0 = __builtin_amdgcn_readlane(idx, k + 0);
            int r1 = __builtin_amdgcn_readlane(idx, k + 1);
            int r2 = __builtin_amdgcn_readlane(idx, k + 2);
            int r3 = __builtin_amdgcn_readlane(idx, k + 3);
            float w0 = readlane_f(wv, k + 0);
            float w1 = readlane_f(wv, k + 1);
            float w2 = readlane_f(wv, k + 2);
            float w3 = readlane_f(wv, k + 3);
            float v0 = __half2float(hw[(size_t)r0 * 64 + lane]);
            float v1 = __half2float(hw[(size_t)r1 * 64 + lane]);
            float v2 = __half2float(hw[(size_t)r2 * 64 + lane]);
            float v3 = __half2float(hw[(size_t)r3 * 64 + lane]);
            a0 = fmaf(v0, w0, a0);
            a1 = fmaf(v1, w1, a1);
            a2 = fmaf(v2, w2, a2);
            a3 = fmaf(v3, w3, a3);
        }
        for (; k < cnt; k++) {
            int r = __builtin_amdgcn_readlane(idx, k);
            float w = readlane_f(wv, k);
            a0 = fmaf(__half2float(hw[(size_t)r * 64 + lane]), w, a0);
        }
    }

    float dc   = dinv[node];
    float self = __half2float(hw[(size_t)node * 64 + lane]);
    float v = ((a0 + a1) + (a2 + a3)) * dc + self * dc * dc + b1[lane];
    h1[(size_t)node * 64 + lane] = fmaxf(v, 0.0f);
}

// ---------------------------------------------------------------------------
// Pull aggregation, F=32. FP16 source rows (64B/row), f32 accumulation,
// FP16 z output. Same chunked scheme, halves on alternate neighbors.
// Fused epilogue 2: z = agg*dc + hw2*dc^2 + b2  (no relu)
// ---------------------------------------------------------------------------
__global__ __launch_bounds__(256) void k_pull32(
    const __half* __restrict__ hw, const int* __restrict__ off,
    const int* __restrict__ nbr, const float* __restrict__ dinv,
    const float* __restrict__ b2, __half* __restrict__ z, int n)
{
    int node = (blockIdx.x * 256 + threadIdx.x) >> 6;
    int lane = threadIdx.x & 63;
    int feat = lane & 31;
    int half = lane >> 5;
    if (node >= n) return;
    int s = off[node], e = off[node + 1];

    float a0 = 0.f, a1 = 0.f;
    for (int base = s; base < e; base += 64) {
        int t = base + lane;
        int idx = 0; float wv = 0.f;
        if (t < e) { idx = nbr[t]; wv = dinv[idx]; }
        int cnt = e - base; if (cnt > 64) cnt = 64;
        int cntp = (cnt + 1) & ~1;         // pad to even (pad lanes are zero)

        int j = half;
        for (; j + 2 < cntp; j += 4) {     // 2 neighbors per half per iter
            int   ra = __shfl(idx, j, 64);
            int   rb = __shfl(idx, j + 2, 64);
            float wa = __shfl(wv, j, 64);
            float wb = __shfl(wv, j + 2, 64);
            float va = __half2float(hw[(size_t)ra * 32 + feat]);
            float vb = __half2float(hw[(size_t)rb * 32 + feat]);
            a0 = fmaf(va, wa, a0);
            a1 = fmaf(vb, wb, a1);
        }
        for (; j < cntp; j += 2) {
            int   r = __shfl(idx, j, 64);
            float w = __shfl(wv, j, 64);
            a0 = fmaf(__half2float(hw[(size_t)r * 32 + feat]), w, a0);
        }
    }

    float acc = a0 + a1;
    acc += __shfl_xor(acc, 32, 64);        // combine even/odd halves
    float dc = dinv[node];
    float v = acc * dc + __half2float(hw[(size_t)node * 32 + feat]) * dc * dc + b2[feat];
    if (half == 0) z[(size_t)node * 32 + feat] = __float2half(v);
}

// ---------------------------------------------------------------------------
// hw2 = h1 @ W2  ([n,64] x [64,32]). f32 compute, FP16 output rows.
// ---------------------------------------------------------------------------
__global__ __launch_bounds__(128) void k_mm2(
    const float* __restrict__ h1, const float* __restrict__ W2,
    __half* __restrict__ hw2, int n)
{
    __shared__ float tile[128 * 65];
    int base  = blockIdx.x * 128;
    int nrows = n - base; if (nrows > 128) nrows = 128;

    for (int idx = threadIdx.x; idx < nrows * 64; idx += 128) {
        int r = idx >> 6, c = idx & 63;
        tile[r * 65 + c] = h1[(size_t)base * 64 + idx];
    }
    __syncthreads();

    int node = base + threadIdx.x;
    if (node >= n) return;

    const float* hrow = &tile[threadIdx.x * 65];
    float acc[32];
#pragma unroll
    for (int s = 0; s < 32; s++) acc[s] = 0.0f;

    for (int k = 0; k < 64; k++) {
        float hk = hrow[k];
        const float* w = W2 + (size_t)k * 32;
#pragma unroll
        for (int s = 0; s < 32; s++) acc[s] = fmaf(hk, w[s], acc[s]);
    }

    // pack 32 halves = 64B per node, coalesced at wave granularity
    uint2* op = reinterpret_cast<uint2*>(hw2 + (size_t)node * 32);
#pragma unroll
    for (int q = 0; q < 8; q++) {
        __half2 lo(__float2half(acc[4*q+0]), __float2half(acc[4*q+1]));
        __half2 hi(__float2half(acc[4*q+2]), __float2half(acc[4*q+3]));
        op[q] = make_uint2(__builtin_bit_cast(unsigned, lo),
                           __builtin_bit_cast(unsigned, hi));
    }
}

// ---------------------------------------------------------------------------
// out[e] = dot(z[src[e]], z[dst[e]]) over 32 features; z is FP16.
// Row = 32 halves = 64B = 4 x uint4  (r11 bug: q<2 read only half the row).
// ---------------------------------------------------------------------------
__global__ void k_dot(const __half* __restrict__ z, const int* __restrict__ src,
                      const int* __restrict__ dst, float* __restrict__ out, int EL)
{
    int e = blockIdx.x * 256 + threadIdx.x;
    if (e >= EL) return;
    const uint4* a = reinterpret_cast<const uint4*>(z + (size_t)src[e] * 32);
    const uint4* b = reinterpret_cast<const uint4*>(z + (size_t)dst[e] * 32);
    float s = 0.0f;
#pragma unroll
    for (int q = 0; q < 4; q++) {
        uint4 av = a[q], bv = b[q];
        unsigned au[4] = {av.x, av.y, av.z, av.w};
        unsigned bu[4] = {bv.x, bv.y, bv.z, bv.w};
#pragma unroll
        for (int p = 0; p < 4; p++) {
            float2 fa = __half22float2(__builtin_bit_cast(__half2, au[p]));
            float2 fb = __half22float2(__builtin_bit_cast(__half2, bu[p]));
            s = fmaf(fa.x, fb.x, s);
            s = fmaf(fa.y, fb.y, s);
        }
    }
    out[e] = s;
}

extern "C" void kernel_launch(void* const* d_in, const int* in_sizes, int n_in,
                              void* d_out, int out_size, void* d_ws, size_t ws_size,
                              hipStream_t stream)
{
    const float* x   = (const float*)d_in[0];
    const int*   ei  = (const int*)d_in[1];
    const int*   eli = (const int*)d_in[2];
    const float* Wih = (const float*)d_in[3];
    // d_in[4] = W_hh: mathematically dead (h0 = c0 = 0)
    const float* bih = (const float*)d_in[5];
    const float* bhh = (const float*)d_in[6];
    const float* W1  = (const float*)d_in[7];
    const float* b1  = (const float*)d_in[8];
    const float* W2  = (const float*)d_in[9];
    const float* b2  = (const float*)d_in[10];

    int n  = in_sizes[0] / 64;
    int E  = in_sizes[1] / 2;
    int EL = in_sizes[2] / 2;

    const int* row  = ei;          // source
    const int* col  = ei + E;      // destination
    const int* lsrc = eli;
    const int* ldst = eli + EL;
    float* out = (float*)d_out;

    // Workspace layout (4B units), liveness-aliased:
    //   bufA [n*64 f32 region]: hw1 FP16 (lstm..pull64), then hw2 FP16
    //                           (mm2..pull32)
    //   bufB [n*64 f32 region]: h1 f32 (pull64..mm2), then z FP16 (pull32..dot)
    //   dinv [n] | off [n+1] | deg [n] | cur [n] | bsum [1024] | bscan [1024]
    //   nbr [E] | WT [64*192]   (~59.3 MB total)
    float*  bufA  = (float*)d_ws;
    float*  bufB  = bufA + (size_t)n * 64;
    float*  dinv  = bufB + (size_t)n * 64;
    int*    off   = (int*)(dinv + n);
    int*    deg   = off + (n + 1);
    int*    cur   = deg + n;
    int*    bsum  = cur + n;
    int*    bscan = bsum + 1024;
    int*    nbr   = bscan + 1024;
    float*  WT    = (float*)(nbr + E);
    __half* hw1h  = (__half*)bufA;
    __half* hw2h  = (__half*)bufA;  // hw1 dead by the time mm2 writes
    float*  h1    = bufB;
    __half* zh    = (__half*)bufB;  // h1 dead by the time pull32 writes

    int nb   = (n + 255) / 256;    // 391 for n=100000; k_scan2 handles nb<=1024
    int gdiv = (n + 7) / 8;        // 8 contiguous col ranges (XCD groups)
    dim3 blk(256);

    // --- weight transpose for LSTM phase-1 (tiny, one-time per call) ---
    k_tr<<<dim3((64 * 192 + 255) / 256), blk, 0, stream>>>(Wih, WT);

    // --- CSR build: counting sort by destination, XCD-partitioned fill ---
    hipMemsetAsync(deg, 0, (size_t)n * sizeof(int), stream);
    k_deg  <<<dim3((E + 255) / 256), blk, 0, stream>>>(col, deg, E);
    k_dinv <<<dim3(nb), blk, 0, stream>>>(deg, dinv, n);
    k_scan1<<<dim3(nb), blk, 0, stream>>>(deg, off, bsum, n);
    k_scan2<<<dim3(1), dim3(1024), 0, stream>>>(bsum, bscan, nb);
    k_scan3<<<dim3(nb), blk, 0, stream>>>(off, bscan, deg, cur, n);
    {
        int fblocks = ((E + 2047) / 2048) * 8;
        k_fillx<<<dim3(fblocks), blk, 0, stream>>>(row, col, cur, nbr, E, gdiv);
    }

    // --- LSTM + first matmul: hw1 (fp16) -> bufA ---
    {
        int blocks = (n + 31) / 32;
        k_lstm_mm1<<<dim3(blocks), blk, 0, stream>>>(x, WT, bih, bhh, W1, hw1h, n);
    }

    // --- GCN1: pull + fused epilogue (relu) : h1 (f32) -> bufB ---
    {
        int blocks = (int)(((size_t)n * 64 + 255) / 256);
        k_pull64<<<dim3(blocks), blk, 0, stream>>>(hw1h, off, nbr, dinv, b1, h1, n);
    }

    // --- second matmul: hw2 (fp16) -> bufA (hw1 dead) ---
    k_mm2<<<dim3((n + 127) / 128), dim3(128), 0, stream>>>(h1, W2, hw2h, n);

    // --- GCN2: pull + fused epilogue : z (fp16) -> bufB (h1 dead) ---
    {
        int blocks = (int)(((size_t)n * 64 + 255) / 256);
        k_pull32<<<dim3(blocks), blk, 0, stream>>>(hw2h, off, nbr, dinv, b2, zh, n);
    }

    // --- edge dot products ---
    k_dot<<<dim3((EL + 255) / 256), blk, 0, stream>>>(zh, lsrc, ldst, out, EL);
}

// Round 13
// 344.138 us; speedup vs baseline: 1.5254x; 1.0412x over previous
//
#include <hip/hip_runtime.h>
#include <hip/hip_bf16.h>
#include <hip/hip_fp16.h>
#include <math.h>

#define NBSH 9        // 512 destination cols per bucket
#define CH   4096     // edges staged per k_bin block

// Fast device transcendentals: native v_exp_f32 + v_rcp_f32.
__device__ __forceinline__ float fast_sigmoid(float x) {
    float t = __expf(x);
    return 1.0f - __builtin_amdgcn_rcpf(1.0f + t);
}
__device__ __forceinline__ float fast_tanh(float x) {
    float t = __expf(2.0f * x);
    return 1.0f - 2.0f * __builtin_amdgcn_rcpf(1.0f + t);
}

__device__ __forceinline__ float readlane_f(float v, int l) {
    return __builtin_bit_cast(float,
        __builtin_amdgcn_readlane(__builtin_bit_cast(int, v), l));
}

// ---------------------------------------------------------------------------
// Degree histogram over col (destination) indices. deg must be zeroed first.
// ---------------------------------------------------------------------------
__global__ void k_deg(const int* __restrict__ col, int* __restrict__ deg, int E) {
    int e = blockIdx.x * 256 + threadIdx.x;
    if (e < E) atomicAdd(&deg[col[e]], 1);
}

// dinv[n] = 1/sqrt(deg[n] + 1)   (+1 for the self loop; always > 0)
__global__ void k_dinv(const int* __restrict__ deg, float* __restrict__ dinv, int n) {
    int i = blockIdx.x * 256 + threadIdx.x;
    if (i < n) dinv[i] = 1.0f / sqrtf((float)(deg[i] + 1));
}

// ---------------------------------------------------------------------------
// Hierarchical exclusive scan of deg -> off (CSR row offsets).
// ---------------------------------------------------------------------------
__global__ __launch_bounds__(256) void k_scan1(const int* __restrict__ deg,
        int* __restrict__ off, int* __restrict__ bsum, int n) {
    __shared__ int tmp[256];
    int tid = threadIdx.x;
    int i = blockIdx.x * 256 + tid;
    int v = (i < n) ? deg[i] : 0;
    tmp[tid] = v;
    __syncthreads();
#pragma unroll
    for (int s = 1; s < 256; s <<= 1) {
        int t = (tid >= s) ? tmp[tid - s] : 0;
        __syncthreads();
        tmp[tid] += t;
        __syncthreads();
    }
    if (i < n) off[i] = tmp[tid] - v;             // block-local exclusive
    if (tid == 255) bsum[blockIdx.x] = tmp[255];  // block total
}

__global__ __launch_bounds__(1024) void k_scan2(const int* __restrict__ bsum,
        int* __restrict__ bscan, int nb) {
    __shared__ int tmp[1024];
    int tid = threadIdx.x;
    int v = (tid < nb) ? bsum[tid] : 0;
    tmp[tid] = v;
    __syncthreads();
#pragma unroll
    for (int s = 1; s < 1024; s <<= 1) {
        int t = (tid >= s) ? tmp[tid - s] : 0;
        __syncthreads();
        tmp[tid] += t;
        __syncthreads();
    }
    if (tid < nb) bscan[tid] = tmp[tid] - v;
}

__global__ __launch_bounds__(256) void k_scan3(int* __restrict__ off,
        const int* __restrict__ bscan, const int* __restrict__ deg,
        int* __restrict__ cur, int n) {
    int i = blockIdx.x * 256 + threadIdx.x;
    if (i >= n) return;
    int o = off[i] + bscan[blockIdx.x];
    off[i] = o;
    cur[i] = o;
    if (i == n - 1) off[n] = o + deg[i];
}

// Bucket cursors, PADDED one per 64B line (stride 16 ints): bucket b's ebuf
// region starts at off[b*512] (free from CSR off; no extra scan needed).
__global__ void k_gcur(const int* __restrict__ off, int* __restrict__ gcur,
                       int nbuck, int n) {
    int b = blockIdx.x * 256 + threadIdx.x;
    if (b < nbuck) {
        int c0 = b << NBSH; if (c0 > n) c0 = n;
        gcur[b * 16] = off[c0];
    }
}

// ---------------------------------------------------------------------------
// Pass 1: LDS-binned partition of edges into 512-col buckets.
// Per block: histogram 4096 edges into LDS counters, block-scan, ONE padded
// global reservation per (bucket, block), sort into LDS staging, copy out as
// coalesced per-bucket runs (~21 edges = 168B contiguous). Each 64B ebuf
// line is written by <=2 blocks -> kills k_fillx's 11x write-amp.
// ---------------------------------------------------------------------------
__global__ __launch_bounds__(256) void k_bin(
    const int* __restrict__ row, const int* __restrict__ col,
    int* __restrict__ gcur, int2* __restrict__ ebuf, int E, int nbuck)
{
    __shared__ int  cnt[256], lofs[256], gbase[256], cur2[256];
    __shared__ int2 stage[CH];
    int tid  = threadIdx.x;
    int base = blockIdx.x * CH;
    int ned  = E - base; if (ned > CH) ned = CH;

    cnt[tid] = 0;
    __syncthreads();

    int r[16], c[16], b[16];
#pragma unroll
    for (int i = 0; i < 16; i++) {
        int idx = i * 256 + tid;
        if (idx < ned) {
            r[i] = row[base + idx];
            c[i] = col[base + idx];
            b[i] = c[i] >> NBSH;
            atomicAdd(&cnt[b[i]], 1);
        } else { r[i] = 0; c[i] = 0; b[i] = -1; }
    }
    __syncthreads();

    // exclusive scan of cnt (inclusive Hillis-Steele, then subtract own)
    int v = cnt[tid];
    lofs[tid] = v;
    __syncthreads();
#pragma unroll
    for (int s = 1; s < 256; s <<= 1) {
        int t = (tid >= s) ? lofs[tid - s] : 0;
        __syncthreads();
        lofs[tid] += t;
        __syncthreads();
    }
    int excl = lofs[tid] - v;
    __syncthreads();
    lofs[tid] = excl;
    cur2[tid] = excl;
    if (tid < nbuck && v > 0)
        gbase[tid] = atomicAdd(&gcur[tid * 16], v);   // padded: no hot line
    __syncthreads();

    // bucket-sort into staging
#pragma unroll
    for (int i = 0; i < 16; i++) {
        if (b[i] >= 0) {
            int p = atomicAdd(&cur2[b[i]], 1);
            stage[p] = make_int2(r[i], c[i]);
        }
    }
    __syncthreads();

    // linear copy staging -> ebuf (coalesced per-bucket runs)
    for (int i = tid; i < ned; i += 256) {
        int2 rc = stage[i];
        int bb = rc.y >> NBSH;
        ebuf[gbase[bb] + (i - lofs[bb])] = rc;
    }
}

// ---------------------------------------------------------------------------
// Pass 2: final CSR fill. One block per bucket; all nbr/cur writes land in a
// ~32KB single-XCD window during one block's lifetime -> 1 writeback/line.
// ---------------------------------------------------------------------------
__global__ __launch_bounds__(512) void k_fill3(
    const int2* __restrict__ ebuf, const int* __restrict__ off,
    int* __restrict__ cur, int* __restrict__ nbr, int n)
{
    int b  = blockIdx.x;
    int c0 = b << NBSH;
    int c1 = c0 + (1 << NBSH); if (c1 > n) c1 = n;
    if (c0 > n) return;
    int lo = off[c0], hi = off[c1];
    for (int t = lo + (int)threadIdx.x; t < hi; t += 512) {
        int2 rc = ebuf[t];
        int p = atomicAdd(&cur[rc.y], 1);
        nbr[p] = rc.x;
    }
}

// ---------------------------------------------------------------------------
// One-time weight transpose for coalesced phase-1 loads:
//   WT[k*192 + g*64 + j] = Wih[row(g,j)*64 + k]
// ---------------------------------------------------------------------------
__global__ void k_tr(const float* __restrict__ Wih, float* __restrict__ WT) {
    int t = blockIdx.x * 256 + threadIdx.x;
    if (t >= 64 * 192) return;
    int k = t / 192, c = t % 192;
    int g = c >> 6, j = c & 63;
    int rowb = (g == 0) ? j : (g == 1) ? (128 + j) : (192 + j);
    WT[t] = Wih[rowb * 64 + k];
}

// ---------------------------------------------------------------------------
// Fused LSTM step + (h @ W1), GEMV-broadcast form.
// Wave owns 8 nodes; lane = output column. hw1 stored FP16.
// ---------------------------------------------------------------------------
__global__ __launch_bounds__(256) void k_lstm_mm1(
    const float* __restrict__ x, const float* __restrict__ WT,
    const float* __restrict__ bih, const float* __restrict__ bhh,
    const float* __restrict__ W1, __half* __restrict__ hw1, int n)
{
    __shared__ float4 xs[4][128];          // per-wave 2KB: [k][8 nodes] as 2xfloat4
    int wv   = threadIdx.x >> 6;
    int lane = threadIdx.x & 63;
    int nbase = (blockIdx.x * 4 + wv) * 8;
    if (nbase >= n) return;                // wave-uniform

    int ni[8];
#pragma unroll
    for (int m = 0; m < 8; m++) {
        int t = nbase + m;
        ni[m] = (t < n) ? t : (n - 1);     // clamp for safe loads
    }

    float xv[8];
#pragma unroll
    for (int m = 0; m < 8; m++) xv[m] = x[(size_t)ni[m] * 64 + lane];
    xs[wv][lane * 2 + 0] = make_float4(xv[0], xv[1], xv[2], xv[3]);
    xs[wv][lane * 2 + 1] = make_float4(xv[4], xv[5], xv[6], xv[7]);

    float gi[8], gg[8], go[8];
#pragma unroll
    for (int m = 0; m < 8; m++) { gi[m] = 0.f; gg[m] = 0.f; go[m] = 0.f; }

#pragma unroll 8
    for (int k = 0; k < 64; k++) {
        float4 xa = xs[wv][k * 2 + 0];     // broadcast
        float4 xb = xs[wv][k * 2 + 1];
        float wi = WT[k * 192 + lane];     // coalesced 256B
        float wg = WT[k * 192 + 64 + lane];
        float wo = WT[k * 192 + 128 + lane];
        gi[0] = fmaf(xa.x, wi, gi[0]); gi[1] = fmaf(xa.y, wi, gi[1]);
        gi[2] = fmaf(xa.z, wi, gi[2]); gi[3] = fmaf(xa.w, wi, gi[3]);
        gi[4] = fmaf(xb.x, wi, gi[4]); gi[5] = fmaf(xb.y, wi, gi[5]);
        gi[6] = fmaf(xb.z, wi, gi[6]); gi[7] = fmaf(xb.w, wi, gi[7]);
        gg[0] = fmaf(xa.x, wg, gg[0]); gg[1] = fmaf(xa.y, wg, gg[1]);
        gg[2] = fmaf(xa.z, wg, gg[2]); gg[3] = fmaf(xa.w, wg, gg[3]);
        gg[4] = fmaf(xb.x, wg, gg[4]); gg[5] = fmaf(xb.y, wg, gg[5]);
        gg[6] = fmaf(xb.z, wg, gg[6]); gg[7] = fmaf(xb.w, wg, gg[7]);
        go[0] = fmaf(xa.x, wo, go[0]); go[1] = fmaf(xa.y, wo, go[1]);
        go[2] = fmaf(xa.z, wo, go[2]); go[3] = fmaf(xa.w, wo, go[3]);
        go[4] = fmaf(xb.x, wo, go[4]); go[5] = fmaf(xb.y, wo, go[5]);
        go[6] = fmaf(xb.z, wo, go[6]); go[7] = fmaf(xb.w, wo, go[7]);
    }

    float bi = bih[lane]       + bhh[lane];
    float bg = bih[128 + lane] + bhh[128 + lane];
    float bo = bih[192 + lane] + bhh[192 + lane];

    float h[8];
#pragma unroll
    for (int m = 0; m < 8; m++) {
        float c = fast_sigmoid(gi[m] + bi) * fast_tanh(gg[m] + bg);
        h[m] = fast_sigmoid(go[m] + bo) * fast_tanh(c);
    }

    // reuse the same per-wave LDS region for h (same-wave DS order is safe)
    xs[wv][lane * 2 + 0] = make_float4(h[0], h[1], h[2], h[3]);
    xs[wv][lane * 2 + 1] = make_float4(h[4], h[5], h[6], h[7]);

    float acc[8];
#pragma unroll
    for (int m = 0; m < 8; m++) acc[m] = 0.f;

#pragma unroll 8
    for (int j = 0; j < 64; j++) {
        float4 ha = xs[wv][j * 2 + 0];     // broadcast
        float4 hb = xs[wv][j * 2 + 1];
        float w = W1[j * 64 + lane];       // coalesced 256B
        acc[0] = fmaf(ha.x, w, acc[0]); acc[1] = fmaf(ha.y, w, acc[1]);
        acc[2] = fmaf(ha.z, w, acc[2]); acc[3] = fmaf(ha.w, w, acc[3]);
        acc[4] = fmaf(hb.x, w, acc[4]); acc[5] = fmaf(hb.y, w, acc[5]);
        acc[6] = fmaf(hb.z, w, acc[6]); acc[7] = fmaf(hb.w, w, acc[7]);
    }

#pragma unroll
    for (int m = 0; m < 8; m++)
        if (nbase + m < n)
            hw1[(size_t)(nbase + m) * 64 + lane] = __float2half(acc[m]);
}

// ---------------------------------------------------------------------------
// Pull aggregation, F=64. One wave per node, lane = feature. FP16 source
// rows (128B/row), f32 accumulation. Chunked readlane: 4 loads in flight.
// Fused epilogue 1: h1 = relu(agg*dc + hw1[node]*dc^2 + b1)   (h1 stays f32)
// ---------------------------------------------------------------------------
__global__ __launch_bounds__(256) void k_pull64(
    const __half* __restrict__ hw, const int* __restrict__ off,
    const int* __restrict__ nbr, const float* __restrict__ dinv,
    const float* __restrict__ b1, float* __restrict__ h1, int n)
{
    int node = (blockIdx.x * 256 + threadIdx.x) >> 6;
    int lane = threadIdx.x & 63;
    if (node >= n) return;
    int s = off[node], e = off[node + 1];

    float a0 = 0.f, a1 = 0.f, a2 = 0.f, a3 = 0.f;
    for (int base = s; base < e; base += 64) {
        int t = base + lane;
        int idx = 0; float wv = 0.f;
        if (t < e) { idx = nbr[t]; wv = dinv[idx]; }
        int cnt = e - base; if (cnt > 64) cnt = 64;

        int k = 0;
        for (; k + 4 <= cnt; k += 4) {
            int r0 = __builtin_amdgcn_readlane(idx, k + 0);
            int r1 = __builtin_amdgcn_readlane(idx, k + 1);
            int r2 = __builtin_amdgcn_readlane(idx, k + 2);
            int r3 = __builtin_amdgcn_readlane(idx, k + 3);
            float w0 = readlane_f(wv, k + 0);
            float w1 = readlane_f(wv, k + 1);
            float w2 = readlane_f(wv, k + 2);
            float w3 = readlane_f(wv, k + 3);
            float v0 = __half2float(hw[(size_t)r0 * 64 + lane]);
            float v1 = __half2float(hw[(size_t)r1 * 64 + lane]);
            float v2 = __half2float(hw[(size_t)r2 * 64 + lane]);
            float v3 = __half2float(hw[(size_t)r3 * 64 + lane]);
            a0 = fmaf(v0, w0, a0);
            a1 = fmaf(v1, w1, a1);
            a2 = fmaf(v2, w2, a2);
            a3 = fmaf(v3, w3, a3);
        }
        for (; k < cnt; k++) {
            int r = __builtin_amdgcn_readlane(idx, k);
            float w = readlane_f(wv, k);
            a0 = fmaf(__half2float(hw[(size_t)r * 64 + lane]), w, a0);
        }
    }

    float dc   = dinv[node];
    float self = __half2float(hw[(size_t)node * 64 + lane]);
    float v = ((a0 + a1) + (a2 + a3)) * dc + self * dc * dc + b1[lane];
    h1[(size_t)node * 64 + lane] = fmaxf(v, 0.0f);
}

// ---------------------------------------------------------------------------
// Pull aggregation, F=32. FP16 source rows (64B/row), f32 accumulation,
// FP16 z output. Halves on alternate neighbors.
// Fused epilogue 2: z = agg*dc + hw2*dc^2 + b2  (no relu)
// ---------------------------------------------------------------------------
__global__ __launch_bounds__(256) void k_pull32(
    const __half* __restrict__ hw, const int* __restrict__ off,
    const int* __restrict__ nbr, const float* __restrict__ dinv,
    const float* __restrict__ b2, __half* __restrict__ z, int n)
{
    int node = (blockIdx.x * 256 + threadIdx.x) >> 6;
    int lane = threadIdx.x & 63;
    int feat = lane & 31;
    int half = lane >> 5;
    if (node >= n) return;
    int s = off[node], e = off[node + 1];

    float a0 = 0.f, a1 = 0.f;
    for (int base = s; base < e; base += 64) {
        int t = base + lane;
        int idx = 0; float wv = 0.f;
        if (t < e) { idx = nbr[t]; wv = dinv[idx]; }
        int cnt = e - base; if (cnt > 64) cnt = 64;
        int cntp = (cnt + 1) & ~1;         // pad to even (pad lanes are zero)

        int j = half;
        for (; j + 2 < cntp; j += 4) {     // 2 neighbors per half per iter
            int   ra = __shfl(idx, j, 64);
            int   rb = __shfl(idx, j + 2, 64);
            float wa = __shfl(wv, j, 64);
            float wb = __shfl(wv, j + 2, 64);
            float va = __half2float(hw[(size_t)ra * 32 + feat]);
            float vb = __half2float(hw[(size_t)rb * 32 + feat]);
            a0 = fmaf(va, wa, a0);
            a1 = fmaf(vb, wb, a1);
        }
        for (; j < cntp; j += 2) {
            int   r = __shfl(idx, j, 64);
            float w = __shfl(wv, j, 64);
            a0 = fmaf(__half2float(hw[(size_t)r * 32 + feat]), w, a0);
        }
    }

    float acc = a0 + a1;
    acc += __shfl_xor(acc, 32, 64);        // combine even/odd halves
    float dc = dinv[node];
    float v = acc * dc + __half2float(hw[(size_t)node * 32 + feat]) * dc * dc + b2[feat];
    if (half == 0) z[(size_t)node * 32 + feat] = __float2half(v);
}

// ---------------------------------------------------------------------------
// hw2 = h1 @ W2  ([n,64] x [64,32]). f32 compute, FP16 output rows.
// ---------------------------------------------------------------------------
__global__ __launch_bounds__(128) void k_mm2(
    const float* __restrict__ h1, const float* __restrict__ W2,
    __half* __restrict__ hw2, int n)
{
    __shared__ float tile[128 * 65];
    int base  = blockIdx.x * 128;
    int nrows = n - base; if (nrows > 128) nrows = 128;

    for (int idx = threadIdx.x; idx < nrows * 64; idx += 128) {
        int r = idx >> 6, c = idx & 63;
        tile[r * 65 + c] = h1[(size_t)base * 64 + idx];
    }
    __syncthreads();

    int node = base + threadIdx.x;
    if (node >= n) return;

    const float* hrow = &tile[threadIdx.x * 65];
    float acc[32];
#pragma unroll
    for (int s = 0; s < 32; s++) acc[s] = 0.0f;

    for (int k = 0; k < 64; k++) {
        float hk = hrow[k];
        const float* w = W2 + (size_t)k * 32;
#pragma unroll
        for (int s = 0; s < 32; s++) acc[s] = fmaf(hk, w[s], acc[s]);
    }

    uint2* op = reinterpret_cast<uint2*>(hw2 + (size_t)node * 32);
#pragma unroll
    for (int q = 0; q < 8; q++) {
        __half2 lo(__float2half(acc[4*q+0]), __float2half(acc[4*q+1]));
        __half2 hi(__float2half(acc[4*q+2]), __float2half(acc[4*q+3]));
        op[q] = make_uint2(__builtin_bit_cast(unsigned, lo),
                           __builtin_bit_cast(unsigned, hi));
    }
}

// ---------------------------------------------------------------------------
// out[e] = dot(z[src[e]], z[dst[e]]) over 32 features; z is FP16.
// Row = 32 halves = 64B = 4 x uint4.
// ---------------------------------------------------------------------------
__global__ void k_dot(const __half* __restrict__ z, const int* __restrict__ src,
                      const int* __restrict__ dst, float* __restrict__ out, int EL)
{
    int e = blockIdx.x * 256 + threadIdx.x;
    if (e >= EL) return;
    const uint4* a = reinterpret_cast<const uint4*>(z + (size_t)src[e] * 32);
    const uint4* b = reinterpret_cast<const uint4*>(z + (size_t)dst[e] * 32);
    float s = 0.0f;
#pragma unroll
    for (int q = 0; q < 4; q++) {
        uint4 av = a[q], bv = b[q];
        unsigned au[4] = {av.x, av.y, av.z, av.w};
        unsigned bu[4] = {bv.x, bv.y, bv.z, bv.w};
#pragma unroll
        for (int p = 0; p < 4; p++) {
            float2 fa = __half22float2(__builtin_bit_cast(__half2, au[p]));
            float2 fb = __half22float2(__builtin_bit_cast(__half2, bu[p]));
            s = fmaf(fa.x, fb.x, s);
            s = fmaf(fa.y, fb.y, s);
        }
    }
    out[e] = s;
}

extern "C" void kernel_launch(void* const* d_in, const int* in_sizes, int n_in,
                              void* d_out, int out_size, void* d_ws, size_t ws_size,
                              hipStream_t stream)
{
    const float* x   = (const float*)d_in[0];
    const int*   ei  = (const int*)d_in[1];
    const int*   eli = (const int*)d_in[2];
    const float* Wih = (const float*)d_in[3];
    // d_in[4] = W_hh: mathematically dead (h0 = c0 = 0)
    const float* bih = (const float*)d_in[5];
    const float* bhh = (const float*)d_in[6];
    const float* W1  = (const float*)d_in[7];
    const float* b1  = (const float*)d_in[8];
    const float* W2  = (const float*)d_in[9];
    const float* b2  = (const float*)d_in[10];

    int n  = in_sizes[0] / 64;
    int E  = in_sizes[1] / 2;
    int EL = in_sizes[2] / 2;

    const int* row  = ei;          // source
    const int* col  = ei + E;      // destination
    const int* lsrc = eli;
    const int* ldst = eli + EL;
    float* out = (float*)d_out;

    // Workspace layout (4B units), liveness-aliased:
    //   bufA [n*64 f32 region]: ebuf int2[E] (bin..fill3), hw1 FP16
    //                           (lstm..pull64), hw2 FP16 (mm2..pull32)
    //   bufB [n*64 f32 region]: h1 f32 (pull64..mm2), z FP16 (pull32..dot)
    //   dinv [n] | off [n+1] | deg [n] | cur [n] | bsum [1024] | bscan [1024]
    //   nbr [E] | WT [64*192] | gcur [nbuck*16]   (~59.4 MB total)
    float*  bufA  = (float*)d_ws;
    float*  bufB  = bufA + (size_t)n * 64;
    float*  dinv  = bufB + (size_t)n * 64;
    int*    off   = (int*)(dinv + n);
    int*    deg   = off + (n + 1);
    int*    cur   = deg + n;
    int*    bsum  = cur + n;
    int*    bscan = bsum + 1024;
    int*    nbr   = bscan + 1024;
    float*  WT    = (float*)(nbr + E);
    int*    gcur  = (int*)(WT + 64 * 192);
    int2*   ebuf  = (int2*)bufA;    // dead until k_lstm_mm1 writes hw1
    __half* hw1h  = (__half*)bufA;
    __half* hw2h  = (__half*)bufA;  // hw1 dead by the time mm2 writes
    float*  h1    = bufB;
    __half* zh    = (__half*)bufB;  // h1 dead by the time pull32 writes

    int nb    = (n + 255) / 256;   // 391; k_scan2 handles nb<=1024
    int nbuck = (n + (1 << NBSH) - 1) >> NBSH;   // 196 buckets (<=256)
    dim3 blk(256);

    // --- weight transpose for LSTM phase-1 (tiny, one-time per call) ---
    k_tr<<<dim3((64 * 192 + 255) / 256), blk, 0, stream>>>(Wih, WT);

    // --- CSR build: counting sort by destination, LDS-binned two-pass fill ---
    hipMemsetAsync(deg, 0, (size_t)n * sizeof(int), stream);
    k_deg  <<<dim3((E + 255) / 256), blk, 0, stream>>>(col, deg, E);
    k_dinv <<<dim3(nb), blk, 0, stream>>>(deg, dinv, n);
    k_scan1<<<dim3(nb), blk, 0, stream>>>(deg, off, bsum, n);
    k_scan2<<<dim3(1), dim3(1024), 0, stream>>>(bsum, bscan, nb);
    k_scan3<<<dim3(nb), blk, 0, stream>>>(off, bscan, deg, cur, n);
    k_gcur <<<dim3((nbuck + 255) / 256), blk, 0, stream>>>(off, gcur, nbuck, n);
    k_bin  <<<dim3((E + CH - 1) / CH), blk, 0, stream>>>(row, col, gcur, ebuf, E, nbuck);
    k_fill3<<<dim3(nbuck), dim3(512), 0, stream>>>(ebuf, off, cur, nbr, n);

    // --- LSTM + first matmul: hw1 (fp16) -> bufA (ebuf dead) ---
    {
        int blocks = (n + 31) / 32;
        k_lstm_mm1<<<dim3(blocks), blk, 0, stream>>>(x, WT, bih, bhh, W1, hw1h, n);
    }

    // --- GCN1: pull + fused epilogue (relu) : h1 (f32) -> bufB ---
    {
        int blocks = (int)(((size_t)n * 64 + 255) / 256);
        k_pull64<<<dim3(blocks), blk, 0, stream>>>(hw1h, off, nbr, dinv, b1, h1, n);
    }

    // --- second matmul: hw2 (fp16) -> bufA (hw1 dead) ---
    k_mm2<<<dim3((n + 127) / 128), dim3(128), 0, stream>>>(h1, W2, hw2h, n);

    // --- GCN2: pull + fused epilogue : z (fp16) -> bufB (h1 dead) ---
    {
        int blocks = (int)(((size_t)n * 64 + 255) / 256);
        k_pull32<<<dim3(blocks), blk, 0, stream>>>(hw2h, off, nbr, dinv, b2, zh, n);
    }

    // --- edge dot products ---
    k_dot<<<dim3((EL + 255) / 256), blk, 0, stream>>>(zh, lsrc, ldst, out, EL);
}

// Round 14
// 261.651 us; speedup vs baseline: 2.0062x; 1.3153x over previous
//
#include <hip/hip_runtime.h>
#include <hip/hip_bf16.h>
#include <hip/hip_fp16.h>
#include <math.h>

#define NBSH 9        // 512 destination cols per bucket
#define CH   4096     // edges staged per k_bin block

// Fast device transcendentals: native v_exp_f32 + v_rcp_f32.
__device__ __forceinline__ float fast_sigmoid(float x) {
    float t = __expf(x);
    return 1.0f - __builtin_amdgcn_rcpf(1.0f + t);
}
__device__ __forceinline__ float fast_tanh(float x) {
    float t = __expf(2.0f * x);
    return 1.0f - 2.0f * __builtin_amdgcn_rcpf(1.0f + t);
}

__device__ __forceinline__ float readlane_f(float v, int l) {
    return __builtin_bit_cast(float,
        __builtin_amdgcn_readlane(__builtin_bit_cast(int, v), l));
}

// ---------------------------------------------------------------------------
// Bucket histogram: per-block LDS histogram of col>>NBSH, then ONE global
// atomic per (bucket, block) -> 77K atomics total vs k_deg's 1.6M scattered
// (which cost 65us / 50MB write-amp). bdeg must be zeroed first.
// ---------------------------------------------------------------------------
__global__ __launch_bounds__(256) void k_bhist(const int* __restrict__ col,
        int* __restrict__ bdeg, int E, int nbuck) {
    __shared__ int cnt[256];
    cnt[threadIdx.x] = 0;
    __syncthreads();
    int base = blockIdx.x * CH;
    int end  = base + CH; if (end > E) end = E;
    for (int t = base + (int)threadIdx.x; t < end; t += 256)
        atomicAdd(&cnt[col[t] >> NBSH], 1);
    __syncthreads();
    if ((int)threadIdx.x < nbuck && cnt[threadIdx.x] > 0)
        atomicAdd(&bdeg[threadIdx.x], cnt[threadIdx.x]);
}

// ---------------------------------------------------------------------------
// Single-block scan of bucket sizes -> boff[0..nbuck]; also inits the padded
// k_bin cursors (gcur[b*16] = boff[b]). Replaces the old n-wide scan chain.
// ---------------------------------------------------------------------------
__global__ __launch_bounds__(256) void k_bscan(const int* __restrict__ bdeg,
        int* __restrict__ boff, int* __restrict__ gcur, int nbuck, int E) {
    __shared__ int tmp[256];
    int tid = threadIdx.x;
    int v = (tid < nbuck) ? bdeg[tid] : 0;
    tmp[tid] = v;
    __syncthreads();
#pragma unroll
    for (int s = 1; s < 256; s <<= 1) {
        int t = (tid >= s) ? tmp[tid - s] : 0;
        __syncthreads();
        tmp[tid] += t;
        __syncthreads();
    }
    if (tid < nbuck) {
        int o = tmp[tid] - v;
        boff[tid] = o;
        gcur[tid * 16] = o;
    }
    if (tid == 0) boff[nbuck] = E;
}

// ---------------------------------------------------------------------------
// Pass 1: LDS-binned partition of edges into 512-col buckets (proven in r13).
// Per block: histogram 4096 edges into LDS counters, block-scan, ONE padded
// global reservation per (bucket, block), sort into LDS staging, copy out as
// coalesced per-bucket runs.
// ---------------------------------------------------------------------------
__global__ __launch_bounds__(256) void k_bin(
    const int* __restrict__ row, const int* __restrict__ col,
    int* __restrict__ gcur, int2* __restrict__ ebuf, int E, int nbuck)
{
    __shared__ int  cnt[256], lofs[256], gbase[256], cur2[256];
    __shared__ int2 stage[CH];
    int tid  = threadIdx.x;
    int base = blockIdx.x * CH;
    int ned  = E - base; if (ned > CH) ned = CH;

    cnt[tid] = 0;
    __syncthreads();

    int r[16], c[16], b[16];
#pragma unroll
    for (int i = 0; i < 16; i++) {
        int idx = i * 256 + tid;
        if (idx < ned) {
            r[i] = row[base + idx];
            c[i] = col[base + idx];
            b[i] = c[i] >> NBSH;
            atomicAdd(&cnt[b[i]], 1);
        } else { r[i] = 0; c[i] = 0; b[i] = -1; }
    }
    __syncthreads();

    int v = cnt[tid];
    lofs[tid] = v;
    __syncthreads();
#pragma unroll
    for (int s = 1; s < 256; s <<= 1) {
        int t = (tid >= s) ? lofs[tid - s] : 0;
        __syncthreads();
        lofs[tid] += t;
        __syncthreads();
    }
    int excl = lofs[tid] - v;
    __syncthreads();
    lofs[tid] = excl;
    cur2[tid] = excl;
    if (tid < nbuck && v > 0)
        gbase[tid] = atomicAdd(&gcur[tid * 16], v);   // padded: no hot line
    __syncthreads();

#pragma unroll
    for (int i = 0; i < 16; i++) {
        if (b[i] >= 0) {
            int p = atomicAdd(&cur2[b[i]], 1);
            stage[p] = make_int2(r[i], c[i]);
        }
    }
    __syncthreads();

    for (int i = tid; i < ned; i += 256) {
        int2 rc = stage[i];
        int bb = rc.y >> NBSH;
        ebuf[gbase[bb] + (i - lofs[bb])] = rc;
    }
}

// ---------------------------------------------------------------------------
// Pass 2: per-bucket CSR finalize. One block per bucket:
//   LDS histogram of local cols -> LDS scan -> write off + dinv directly,
//   then scatter nbr with LDS cursors (ZERO global atomics; nbr writes land
//   in the bucket's contiguous region during one block's lifetime).
// Replaces k_deg + k_dinv + k_scan1/2/3 + k_fill3.
// ---------------------------------------------------------------------------
__global__ __launch_bounds__(512) void k_csr(
    const int2* __restrict__ ebuf, const int* __restrict__ boff,
    int* __restrict__ off, float* __restrict__ dinv,
    int* __restrict__ nbr, int n, int nbuck, int E)
{
    __shared__ int cnt[512], lofs[512];
    int b   = blockIdx.x;
    int tid = threadIdx.x;
    int c0  = b << NBSH;
    int nn  = n - c0; if (nn > 512) nn = 512; if (nn < 0) nn = 0;
    int lo  = boff[b], hi = boff[b + 1];

    cnt[tid] = 0;
    __syncthreads();
    for (int t = lo + tid; t < hi; t += 512)
        atomicAdd(&cnt[ebuf[t].y & 511], 1);
    __syncthreads();

    int v = cnt[tid];
    lofs[tid] = v;
    __syncthreads();
#pragma unroll
    for (int s = 1; s < 512; s <<= 1) {
        int t = (tid >= s) ? lofs[tid - s] : 0;
        __syncthreads();
        lofs[tid] += t;
        __syncthreads();
    }
    int excl = lofs[tid] - v;
    __syncthreads();

    if (tid < nn) {
        off[c0 + tid]  = lo + excl;
        dinv[c0 + tid] = 1.0f / sqrtf((float)(v + 1));
    }
    if (b == nbuck - 1 && tid == 0) off[n] = E;

    cnt[tid] = excl;                       // reuse as LDS cursors
    __syncthreads();
    for (int t = lo + tid; t < hi; t += 512) {
        int2 rc = ebuf[t];
        int p = atomicAdd(&cnt[rc.y & 511], 1);
        nbr[lo + p] = rc.x;
    }
}

// ---------------------------------------------------------------------------
// One-time weight transpose for coalesced phase-1 loads:
//   WT[k*192 + g*64 + j] = Wih[row(g,j)*64 + k]
// ---------------------------------------------------------------------------
__global__ void k_tr(const float* __restrict__ Wih, float* __restrict__ WT) {
    int t = blockIdx.x * 256 + threadIdx.x;
    if (t >= 64 * 192) return;
    int k = t / 192, c = t % 192;
    int g = c >> 6, j = c & 63;
    int rowb = (g == 0) ? j : (g == 1) ? (128 + j) : (192 + j);
    WT[t] = Wih[rowb * 64 + k];
}

// ---------------------------------------------------------------------------
// Fused LSTM step + (h @ W1), GEMV-broadcast form.
// Wave owns 8 nodes; lane = output column. hw1 stored FP16.
// ---------------------------------------------------------------------------
__global__ __launch_bounds__(256) void k_lstm_mm1(
    const float* __restrict__ x, const float* __restrict__ WT,
    const float* __restrict__ bih, const float* __restrict__ bhh,
    const float* __restrict__ W1, __half* __restrict__ hw1, int n)
{
    __shared__ float4 xs[4][128];          // per-wave 2KB: [k][8 nodes] as 2xfloat4
    int wv   = threadIdx.x >> 6;
    int lane = threadIdx.x & 63;
    int nbase = (blockIdx.x * 4 + wv) * 8;
    if (nbase >= n) return;                // wave-uniform

    int ni[8];
#pragma unroll
    for (int m = 0; m < 8; m++) {
        int t = nbase + m;
        ni[m] = (t < n) ? t : (n - 1);     // clamp for safe loads
    }

    float xv[8];
#pragma unroll
    for (int m = 0; m < 8; m++) xv[m] = x[(size_t)ni[m] * 64 + lane];
    xs[wv][lane * 2 + 0] = make_float4(xv[0], xv[1], xv[2], xv[3]);
    xs[wv][lane * 2 + 1] = make_float4(xv[4], xv[5], xv[6], xv[7]);

    float gi[8], gg[8], go[8];
#pragma unroll
    for (int m = 0; m < 8; m++) { gi[m] = 0.f; gg[m] = 0.f; go[m] = 0.f; }

#pragma unroll 8
    for (int k = 0; k < 64; k++) {
        float4 xa = xs[wv][k * 2 + 0];     // broadcast
        float4 xb = xs[wv][k * 2 + 1];
        float wi = WT[k * 192 + lane];     // coalesced 256B
        float wg = WT[k * 192 + 64 + lane];
        float wo = WT[k * 192 + 128 + lane];
        gi[0] = fmaf(xa.x, wi, gi[0]); gi[1] = fmaf(xa.y, wi, gi[1]);
        gi[2] = fmaf(xa.z, wi, gi[2]); gi[3] = fmaf(xa.w, wi, gi[3]);
        gi[4] = fmaf(xb.x, wi, gi[4]); gi[5] = fmaf(xb.y, wi, gi[5]);
        gi[6] = fmaf(xb.z, wi, gi[6]); gi[7] = fmaf(xb.w, wi, gi[7]);
        gg[0] = fmaf(xa.x, wg, gg[0]); gg[1] = fmaf(xa.y, wg, gg[1]);
        gg[2] = fmaf(xa.z, wg, gg[2]); gg[3] = fmaf(xa.w, wg, gg[3]);
        gg[4] = fmaf(xb.x, wg, gg[4]); gg[5] = fmaf(xb.y, wg, gg[5]);
        gg[6] = fmaf(xb.z, wg, gg[6]); gg[7] = fmaf(xb.w, wg, gg[7]);
        go[0] = fmaf(xa.x, wo, go[0]); go[1] = fmaf(xa.y, wo, go[1]);
        go[2] = fmaf(xa.z, wo, go[2]); go[3] = fmaf(xa.w, wo, go[3]);
        go[4] = fmaf(xb.x, wo, go[4]); go[5] = fmaf(xb.y, wo, go[5]);
        go[6] = fmaf(xb.z, wo, go[6]); go[7] = fmaf(xb.w, wo, go[7]);
    }

    float bi = bih[lane]       + bhh[lane];
    float bg = bih[128 + lane] + bhh[128 + lane];
    float bo = bih[192 + lane] + bhh[192 + lane];

    float h[8];
#pragma unroll
    for (int m = 0; m < 8; m++) {
        float c = fast_sigmoid(gi[m] + bi) * fast_tanh(gg[m] + bg);
        h[m] = fast_sigmoid(go[m] + bo) * fast_tanh(c);
    }

    // reuse the same per-wave LDS region for h (same-wave DS order is safe)
    xs[wv][lane * 2 + 0] = make_float4(h[0], h[1], h[2], h[3]);
    xs[wv][lane * 2 + 1] = make_float4(h[4], h[5], h[6], h[7]);

    float acc[8];
#pragma unroll
    for (int m = 0; m < 8; m++) acc[m] = 0.f;

#pragma unroll 8
    for (int j = 0; j < 64; j++) {
        float4 ha = xs[wv][j * 2 + 0];     // broadcast
        float4 hb = xs[wv][j * 2 + 1];
        float w = W1[j * 64 + lane];       // coalesced 256B
        acc[0] = fmaf(ha.x, w, acc[0]); acc[1] = fmaf(ha.y, w, acc[1]);
        acc[2] = fmaf(ha.z, w, acc[2]); acc[3] = fmaf(ha.w, w, acc[3]);
        acc[4] = fmaf(hb.x, w, acc[4]); acc[5] = fmaf(hb.y, w, acc[5]);
        acc[6] = fmaf(hb.z, w, acc[6]); acc[7] = fmaf(hb.w, w, acc[7]);
    }

#pragma unroll
    for (int m = 0; m < 8; m++)
        if (nbase + m < n)
            hw1[(size_t)(nbase + m) * 64 + lane] = __float2half(acc[m]);
}

// ---------------------------------------------------------------------------
// Pull aggregation, F=64. One wave per node, lane = feature. FP16 source
// rows (128B/row), f32 accumulation. Chunked readlane: 4 loads in flight.
// Fused epilogue 1: h1 = relu(agg*dc + hw1[node]*dc^2 + b1)   (h1 stays f32)
// ---------------------------------------------------------------------------
__global__ __launch_bounds__(256) void k_pull64(
    const __half* __restrict__ hw, const int* __restrict__ off,
    const int* __restrict__ nbr, const float* __restrict__ dinv,
    const float* __restrict__ b1, float* __restrict__ h1, int n)
{
    int node = (blockIdx.x * 256 + threadIdx.x) >> 6;
    int lane = threadIdx.x & 63;
    if (node >= n) return;
    int s = off[node], e = off[node + 1];

    float a0 = 0.f, a1 = 0.f, a2 = 0.f, a3 = 0.f;
    for (int base = s; base < e; base += 64) {
        int t = base + lane;
        int idx = 0; float wv = 0.f;
        if (t < e) { idx = nbr[t]; wv = dinv[idx]; }
        int cnt = e - base; if (cnt > 64) cnt = 64;

        int k = 0;
        for (; k + 4 <= cnt; k += 4) {
            int r0 = __builtin_amdgcn_readlane(idx, k + 0);
            int r1 = __builtin_amdgcn_readlane(idx, k + 1);
            int r2 = __builtin_amdgcn_readlane(idx, k + 2);
            int r3 = __builtin_amdgcn_readlane(idx, k + 3);
            float w0 = readlane_f(wv, k + 0);
            float w1 = readlane_f(wv, k + 1);
            float w2 = readlane_f(wv, k + 2);
            float w3 = readlane_f(wv, k + 3);
            float v0 = __half2float(hw[(size_t)r0 * 64 + lane]);
            float v1 = __half2float(hw[(size_t)r1 * 64 + lane]);
            float v2 = __half2float(hw[(size_t)r2 * 64 + lane]);
            float v3 = __half2float(hw[(size_t)r3 * 64 + lane]);
            a0 = fmaf(v0, w0, a0);
            a1 = fmaf(v1, w1, a1);
            a2 = fmaf(v2, w2, a2);
            a3 = fmaf(v3, w3, a3);
        }
        for (; k < cnt; k++) {
            int r = __builtin_amdgcn_readlane(idx, k);
            float w = readlane_f(wv, k);
            a0 = fmaf(__half2float(hw[(size_t)r * 64 + lane]), w, a0);
        }
    }

    float dc   = dinv[node];
    float self = __half2float(hw[(size_t)node * 64 + lane]);
    float v = ((a0 + a1) + (a2 + a3)) * dc + self * dc * dc + b1[lane];
    h1[(size_t)node * 64 + lane] = fmaxf(v, 0.0f);
}

// ---------------------------------------------------------------------------
// Pull aggregation, F=32. FP16 source rows (64B/row), f32 accumulation,
// FP16 z output. Halves on alternate neighbors.
// Fused epilogue 2: z = agg*dc + hw2*dc^2 + b2  (no relu)
// ---------------------------------------------------------------------------
__global__ __launch_bounds__(256) void k_pull32(
    const __half* __restrict__ hw, const int* __restrict__ off,
    const int* __restrict__ nbr, const float* __restrict__ dinv,
    const float* __restrict__ b2, __half* __restrict__ z, int n)
{
    int node = (blockIdx.x * 256 + threadIdx.x) >> 6;
    int lane = threadIdx.x & 63;
    int feat = lane & 31;
    int half = lane >> 5;
    if (node >= n) return;
    int s = off[node], e = off[node + 1];

    float a0 = 0.f, a1 = 0.f;
    for (int base = s; base < e; base += 64) {
        int t = base + lane;
        int idx = 0; float wv = 0.f;
        if (t < e) { idx = nbr[t]; wv = dinv[idx]; }
        int cnt = e - base; if (cnt > 64) cnt = 64;
        int cntp = (cnt + 1) & ~1;         // pad to even (pad lanes are zero)

        int j = half;
        for (; j + 2 < cntp; j += 4) {     // 2 neighbors per half per iter
            int   ra = __shfl(idx, j, 64);
            int   rb = __shfl(idx, j + 2, 64);
            float wa = __shfl(wv, j, 64);
            float wb = __shfl(wv, j + 2, 64);
            float va = __half2float(hw[(size_t)ra * 32 + feat]);
            float vb = __half2float(hw[(size_t)rb * 32 + feat]);
            a0 = fmaf(va, wa, a0);
            a1 = fmaf(vb, wb, a1);
        }
        for (; j < cntp; j += 2) {
            int   r = __shfl(idx, j, 64);
            float w = __shfl(wv, j, 64);
            a0 = fmaf(__half2float(hw[(size_t)r * 32 + feat]), w, a0);
        }
    }

    float acc = a0 + a1;
    acc += __shfl_xor(acc, 32, 64);        // combine even/odd halves
    float dc = dinv[node];
    float v = acc * dc + __half2float(hw[(size_t)node * 32 + feat]) * dc * dc + b2[feat];
    if (half == 0) z[(size_t)node * 32 + feat] = __float2half(v);
}

// ---------------------------------------------------------------------------
// hw2 = h1 @ W2  ([n,64] x [64,32]). f32 compute, FP16 output rows.
// ---------------------------------------------------------------------------
__global__ __launch_bounds__(128) void k_mm2(
    const float* __restrict__ h1, const float* __restrict__ W2,
    __half* __restrict__ hw2, int n)
{
    __shared__ float tile[128 * 65];
    int base  = blockIdx.x * 128;
    int nrows = n - base; if (nrows > 128) nrows = 128;

    for (int idx = threadIdx.x; idx < nrows * 64; idx += 128) {
        int r = idx >> 6, c = idx & 63;
        tile[r * 65 + c] = h1[(size_t)base * 64 + idx];
    }
    __syncthreads();

    int node = base + threadIdx.x;
    if (node >= n) return;

    const float* hrow = &tile[threadIdx.x * 65];
    float acc[32];
#pragma unroll
    for (int s = 0; s < 32; s++) acc[s] = 0.0f;

    for (int k = 0; k < 64; k++) {
        float hk = hrow[k];
        const float* w = W2 + (size_t)k * 32;
#pragma unroll
        for (int s = 0; s < 32; s++) acc[s] = fmaf(hk, w[s], acc[s]);
    }

    uint2* op = reinterpret_cast<uint2*>(hw2 + (size_t)node * 32);
#pragma unroll
    for (int q = 0; q < 8; q++) {
        __half2 lo(__float2half(acc[4*q+0]), __float2half(acc[4*q+1]));
        __half2 hi(__float2half(acc[4*q+2]), __float2half(acc[4*q+3]));
        op[q] = make_uint2(__builtin_bit_cast(unsigned, lo),
                           __builtin_bit_cast(unsigned, hi));
    }
}

// ---------------------------------------------------------------------------
// out[e] = dot(z[src[e]], z[dst[e]]) over 32 features; z is FP16.
// Row = 32 halves = 64B = 4 x uint4.
// ---------------------------------------------------------------------------
__global__ void k_dot(const __half* __restrict__ z, const int* __restrict__ src,
                      const int* __restrict__ dst, float* __restrict__ out, int EL)
{
    int e = blockIdx.x * 256 + threadIdx.x;
    if (e >= EL) return;
    const uint4* a = reinterpret_cast<const uint4*>(z + (size_t)src[e] * 32);
    const uint4* b = reinterpret_cast<const uint4*>(z + (size_t)dst[e] * 32);
    float s = 0.0f;
#pragma unroll
    for (int q = 0; q < 4; q++) {
        uint4 av = a[q], bv = b[q];
        unsigned au[4] = {av.x, av.y, av.z, av.w};
        unsigned bu[4] = {bv.x, bv.y, bv.z, bv.w};
#pragma unroll
        for (int p = 0; p < 4; p++) {
            float2 fa = __half22float2(__builtin_bit_cast(__half2, au[p]));
            float2 fb = __half22float2(__builtin_bit_cast(__half2, bu[p]));
            s = fmaf(fa.x, fb.x, s);
            s = fmaf(fa.y, fb.y, s);
        }
    }
    out[e] = s;
}

extern "C" void kernel_launch(void* const* d_in, const int* in_sizes, int n_in,
                              void* d_out, int out_size, void* d_ws, size_t ws_size,
                              hipStream_t stream)
{
    const float* x   = (const float*)d_in[0];
    const int*   ei  = (const int*)d_in[1];
    const int*   eli = (const int*)d_in[2];
    const float* Wih = (const float*)d_in[3];
    // d_in[4] = W_hh: mathematically dead (h0 = c0 = 0)
    const float* bih = (const float*)d_in[5];
    const float* bhh = (const float*)d_in[6];
    const float* W1  = (const float*)d_in[7];
    const float* b1  = (const float*)d_in[8];
    const float* W2  = (const float*)d_in[9];
    const float* b2  = (const float*)d_in[10];

    int n  = in_sizes[0] / 64;
    int E  = in_sizes[1] / 2;
    int EL = in_sizes[2] / 2;

    const int* row  = ei;          // source
    const int* col  = ei + E;      // destination
    const int* lsrc = eli;
    const int* ldst = eli + EL;
    float* out = (float*)d_out;

    // Workspace layout (4B units), liveness-aliased:
    //   bufA [n*64 f32 region]: ebuf int2[E] (bin..csr), hw1 FP16
    //                           (lstm..pull64), hw2 FP16 (mm2..pull32)
    //   bufB [n*64 f32 region]: h1 f32 (pull64..mm2), z FP16 (pull32..dot)
    //   dinv [n] | off [n+1] | nbr [E] | WT [64*192]
    //   bdeg [256] | boff [257] | gcur [nbuck*16]
    float*  bufA  = (float*)d_ws;
    float*  bufB  = bufA + (size_t)n * 64;
    float*  dinv  = bufB + (size_t)n * 64;
    int*    off   = (int*)(dinv + n);
    int*    nbr   = off + (n + 1);
    float*  WT    = (float*)(nbr + E);
    int*    bdeg  = (int*)(WT + 64 * 192);
    int*    boff  = bdeg + 256;
    int*    gcur  = boff + 257;
    int2*   ebuf  = (int2*)bufA;    // dead until k_lstm_mm1 writes hw1
    __half* hw1h  = (__half*)bufA;
    __half* hw2h  = (__half*)bufA;  // hw1 dead by the time mm2 writes
    float*  h1    = bufB;
    __half* zh    = (__half*)bufB;  // h1 dead by the time pull32 writes

    int nbuck   = (n + (1 << NBSH) - 1) >> NBSH;   // 196 buckets (<=256)
    int eblocks = (E + CH - 1) / CH;               // 391
    dim3 blk(256);

    // --- weight transpose for LSTM phase-1 (tiny, one-time per call) ---
    k_tr<<<dim3((64 * 192 + 255) / 256), blk, 0, stream>>>(Wih, WT);

    // --- CSR build: bucket histogram -> scan -> binned partition -> per-
    //     bucket finalize (off/dinv/nbr; LDS atomics only) ---
    hipMemsetAsync(bdeg, 0, 256 * sizeof(int), stream);
    k_bhist<<<dim3(eblocks), blk, 0, stream>>>(col, bdeg, E, nbuck);
    k_bscan<<<dim3(1), blk, 0, stream>>>(bdeg, boff, gcur, nbuck, E);
    k_bin  <<<dim3(eblocks), blk, 0, stream>>>(row, col, gcur, ebuf, E, nbuck);
    k_csr  <<<dim3(nbuck), dim3(512), 0, stream>>>(ebuf, boff, off, dinv, nbr, n, nbuck, E);

    // --- LSTM + first matmul: hw1 (fp16) -> bufA (ebuf dead) ---
    {
        int blocks = (n + 31) / 32;
        k_lstm_mm1<<<dim3(blocks), blk, 0, stream>>>(x, WT, bih, bhh, W1, hw1h, n);
    }

    // --- GCN1: pull + fused epilogue (relu) : h1 (f32) -> bufB ---
    {
        int blocks = (int)(((size_t)n * 64 + 255) / 256);
        k_pull64<<<dim3(blocks), blk, 0, stream>>>(hw1h, off, nbr, dinv, b1, h1, n);
    }

    // --- second matmul: hw2 (fp16) -> bufA (hw1 dead) ---
    k_mm2<<<dim3((n + 127) / 128), dim3(128), 0, stream>>>(h1, W2, hw2h, n);

    // --- GCN2: pull + fused epilogue : z (fp16) -> bufB (h1 dead) ---
    {
        int blocks = (int)(((size_t)n * 64 + 255) / 256);
        k_pull32<<<dim3(blocks), blk, 0, stream>>>(hw2h, off, nbr, dinv, b2, zh, n);
    }

    // --- edge dot products ---
    k_dot<<<dim3((EL + 255) / 256), blk, 0, stream>>>(zh, lsrc, ldst, out, EL);
}

// Round 15
// 249.737 us; speedup vs baseline: 2.1020x; 1.0477x over previous
//
#include <hip/hip_runtime.h>
#include <hip/hip_bf16.h>
#include <hip/hip_fp16.h>
#include <math.h>

#define NBSH 9        // 512 destination cols per bucket
#define CH   4096     // edges staged per k_bin block

typedef _Float16 h2v __attribute__((ext_vector_type(2)));

__device__ __forceinline__ float fdot2_(unsigned a, unsigned b, float c) {
    return __builtin_amdgcn_fdot2(__builtin_bit_cast(h2v, a),
                                  __builtin_bit_cast(h2v, b), c, false);
}

// Fast device transcendentals: native v_exp_f32 + v_rcp_f32.
__device__ __forceinline__ float fast_sigmoid(float x) {
    float t = __expf(x);
    return 1.0f - __builtin_amdgcn_rcpf(1.0f + t);
}
__device__ __forceinline__ float fast_tanh(float x) {
    float t = __expf(2.0f * x);
    return 1.0f - 2.0f * __builtin_amdgcn_rcpf(1.0f + t);
}

__device__ __forceinline__ float readlane_f(float v, int l) {
    return __builtin_bit_cast(float,
        __builtin_amdgcn_readlane(__builtin_bit_cast(int, v), l));
}

// ---------------------------------------------------------------------------
// Bucket histogram: per-block LDS histogram of col>>NBSH, then ONE global
// atomic per (bucket, block). bdeg must be zeroed first.
// ---------------------------------------------------------------------------
__global__ __launch_bounds__(256) void k_bhist(const int* __restrict__ col,
        int* __restrict__ bdeg, int E, int nbuck) {
    __shared__ int cnt[256];
    cnt[threadIdx.x] = 0;
    __syncthreads();
    int base = blockIdx.x * CH;
    int end  = base + CH; if (end > E) end = E;
    for (int t = base + (int)threadIdx.x; t < end; t += 256)
        atomicAdd(&cnt[col[t] >> NBSH], 1);
    __syncthreads();
    if ((int)threadIdx.x < nbuck && cnt[threadIdx.x] > 0)
        atomicAdd(&bdeg[threadIdx.x], cnt[threadIdx.x]);
}

// ---------------------------------------------------------------------------
// Single-block scan of bucket sizes -> boff[0..nbuck]; inits padded k_bin
// cursors (gcur[b*16] = boff[b]).
// ---------------------------------------------------------------------------
__global__ __launch_bounds__(256) void k_bscan(const int* __restrict__ bdeg,
        int* __restrict__ boff, int* __restrict__ gcur, int nbuck, int E) {
    __shared__ int tmp[256];
    int tid = threadIdx.x;
    int v = (tid < nbuck) ? bdeg[tid] : 0;
    tmp[tid] = v;
    __syncthreads();
#pragma unroll
    for (int s = 1; s < 256; s <<= 1) {
        int t = (tid >= s) ? tmp[tid - s] : 0;
        __syncthreads();
        tmp[tid] += t;
        __syncthreads();
    }
    if (tid < nbuck) {
        int o = tmp[tid] - v;
        boff[tid] = o;
        gcur[tid * 16] = o;
    }
    if (tid == 0) boff[nbuck] = E;
}

// ---------------------------------------------------------------------------
// Pass 1: LDS-binned partition of edges into 512-col buckets (proven r13/14).
// ---------------------------------------------------------------------------
__global__ __launch_bounds__(256) void k_bin(
    const int* __restrict__ row, const int* __restrict__ col,
    int* __restrict__ gcur, int2* __restrict__ ebuf, int E, int nbuck)
{
    __shared__ int  cnt[256], lofs[256], gbase[256], cur2[256];
    __shared__ int2 stage[CH];
    int tid  = threadIdx.x;
    int base = blockIdx.x * CH;
    int ned  = E - base; if (ned > CH) ned = CH;

    cnt[tid] = 0;
    __syncthreads();

    int r[16], c[16], b[16];
#pragma unroll
    for (int i = 0; i < 16; i++) {
        int idx = i * 256 + tid;
        if (idx < ned) {
            r[i] = row[base + idx];
            c[i] = col[base + idx];
            b[i] = c[i] >> NBSH;
            atomicAdd(&cnt[b[i]], 1);
        } else { r[i] = 0; c[i] = 0; b[i] = -1; }
    }
    __syncthreads();

    int v = cnt[tid];
    lofs[tid] = v;
    __syncthreads();
#pragma unroll
    for (int s = 1; s < 256; s <<= 1) {
        int t = (tid >= s) ? lofs[tid - s] : 0;
        __syncthreads();
        lofs[tid] += t;
        __syncthreads();
    }
    int excl = lofs[tid] - v;
    __syncthreads();
    lofs[tid] = excl;
    cur2[tid] = excl;
    if (tid < nbuck && v > 0)
        gbase[tid] = atomicAdd(&gcur[tid * 16], v);   // padded: no hot line
    __syncthreads();

#pragma unroll
    for (int i = 0; i < 16; i++) {
        if (b[i] >= 0) {
            int p = atomicAdd(&cur2[b[i]], 1);
            stage[p] = make_int2(r[i], c[i]);
        }
    }
    __syncthreads();

    for (int i = tid; i < ned; i += 256) {
        int2 rc = stage[i];
        int bb = rc.y >> NBSH;
        ebuf[gbase[bb] + (i - lofs[bb])] = rc;
    }
}

// ---------------------------------------------------------------------------
// Pass 2: per-bucket CSR finalize (off/dinv/nbr; LDS atomics only).
// ---------------------------------------------------------------------------
__global__ __launch_bounds__(512) void k_csr(
    const int2* __restrict__ ebuf, const int* __restrict__ boff,
    int* __restrict__ off, float* __restrict__ dinv,
    int* __restrict__ nbr, int n, int nbuck, int E)
{
    __shared__ int cnt[512], lofs[512];
    int b   = blockIdx.x;
    int tid = threadIdx.x;
    int c0  = b << NBSH;
    int nn  = n - c0; if (nn > 512) nn = 512; if (nn < 0) nn = 0;
    int lo  = boff[b], hi = boff[b + 1];

    cnt[tid] = 0;
    __syncthreads();
    for (int t = lo + tid; t < hi; t += 512)
        atomicAdd(&cnt[ebuf[t].y & 511], 1);
    __syncthreads();

    int v = cnt[tid];
    lofs[tid] = v;
    __syncthreads();
#pragma unroll
    for (int s = 1; s < 512; s <<= 1) {
        int t = (tid >= s) ? lofs[tid - s] : 0;
        __syncthreads();
        lofs[tid] += t;
        __syncthreads();
    }
    int excl = lofs[tid] - v;
    __syncthreads();

    if (tid < nn) {
        off[c0 + tid]  = lo + excl;
        dinv[c0 + tid] = 1.0f / sqrtf((float)(v + 1));
    }
    if (b == nbuck - 1 && tid == 0) off[n] = E;

    cnt[tid] = excl;                       // reuse as LDS cursors
    __syncthreads();
    for (int t = lo + tid; t < hi; t += 512) {
        int2 rc = ebuf[t];
        int p = atomicAdd(&cnt[rc.y & 511], 1);
        nbr[lo + p] = rc.x;
    }
}

// ---------------------------------------------------------------------------
// One-time weight transpose + fp16 pack for fdot2:
//   WT2[kk*192 + g*64 + j] = half2(Wih[row(g,j)][2kk], Wih[row(g,j)][2kk+1])
//   W1T2[jj*64 + s]        = half2(W1[2jj][s],        W1[2jj+1][s])
// 6144 + 2048 = 8192 elements.
// ---------------------------------------------------------------------------
__global__ void k_tr(const float* __restrict__ Wih, const float* __restrict__ W1,
                     unsigned* __restrict__ WT2, unsigned* __restrict__ W1T2) {
    int t = blockIdx.x * 256 + threadIdx.x;
    if (t < 32 * 192) {
        int kk = t / 192, c = t % 192;
        int g = c >> 6, j = c & 63;
        int rowb = (g == 0) ? j : (g == 1) ? (128 + j) : (192 + j);
        h2v p;
        p.x = (_Float16)Wih[rowb * 64 + 2 * kk];
        p.y = (_Float16)Wih[rowb * 64 + 2 * kk + 1];
        WT2[t] = __builtin_bit_cast(unsigned, p);
    } else if (t < 32 * 192 + 32 * 64) {
        int u = t - 32 * 192;
        int jj = u >> 6, s = u & 63;
        h2v p;
        p.x = (_Float16)W1[(2 * jj) * 64 + s];
        p.y = (_Float16)W1[(2 * jj + 1) * 64 + s];
        W1T2[u] = __builtin_bit_cast(unsigned, p);
    }
}

// ---------------------------------------------------------------------------
// Fused LSTM step + (h @ W1), GEMV-broadcast + v_dot2_f32_f16.
// Wave owns 8 nodes; lane = output column. fp16 pair math, f32 accumulate:
// per kk (k-pair): 2 uniform b128 LDS broadcasts + 3 dword weight loads +
// 24 fdot2 (was 48 fma) -> ~55% of the instruction count of the f32 version.
// x/h staged in LDS as [kk][node][2] fp16 (1KB/wave each).
// ---------------------------------------------------------------------------
__global__ __launch_bounds__(256) void k_lstm_mm1(
    const float* __restrict__ x, const unsigned* __restrict__ WT2,
    const float* __restrict__ bih, const float* __restrict__ bhh,
    const unsigned* __restrict__ W1T2, __half* __restrict__ hw1, int n)
{
    __shared__ _Float16 xs16[4][512];      // [wv][kk*16 + m*2 + parity]
    __shared__ _Float16 hs16[4][512];
    int wv   = threadIdx.x >> 6;
    int lane = threadIdx.x & 63;
    int nbase = (blockIdx.x * 4 + wv) * 8;
    if (nbase >= n) return;                // wave-uniform

    int ni[8];
#pragma unroll
    for (int m = 0; m < 8; m++) {
        int t = nbase + m;
        ni[m] = (t < n) ? t : (n - 1);     // clamp for safe loads
    }

    // stage x rows: lane k writes its 8 nodes' values as fp16
    {
        int idx = (lane >> 1) * 16 + (lane & 1);
#pragma unroll
        for (int m = 0; m < 8; m++)
            xs16[wv][idx + m * 2] = (_Float16)x[(size_t)ni[m] * 64 + lane];
    }

    float gi[8], gg[8], go[8];
#pragma unroll
    for (int m = 0; m < 8; m++) { gi[m] = 0.f; gg[m] = 0.f; go[m] = 0.f; }

#pragma unroll 8
    for (int kk = 0; kk < 32; kk++) {
        const uint4* xrow = reinterpret_cast<const uint4*>(&xs16[wv][kk * 16]);
        uint4 A = xrow[0];                 // nodes 0..3 (half2 each), broadcast
        uint4 B = xrow[1];                 // nodes 4..7
        unsigned wi = WT2[kk * 192 + lane];        // coalesced dword
        unsigned wg = WT2[kk * 192 + 64 + lane];
        unsigned wo = WT2[kk * 192 + 128 + lane];
        gi[0] = fdot2_(A.x, wi, gi[0]); gi[1] = fdot2_(A.y, wi, gi[1]);
        gi[2] = fdot2_(A.z, wi, gi[2]); gi[3] = fdot2_(A.w, wi, gi[3]);
        gi[4] = fdot2_(B.x, wi, gi[4]); gi[5] = fdot2_(B.y, wi, gi[5]);
        gi[6] = fdot2_(B.z, wi, gi[6]); gi[7] = fdot2_(B.w, wi, gi[7]);
        gg[0] = fdot2_(A.x, wg, gg[0]); gg[1] = fdot2_(A.y, wg, gg[1]);
        gg[2] = fdot2_(A.z, wg, gg[2]); gg[3] = fdot2_(A.w, wg, gg[3]);
        gg[4] = fdot2_(B.x, wg, gg[4]); gg[5] = fdot2_(B.y, wg, gg[5]);
        gg[6] = fdot2_(B.z, wg, gg[6]); gg[7] = fdot2_(B.w, wg, gg[7]);
        go[0] = fdot2_(A.x, wo, go[0]); go[1] = fdot2_(A.y, wo, go[1]);
        go[2] = fdot2_(A.z, wo, go[2]); go[3] = fdot2_(A.w, wo, go[3]);
        go[4] = fdot2_(B.x, wo, go[4]); go[5] = fdot2_(B.y, wo, go[5]);
        go[6] = fdot2_(B.z, wo, go[6]); go[7] = fdot2_(B.w, wo, go[7]);
    }

    float bi = bih[lane]       + bhh[lane];
    float bg = bih[128 + lane] + bhh[128 + lane];
    float bo = bih[192 + lane] + bhh[192 + lane];

    // transcendentals (lane = gate index j), h -> LDS fp16
    {
        int idx = (lane >> 1) * 16 + (lane & 1);
#pragma unroll
        for (int m = 0; m < 8; m++) {
            float c = fast_sigmoid(gi[m] + bi) * fast_tanh(gg[m] + bg);
            float h = fast_sigmoid(go[m] + bo) * fast_tanh(c);
            hs16[wv][idx + m * 2] = (_Float16)h;
        }
    }

    float acc[8];
#pragma unroll
    for (int m = 0; m < 8; m++) acc[m] = 0.f;

#pragma unroll 8
    for (int jj = 0; jj < 32; jj++) {
        const uint4* hrow = reinterpret_cast<const uint4*>(&hs16[wv][jj * 16]);
        uint4 A = hrow[0];
        uint4 B = hrow[1];
        unsigned w = W1T2[jj * 64 + lane];         // coalesced dword
        acc[0] = fdot2_(A.x, w, acc[0]); acc[1] = fdot2_(A.y, w, acc[1]);
        acc[2] = fdot2_(A.z, w, acc[2]); acc[3] = fdot2_(A.w, w, acc[3]);
        acc[4] = fdot2_(B.x, w, acc[4]); acc[5] = fdot2_(B.y, w, acc[5]);
        acc[6] = fdot2_(B.z, w, acc[6]); acc[7] = fdot2_(B.w, w, acc[7]);
    }

#pragma unroll
    for (int m = 0; m < 8; m++)
        if (nbase + m < n)
            hw1[(size_t)(nbase + m) * 64 + lane] = __float2half(acc[m]);
}

// ---------------------------------------------------------------------------
// Pull aggregation, F=64. One wave per node, lane = feature. FP16 source
// rows (128B/row), f32 accumulation. Chunked readlane: 4 loads in flight.
// Fused epilogue 1: h1 = relu(agg*dc + hw1[node]*dc^2 + b1)   (h1 stays f32)
// ---------------------------------------------------------------------------
__global__ __launch_bounds__(256) void k_pull64(
    const __half* __restrict__ hw, const int* __restrict__ off,
    const int* __restrict__ nbr, const float* __restrict__ dinv,
    const float* __restrict__ b1, float* __restrict__ h1, int n)
{
    int node = (blockIdx.x * 256 + threadIdx.x) >> 6;
    int lane = threadIdx.x & 63;
    if (node >= n) return;
    int s = off[node], e = off[node + 1];

    float a0 = 0.f, a1 = 0.f, a2 = 0.f, a3 = 0.f;
    for (int base = s; base < e; base += 64) {
        int t = base + lane;
        int idx = 0; float wv = 0.f;
        if (t < e) { idx = nbr[t]; wv = dinv[idx]; }
        int cnt = e - base; if (cnt > 64) cnt = 64;

        int k = 0;
        for (; k + 4 <= cnt; k += 4) {
            int r0 = __builtin_amdgcn_readlane(idx, k + 0);
            int r1 = __builtin_amdgcn_readlane(idx, k + 1);
            int r2 = __builtin_amdgcn_readlane(idx, k + 2);
            int r3 = __builtin_amdgcn_readlane(idx, k + 3);
            float w0 = readlane_f(wv, k + 0);
            float w1 = readlane_f(wv, k + 1);
            float w2 = readlane_f(wv, k + 2);
            float w3 = readlane_f(wv, k + 3);
            float v0 = __half2float(hw[(size_t)r0 * 64 + lane]);
            float v1 = __half2float(hw[(size_t)r1 * 64 + lane]);
            float v2 = __half2float(hw[(size_t)r2 * 64 + lane]);
            float v3 = __half2float(hw[(size_t)r3 * 64 + lane]);
            a0 = fmaf(v0, w0, a0);
            a1 = fmaf(v1, w1, a1);
            a2 = fmaf(v2, w2, a2);
            a3 = fmaf(v3, w3, a3);
        }
        for (; k < cnt; k++) {
            int r = __builtin_amdgcn_readlane(idx, k);
            float w = readlane_f(wv, k);
            a0 = fmaf(__half2float(hw[(size_t)r * 64 + lane]), w, a0);
        }
    }

    float dc   = dinv[node];
    float self = __half2float(hw[(size_t)node * 64 + lane]);
    float v = ((a0 + a1) + (a2 + a3)) * dc + self * dc * dc + b1[lane];
    h1[(size_t)node * 64 + lane] = fmaxf(v, 0.0f);
}

// ---------------------------------------------------------------------------
// Pull aggregation, F=32. FP16 source rows (64B/row), f32 accumulation,
// FP16 z output. Halves on alternate neighbors.
// ---------------------------------------------------------------------------
__global__ __launch_bounds__(256) void k_pull32(
    const __half* __restrict__ hw, const int* __restrict__ off,
    const int* __restrict__ nbr, const float* __restrict__ dinv,
    const float* __restrict__ b2, __half* __restrict__ z, int n)
{
    int node = (blockIdx.x * 256 + threadIdx.x) >> 6;
    int lane = threadIdx.x & 63;
    int feat = lane & 31;
    int half = lane >> 5;
    if (node >= n) return;
    int s = off[node], e = off[node + 1];

    float a0 = 0.f, a1 = 0.f;
    for (int base = s; base < e; base += 64) {
        int t = base + lane;
        int idx = 0; float wv = 0.f;
        if (t < e) { idx = nbr[t]; wv = dinv[idx]; }
        int cnt = e - base; if (cnt > 64) cnt = 64;
        int cntp = (cnt + 1) & ~1;         // pad to even (pad lanes are zero)

        int j = half;
        for (; j + 2 < cntp; j += 4) {     // 2 neighbors per half per iter
            int   ra = __shfl(idx, j, 64);
            int   rb = __shfl(idx, j + 2, 64);
            float wa = __shfl(wv, j, 64);
            float wb = __shfl(wv, j + 2, 64);
            float va = __half2float(hw[(size_t)ra * 32 + feat]);
            float vb = __half2float(hw[(size_t)rb * 32 + feat]);
            a0 = fmaf(va, wa, a0);
            a1 = fmaf(vb, wb, a1);
        }
        for (; j < cntp; j += 2) {
            int   r = __shfl(idx, j, 64);
            float w = __shfl(wv, j, 64);
            a0 = fmaf(__half2float(hw[(size_t)r * 32 + feat]), w, a0);
        }
    }

    float acc = a0 + a1;
    acc += __shfl_xor(acc, 32, 64);        // combine even/odd halves
    float dc = dinv[node];
    float v = acc * dc + __half2float(hw[(size_t)node * 32 + feat]) * dc * dc + b2[feat];
    if (half == 0) z[(size_t)node * 32 + feat] = __float2half(v);
}

// ---------------------------------------------------------------------------
// hw2 = h1 @ W2  ([n,64] x [64,32]). f32 compute, FP16 output rows.
// ---------------------------------------------------------------------------
__global__ __launch_bounds__(128) void k_mm2(
    const float* __restrict__ h1, const float* __restrict__ W2,
    __half* __restrict__ hw2, int n)
{
    __shared__ float tile[128 * 65];
    int base  = blockIdx.x * 128;
    int nrows = n - base; if (nrows > 128) nrows = 128;

    for (int idx = threadIdx.x; idx < nrows * 64; idx += 128) {
        int r = idx >> 6, c = idx & 63;
        tile[r * 65 + c] = h1[(size_t)base * 64 + idx];
    }
    __syncthreads();

    int node = base + threadIdx.x;
    if (node >= n) return;

    const float* hrow = &tile[threadIdx.x * 65];
    float acc[32];
#pragma unroll
    for (int s = 0; s < 32; s++) acc[s] = 0.0f;

    for (int k = 0; k < 64; k++) {
        float hk = hrow[k];
        const float* w = W2 + (size_t)k * 32;
#pragma unroll
        for (int s = 0; s < 32; s++) acc[s] = fmaf(hk, w[s], acc[s]);
    }

    uint2* op = reinterpret_cast<uint2*>(hw2 + (size_t)node * 32);
#pragma unroll
    for (int q = 0; q < 8; q++) {
        __half2 lo(__float2half(acc[4*q+0]), __float2half(acc[4*q+1]));
        __half2 hi(__float2half(acc[4*q+2]), __float2half(acc[4*q+3]));
        op[q] = make_uint2(__builtin_bit_cast(unsigned, lo),
                           __builtin_bit_cast(unsigned, hi));
    }
}

// ---------------------------------------------------------------------------
// out[e] = dot(z[src[e]], z[dst[e]]) over 32 features; z is FP16.
// Row = 32 halves = 64B = 4 x uint4.
// ---------------------------------------------------------------------------
__global__ void k_dot(const __half* __restrict__ z, const int* __restrict__ src,
                      const int* __restrict__ dst, float* __restrict__ out, int EL)
{
    int e = blockIdx.x * 256 + threadIdx.x;
    if (e >= EL) return;
    const uint4* a = reinterpret_cast<const uint4*>(z + (size_t)src[e] * 32);
    const uint4* b = reinterpret_cast<const uint4*>(z + (size_t)dst[e] * 32);
    float s = 0.0f;
#pragma unroll
    for (int q = 0; q < 4; q++) {
        uint4 av = a[q], bv = b[q];
        s = fdot2_(av.x, bv.x, s);
        s = fdot2_(av.y, bv.y, s);
        s = fdot2_(av.z, bv.z, s);
        s = fdot2_(av.w, bv.w, s);
    }
    out[e] = s;
}

extern "C" void kernel_launch(void* const* d_in, const int* in_sizes, int n_in,
                              void* d_out, int out_size, void* d_ws, size_t ws_size,
                              hipStream_t stream)
{
    const float* x   = (const float*)d_in[0];
    const int*   ei  = (const int*)d_in[1];
    const int*   eli = (const int*)d_in[2];
    const float* Wih = (const float*)d_in[3];
    // d_in[4] = W_hh: mathematically dead (h0 = c0 = 0)
    const float* bih = (const float*)d_in[5];
    const float* bhh = (const float*)d_in[6];
    const float* W1  = (const float*)d_in[7];
    const float* b1  = (const float*)d_in[8];
    const float* W2  = (const float*)d_in[9];
    const float* b2  = (const float*)d_in[10];

    int n  = in_sizes[0] / 64;
    int E  = in_sizes[1] / 2;
    int EL = in_sizes[2] / 2;

    const int* row  = ei;          // source
    const int* col  = ei + E;      // destination
    const int* lsrc = eli;
    const int* ldst = eli + EL;
    float* out = (float*)d_out;

    // Workspace layout (4B units), liveness-aliased:
    //   bufA [n*64 f32 region]: ebuf int2[E] (bin..csr), hw1 FP16
    //                           (lstm..pull64), hw2 FP16 (mm2..pull32)
    //   bufB [n*64 f32 region]: h1 f32 (pull64..mm2), z FP16 (pull32..dot)
    //   dinv [n] | off [n+1] | nbr [E] | WT2 [6144] | W1T2 [2048]
    //   bdeg [256] | boff [257] | gcur [nbuck*16]
    float*    bufA  = (float*)d_ws;
    float*    bufB  = bufA + (size_t)n * 64;
    float*    dinv  = bufB + (size_t)n * 64;
    int*      off   = (int*)(dinv + n);
    int*      nbr   = off + (n + 1);
    unsigned* WT2   = (unsigned*)(nbr + E);
    unsigned* W1T2  = WT2 + 32 * 192;
    int*      bdeg  = (int*)(W1T2 + 32 * 64);
    int*      boff  = bdeg + 256;
    int*      gcur  = boff + 257;
    int2*     ebuf  = (int2*)bufA;    // dead until k_lstm_mm1 writes hw1
    __half*   hw1h  = (__half*)bufA;
    __half*   hw2h  = (__half*)bufA;  // hw1 dead by the time mm2 writes
    float*    h1    = bufB;
    __half*   zh    = (__half*)bufB;  // h1 dead by the time pull32 writes

    int nbuck   = (n + (1 << NBSH) - 1) >> NBSH;   // 196 buckets (<=256)
    int eblocks = (E + CH - 1) / CH;               // 391
    dim3 blk(256);

    // --- weight transpose + fp16 pack (8192 elements, one-time per call) ---
    k_tr<<<dim3(32), blk, 0, stream>>>(Wih, W1, WT2, W1T2);

    // --- CSR build: bucket histogram -> scan -> binned partition -> per-
    //     bucket finalize (off/dinv/nbr; LDS atomics only) ---
    hipMemsetAsync(bdeg, 0, 256 * sizeof(int), stream);
    k_bhist<<<dim3(eblocks), blk, 0, stream>>>(col, bdeg, E, nbuck);
    k_bscan<<<dim3(1), blk, 0, stream>>>(bdeg, boff, gcur, nbuck, E);
    k_bin  <<<dim3(eblocks), blk, 0, stream>>>(row, col, gcur, ebuf, E, nbuck);
    k_csr  <<<dim3(nbuck), dim3(512), 0, stream>>>(ebuf, boff, off, dinv, nbr, n, nbuck, E);

    // --- LSTM + first matmul: hw1 (fp16) -> bufA (ebuf dead) ---
    {
        int blocks = (n + 31) / 32;
        k_lstm_mm1<<<dim3(blocks), blk, 0, stream>>>(x, WT2, bih, bhh, W1T2, hw1h, n);
    }

    // --- GCN1: pull + fused epilogue (relu) : h1 (f32) -> bufB ---
    {
        int blocks = (int)(((size_t)n * 64 + 255) / 256);
        k_pull64<<<dim3(blocks), blk, 0, stream>>>(hw1h, off, nbr, dinv, b1, h1, n);
    }

    // --- second matmul: hw2 (fp16) -> bufA (hw1 dead) ---
    k_mm2<<<dim3((n + 127) / 128), dim3(128), 0, stream>>>(h1, W2, hw2h, n);

    // --- GCN2: pull + fused epilogue : z (fp16) -> bufB (h1 dead) ---
    {
        int blocks = (int)(((size_t)n * 64 + 255) / 256);
        k_pull32<<<dim3(blocks), blk, 0, stream>>>(hw2h, off, nbr, dinv, b2, zh, n);
    }

    // --- edge dot products ---
    k_dot<<<dim3((EL + 255) / 256), blk, 0, stream>>>(zh, lsrc, ldst, out, EL);
}

// Round 16
// 236.558 us; speedup vs baseline: 2.2191x; 1.0557x over previous
//
#include <hip/hip_runtime.h>
#include <hip/hip_bf16.h>
#include <hip/hip_fp16.h>
#include <math.h>

#define NBSH 9        // 512 destination cols per bucket
#define CH   4096     // edges staged per k_bin block

typedef _Float16 h2v __attribute__((ext_vector_type(2)));

__device__ __forceinline__ float fdot2_(unsigned a, unsigned b, float c) {
    return __builtin_amdgcn_fdot2(__builtin_bit_cast(h2v, a),
                                  __builtin_bit_cast(h2v, b), c, false);
}

__device__ __forceinline__ float2 h2f2_(unsigned u) {
    return __half22float2(__builtin_bit_cast(__half2, u));
}

// Fast device transcendentals: native v_exp_f32 + v_rcp_f32.
__device__ __forceinline__ float fast_sigmoid(float x) {
    float t = __expf(x);
    return 1.0f - __builtin_amdgcn_rcpf(1.0f + t);
}
__device__ __forceinline__ float fast_tanh(float x) {
    float t = __expf(2.0f * x);
    return 1.0f - 2.0f * __builtin_amdgcn_rcpf(1.0f + t);
}

// ---------------------------------------------------------------------------
// Bucket histogram: per-block LDS histogram of col>>NBSH, then ONE global
// atomic per (bucket, block). bdeg must be zeroed first.
// ---------------------------------------------------------------------------
__global__ __launch_bounds__(256) void k_bhist(const int* __restrict__ col,
        int* __restrict__ bdeg, int E, int nbuck) {
    __shared__ int cnt[256];
    cnt[threadIdx.x] = 0;
    __syncthreads();
    int base = blockIdx.x * CH;
    int end  = base + CH; if (end > E) end = E;
    for (int t = base + (int)threadIdx.x; t < end; t += 256)
        atomicAdd(&cnt[col[t] >> NBSH], 1);
    __syncthreads();
    if ((int)threadIdx.x < nbuck && cnt[threadIdx.x] > 0)
        atomicAdd(&bdeg[threadIdx.x], cnt[threadIdx.x]);
}

// ---------------------------------------------------------------------------
// Single-block scan of bucket sizes -> boff[0..nbuck]; inits padded k_bin
// cursors (gcur[b*16] = boff[b]).
// ---------------------------------------------------------------------------
__global__ __launch_bounds__(256) void k_bscan(const int* __restrict__ bdeg,
        int* __restrict__ boff, int* __restrict__ gcur, int nbuck, int E) {
    __shared__ int tmp[256];
    int tid = threadIdx.x;
    int v = (tid < nbuck) ? bdeg[tid] : 0;
    tmp[tid] = v;
    __syncthreads();
#pragma unroll
    for (int s = 1; s < 256; s <<= 1) {
        int t = (tid >= s) ? tmp[tid - s] : 0;
        __syncthreads();
        tmp[tid] += t;
        __syncthreads();
    }
    if (tid < nbuck) {
        int o = tmp[tid] - v;
        boff[tid] = o;
        gcur[tid * 16] = o;
    }
    if (tid == 0) boff[nbuck] = E;
}

// ---------------------------------------------------------------------------
// Pass 1: LDS-binned partition of edges into 512-col buckets (proven r13/14).
// ---------------------------------------------------------------------------
__global__ __launch_bounds__(256) void k_bin(
    const int* __restrict__ row, const int* __restrict__ col,
    int* __restrict__ gcur, int2* __restrict__ ebuf, int E, int nbuck)
{
    __shared__ int  cnt[256], lofs[256], gbase[256], cur2[256];
    __shared__ int2 stage[CH];
    int tid  = threadIdx.x;
    int base = blockIdx.x * CH;
    int ned  = E - base; if (ned > CH) ned = CH;

    cnt[tid] = 0;
    __syncthreads();

    int r[16], c[16], b[16];
#pragma unroll
    for (int i = 0; i < 16; i++) {
        int idx = i * 256 + tid;
        if (idx < ned) {
            r[i] = row[base + idx];
            c[i] = col[base + idx];
            b[i] = c[i] >> NBSH;
            atomicAdd(&cnt[b[i]], 1);
        } else { r[i] = 0; c[i] = 0; b[i] = -1; }
    }
    __syncthreads();

    int v = cnt[tid];
    lofs[tid] = v;
    __syncthreads();
#pragma unroll
    for (int s = 1; s < 256; s <<= 1) {
        int t = (tid >= s) ? lofs[tid - s] : 0;
        __syncthreads();
        lofs[tid] += t;
        __syncthreads();
    }
    int excl = lofs[tid] - v;
    __syncthreads();
    lofs[tid] = excl;
    cur2[tid] = excl;
    if (tid < nbuck && v > 0)
        gbase[tid] = atomicAdd(&gcur[tid * 16], v);   // padded: no hot line
    __syncthreads();

#pragma unroll
    for (int i = 0; i < 16; i++) {
        if (b[i] >= 0) {
            int p = atomicAdd(&cur2[b[i]], 1);
            stage[p] = make_int2(r[i], c[i]);
        }
    }
    __syncthreads();

    for (int i = tid; i < ned; i += 256) {
        int2 rc = stage[i];
        int bb = rc.y >> NBSH;
        ebuf[gbase[bb] + (i - lofs[bb])] = rc;
    }
}

// ---------------------------------------------------------------------------
// Pass 2: per-bucket CSR finalize (off/dinv/nbr; LDS atomics only).
// ---------------------------------------------------------------------------
__global__ __launch_bounds__(512) void k_csr(
    const int2* __restrict__ ebuf, const int* __restrict__ boff,
    int* __restrict__ off, float* __restrict__ dinv,
    int* __restrict__ nbr, int n, int nbuck, int E)
{
    __shared__ int cnt[512], lofs[512];
    int b   = blockIdx.x;
    int tid = threadIdx.x;
    int c0  = b << NBSH;
    int nn  = n - c0; if (nn > 512) nn = 512; if (nn < 0) nn = 0;
    int lo  = boff[b], hi = boff[b + 1];

    cnt[tid] = 0;
    __syncthreads();
    for (int t = lo + tid; t < hi; t += 512)
        atomicAdd(&cnt[ebuf[t].y & 511], 1);
    __syncthreads();

    int v = cnt[tid];
    lofs[tid] = v;
    __syncthreads();
#pragma unroll
    for (int s = 1; s < 512; s <<= 1) {
        int t = (tid >= s) ? lofs[tid - s] : 0;
        __syncthreads();
        lofs[tid] += t;
        __syncthreads();
    }
    int excl = lofs[tid] - v;
    __syncthreads();

    if (tid < nn) {
        off[c0 + tid]  = lo + excl;
        dinv[c0 + tid] = 1.0f / sqrtf((float)(v + 1));
    }
    if (b == nbuck - 1 && tid == 0) off[n] = E;

    cnt[tid] = excl;                       // reuse as LDS cursors
    __syncthreads();
    for (int t = lo + tid; t < hi; t += 512) {
        int2 rc = ebuf[t];
        int p = atomicAdd(&cnt[rc.y & 511], 1);
        nbr[lo + p] = rc.x;
    }
}

// ---------------------------------------------------------------------------
// One-time weight transpose + fp16 pack for fdot2:
//   WT2[kk*192 + g*64 + j] = half2(Wih[row(g,j)][2kk], Wih[row(g,j)][2kk+1])
//   W1T2[jj*64 + s]        = half2(W1[2jj][s],        W1[2jj+1][s])
// ---------------------------------------------------------------------------
__global__ void k_tr(const float* __restrict__ Wih, const float* __restrict__ W1,
                     unsigned* __restrict__ WT2, unsigned* __restrict__ W1T2) {
    int t = blockIdx.x * 256 + threadIdx.x;
    if (t < 32 * 192) {
        int kk = t / 192, c = t % 192;
        int g = c >> 6, j = c & 63;
        int rowb = (g == 0) ? j : (g == 1) ? (128 + j) : (192 + j);
        h2v p;
        p.x = (_Float16)Wih[rowb * 64 + 2 * kk];
        p.y = (_Float16)Wih[rowb * 64 + 2 * kk + 1];
        WT2[t] = __builtin_bit_cast(unsigned, p);
    } else if (t < 32 * 192 + 32 * 64) {
        int u = t - 32 * 192;
        int jj = u >> 6, s = u & 63;
        h2v p;
        p.x = (_Float16)W1[(2 * jj) * 64 + s];
        p.y = (_Float16)W1[(2 * jj + 1) * 64 + s];
        W1T2[u] = __builtin_bit_cast(unsigned, p);
    }
}

// ---------------------------------------------------------------------------
// Fused LSTM step + (h @ W1), GEMV-broadcast + v_dot2_f32_f16 (r15, proven).
// ---------------------------------------------------------------------------
__global__ __launch_bounds__(256) void k_lstm_mm1(
    const float* __restrict__ x, const unsigned* __restrict__ WT2,
    const float* __restrict__ bih, const float* __restrict__ bhh,
    const unsigned* __restrict__ W1T2, __half* __restrict__ hw1, int n)
{
    __shared__ _Float16 xs16[4][512];      // [wv][kk*16 + m*2 + parity]
    __shared__ _Float16 hs16[4][512];
    int wv   = threadIdx.x >> 6;
    int lane = threadIdx.x & 63;
    int nbase = (blockIdx.x * 4 + wv) * 8;
    if (nbase >= n) return;                // wave-uniform

    int ni[8];
#pragma unroll
    for (int m = 0; m < 8; m++) {
        int t = nbase + m;
        ni[m] = (t < n) ? t : (n - 1);     // clamp for safe loads
    }

    {
        int idx = (lane >> 1) * 16 + (lane & 1);
#pragma unroll
        for (int m = 0; m < 8; m++)
            xs16[wv][idx + m * 2] = (_Float16)x[(size_t)ni[m] * 64 + lane];
    }

    float gi[8], gg[8], go[8];
#pragma unroll
    for (int m = 0; m < 8; m++) { gi[m] = 0.f; gg[m] = 0.f; go[m] = 0.f; }

#pragma unroll 8
    for (int kk = 0; kk < 32; kk++) {
        const uint4* xrow = reinterpret_cast<const uint4*>(&xs16[wv][kk * 16]);
        uint4 A = xrow[0];                 // nodes 0..3 (half2 each), broadcast
        uint4 B = xrow[1];                 // nodes 4..7
        unsigned wi = WT2[kk * 192 + lane];        // coalesced dword
        unsigned wg = WT2[kk * 192 + 64 + lane];
        unsigned wo = WT2[kk * 192 + 128 + lane];
        gi[0] = fdot2_(A.x, wi, gi[0]); gi[1] = fdot2_(A.y, wi, gi[1]);
        gi[2] = fdot2_(A.z, wi, gi[2]); gi[3] = fdot2_(A.w, wi, gi[3]);
        gi[4] = fdot2_(B.x, wi, gi[4]); gi[5] = fdot2_(B.y, wi, gi[5]);
        gi[6] = fdot2_(B.z, wi, gi[6]); gi[7] = fdot2_(B.w, wi, gi[7]);
        gg[0] = fdot2_(A.x, wg, gg[0]); gg[1] = fdot2_(A.y, wg, gg[1]);
        gg[2] = fdot2_(A.z, wg, gg[2]); gg[3] = fdot2_(A.w, wg, gg[3]);
        gg[4] = fdot2_(B.x, wg, gg[4]); gg[5] = fdot2_(B.y, wg, gg[5]);
        gg[6] = fdot2_(B.z, wg, gg[6]); gg[7] = fdot2_(B.w, wg, gg[7]);
        go[0] = fdot2_(A.x, wo, go[0]); go[1] = fdot2_(A.y, wo, go[1]);
        go[2] = fdot2_(A.z, wo, go[2]); go[3] = fdot2_(A.w, wo, go[3]);
        go[4] = fdot2_(B.x, wo, go[4]); go[5] = fdot2_(B.y, wo, go[5]);
        go[6] = fdot2_(B.z, wo, go[6]); go[7] = fdot2_(B.w, wo, go[7]);
    }

    float bi = bih[lane]       + bhh[lane];
    float bg = bih[128 + lane] + bhh[128 + lane];
    float bo = bih[192 + lane] + bhh[192 + lane];

    {
        int idx = (lane >> 1) * 16 + (lane & 1);
#pragma unroll
        for (int m = 0; m < 8; m++) {
            float c = fast_sigmoid(gi[m] + bi) * fast_tanh(gg[m] + bg);
            float h = fast_sigmoid(go[m] + bo) * fast_tanh(c);
            hs16[wv][idx + m * 2] = (_Float16)h;
        }
    }

    float acc[8];
#pragma unroll
    for (int m = 0; m < 8; m++) acc[m] = 0.f;

#pragma unroll 8
    for (int jj = 0; jj < 32; jj++) {
        const uint4* hrow = reinterpret_cast<const uint4*>(&hs16[wv][jj * 16]);
        uint4 A = hrow[0];
        uint4 B = hrow[1];
        unsigned w = W1T2[jj * 64 + lane];         // coalesced dword
        acc[0] = fdot2_(A.x, w, acc[0]); acc[1] = fdot2_(A.y, w, acc[1]);
        acc[2] = fdot2_(A.z, w, acc[2]); acc[3] = fdot2_(A.w, w, acc[3]);
        acc[4] = fdot2_(B.x, w, acc[4]); acc[5] = fdot2_(B.y, w, acc[5]);
        acc[6] = fdot2_(B.z, w, acc[6]); acc[7] = fdot2_(B.w, w, acc[7]);
    }

#pragma unroll
    for (int m = 0; m < 8; m++)
        if (nbase + m < n)
            hw1[(size_t)(nbase + m) * 64 + lane] = __float2half(acc[m]);
}

// ---------------------------------------------------------------------------
// Pull aggregation, F=64 -- 2 NODES PER WAVE, half2-packed gathers.
// Lanes 0-31 = node A, lanes 32-63 = node B; fp = lane&31 = feature pair.
// One load instruction fetches TWO full 128B rows (256B/instr, was 128B);
// indices broadcast via width-32 shfl within each half. 4-slot unroll ->
// 8 edges in flight per wave (2x MLP), ~3.5 VALU/edge (was ~5).
// Fused epilogue 1: h1 = relu(agg*dc + hw1[node]*dc^2 + b1)   (h1 stays f32)
// ---------------------------------------------------------------------------
__global__ __launch_bounds__(256) void k_pull64(
    const __half* __restrict__ hw, const int* __restrict__ off,
    const int* __restrict__ nbr, const float* __restrict__ dinv,
    const float* __restrict__ b1, float* __restrict__ h1, int n)
{
    int w    = (blockIdx.x * 256 + threadIdx.x) >> 6;   // wave id
    int lane = threadIdx.x & 63;
    int half = lane >> 5;
    int fp   = lane & 31;              // features 2fp, 2fp+1
    if (w * 2 >= n) return;            // wave-uniform
    int node = w * 2 + half;
    bool alive = node < n;
    int s = 0, e = 0;
    if (alive) { s = off[node]; e = off[node + 1]; }

    float ax0 = 0.f, ay0 = 0.f, ax1 = 0.f, ay1 = 0.f;
    float ax2 = 0.f, ay2 = 0.f, ax3 = 0.f, ay3 = 0.f;

    for (int base = s; base < e; base += 32) {
        int t = base + fp;
        int idx = 0; float wv = 0.f;
        if (t < e) { idx = nbr[t]; wv = dinv[idx]; }
        int cnt = e - base; if (cnt > 32) cnt = 32;

        int k = 0;
        for (; k + 4 <= cnt; k += 4) {
            int   r0 = __shfl(idx, k + 0, 32); float w0 = __shfl(wv, k + 0, 32);
            int   r1 = __shfl(idx, k + 1, 32); float w1 = __shfl(wv, k + 1, 32);
            int   r2 = __shfl(idx, k + 2, 32); float w2 = __shfl(wv, k + 2, 32);
            int   r3 = __shfl(idx, k + 3, 32); float w3 = __shfl(wv, k + 3, 32);
            unsigned u0 = reinterpret_cast<const unsigned*>(hw + (size_t)r0 * 64)[fp];
            unsigned u1 = reinterpret_cast<const unsigned*>(hw + (size_t)r1 * 64)[fp];
            unsigned u2 = reinterpret_cast<const unsigned*>(hw + (size_t)r2 * 64)[fp];
            unsigned u3 = reinterpret_cast<const unsigned*>(hw + (size_t)r3 * 64)[fp];
            float2 f0 = h2f2_(u0), f1 = h2f2_(u1), f2 = h2f2_(u2), f3 = h2f2_(u3);
            ax0 = fmaf(f0.x, w0, ax0); ay0 = fmaf(f0.y, w0, ay0);
            ax1 = fmaf(f1.x, w1, ax1); ay1 = fmaf(f1.y, w1, ay1);
            ax2 = fmaf(f2.x, w2, ax2); ay2 = fmaf(f2.y, w2, ay2);
            ax3 = fmaf(f3.x, w3, ax3); ay3 = fmaf(f3.y, w3, ay3);
        }
        for (; k < cnt; k++) {
            int   r0 = __shfl(idx, k, 32);
            float w0 = __shfl(wv, k, 32);
            unsigned u0 = reinterpret_cast<const unsigned*>(hw + (size_t)r0 * 64)[fp];
            float2 f0 = h2f2_(u0);
            ax0 = fmaf(f0.x, w0, ax0); ay0 = fmaf(f0.y, w0, ay0);
        }
    }

    if (alive) {
        float ax = (ax0 + ax1) + (ax2 + ax3);
        float ay = (ay0 + ay1) + (ay2 + ay3);
        float dc = dinv[node];
        unsigned su = reinterpret_cast<const unsigned*>(hw + (size_t)node * 64)[fp];
        float2 sf = h2f2_(su);
        float2 bb = reinterpret_cast<const float2*>(b1)[fp];
        float vx = fmaxf(ax * dc + sf.x * dc * dc + bb.x, 0.0f);
        float vy = fmaxf(ay * dc + sf.y * dc * dc + bb.y, 0.0f);
        reinterpret_cast<float2*>(h1 + (size_t)node * 64)[fp] = make_float2(vx, vy);
    }
}

// ---------------------------------------------------------------------------
// Pull aggregation, F=32. FP16 source rows (64B/row), f32 accumulation,
// FP16 z output. Halves on alternate neighbors.
// ---------------------------------------------------------------------------
__global__ __launch_bounds__(256) void k_pull32(
    const __half* __restrict__ hw, const int* __restrict__ off,
    const int* __restrict__ nbr, const float* __restrict__ dinv,
    const float* __restrict__ b2, __half* __restrict__ z, int n)
{
    int node = (blockIdx.x * 256 + threadIdx.x) >> 6;
    int lane = threadIdx.x & 63;
    int feat = lane & 31;
    int half = lane >> 5;
    if (node >= n) return;
    int s = off[node], e = off[node + 1];

    float a0 = 0.f, a1 = 0.f;
    for (int base = s; base < e; base += 64) {
        int t = base + lane;
        int idx = 0; float wv = 0.f;
        if (t < e) { idx = nbr[t]; wv = dinv[idx]; }
        int cnt = e - base; if (cnt > 64) cnt = 64;
        int cntp = (cnt + 1) & ~1;         // pad to even (pad lanes are zero)

        int j = half;
        for (; j + 2 < cntp; j += 4) {     // 2 neighbors per half per iter
            int   ra = __shfl(idx, j, 64);
            int   rb = __shfl(idx, j + 2, 64);
            float wa = __shfl(wv, j, 64);
            float wb = __shfl(wv, j + 2, 64);
            float va = __half2float(hw[(size_t)ra * 32 + feat]);
            float vb = __half2float(hw[(size_t)rb * 32 + feat]);
            a0 = fmaf(va, wa, a0);
            a1 = fmaf(vb, wb, a1);
        }
        for (; j < cntp; j += 2) {
            int   r = __shfl(idx, j, 64);
            float w = __shfl(wv, j, 64);
            a0 = fmaf(__half2float(hw[(size_t)r * 32 + feat]), w, a0);
        }
    }

    float acc = a0 + a1;
    acc += __shfl_xor(acc, 32, 64);        // combine even/odd halves
    float dc = dinv[node];
    float v = acc * dc + __half2float(hw[(size_t)node * 32 + feat]) * dc * dc + b2[feat];
    if (half == 0) z[(size_t)node * 32 + feat] = __float2half(v);
}

// ---------------------------------------------------------------------------
// hw2 = h1 @ W2  ([n,64] x [64,32]). f32 compute, FP16 output rows.
// ---------------------------------------------------------------------------
__global__ __launch_bounds__(128) void k_mm2(
    const float* __restrict__ h1, const float* __restrict__ W2,
    __half* __restrict__ hw2, int n)
{
    __shared__ float tile[128 * 65];
    int base  = blockIdx.x * 128;
    int nrows = n - base; if (nrows > 128) nrows = 128;

    for (int idx = threadIdx.x; idx < nrows * 64; idx += 128) {
        int r = idx >> 6, c = idx & 63;
        tile[r * 65 + c] = h1[(size_t)base * 64 + idx];
    }
    __syncthreads();

    int node = base + threadIdx.x;
    if (node >= n) return;

    const float* hrow = &tile[threadIdx.x * 65];
    float acc[32];
#pragma unroll
    for (int s = 0; s < 32; s++) acc[s] = 0.0f;

    for (int k = 0; k < 64; k++) {
        float hk = hrow[k];
        const float* w = W2 + (size_t)k * 32;
#pragma unroll
        for (int s = 0; s < 32; s++) acc[s] = fmaf(hk, w[s], acc[s]);
    }

    uint2* op = reinterpret_cast<uint2*>(hw2 + (size_t)node * 32);
#pragma unroll
    for (int q = 0; q < 8; q++) {
        __half2 lo(__float2half(acc[4*q+0]), __float2half(acc[4*q+1]));
        __half2 hi(__float2half(acc[4*q+2]), __float2half(acc[4*q+3]));
        op[q] = make_uint2(__builtin_bit_cast(unsigned, lo),
                           __builtin_bit_cast(unsigned, hi));
    }
}

// ---------------------------------------------------------------------------
// out[e] = dot(z[src[e]], z[dst[e]]) over 32 features; z is FP16.
// Row = 32 halves = 64B = 4 x uint4.
// ---------------------------------------------------------------------------
__global__ void k_dot(const __half* __restrict__ z, const int* __restrict__ src,
                      const int* __restrict__ dst, float* __restrict__ out, int EL)
{
    int e = blockIdx.x * 256 + threadIdx.x;
    if (e >= EL) return;
    const uint4* a = reinterpret_cast<const uint4*>(z + (size_t)src[e] * 32);
    const uint4* b = reinterpret_cast<const uint4*>(z + (size_t)dst[e] * 32);
    float s = 0.0f;
#pragma unroll
    for (int q = 0; q < 4; q++) {
        uint4 av = a[q], bv = b[q];
        s = fdot2_(av.x, bv.x, s);
        s = fdot2_(av.y, bv.y, s);
        s = fdot2_(av.z, bv.z, s);
        s = fdot2_(av.w, bv.w, s);
    }
    out[e] = s;
}

extern "C" void kernel_launch(void* const* d_in, const int* in_sizes, int n_in,
                              void* d_out, int out_size, void* d_ws, size_t ws_size,
                              hipStream_t stream)
{
    const float* x   = (const float*)d_in[0];
    const int*   ei  = (const int*)d_in[1];
    const int*   eli = (const int*)d_in[2];
    const float* Wih = (const float*)d_in[3];
    // d_in[4] = W_hh: mathematically dead (h0 = c0 = 0)
    const float* bih = (const float*)d_in[5];
    const float* bhh = (const float*)d_in[6];
    const float* W1  = (const float*)d_in[7];
    const float* b1  = (const float*)d_in[8];
    const float* W2  = (const float*)d_in[9];
    const float* b2  = (const float*)d_in[10];

    int n  = in_sizes[0] / 64;
    int E  = in_sizes[1] / 2;
    int EL = in_sizes[2] / 2;

    const int* row  = ei;          // source
    const int* col  = ei + E;      // destination
    const int* lsrc = eli;
    const int* ldst = eli + EL;
    float* out = (float*)d_out;

    // Workspace layout (4B units), liveness-aliased:
    //   bufA [n*64 f32 region]: ebuf int2[E] (bin..csr), hw1 FP16
    //                           (lstm..pull64), hw2 FP16 (mm2..pull32)
    //   bufB [n*64 f32 region]: h1 f32 (pull64..mm2), z FP16 (pull32..dot)
    //   dinv [n] | off [n+1] | nbr [E] | WT2 [6144] | W1T2 [2048]
    //   bdeg [256] | boff [257] | gcur [nbuck*16]
    float*    bufA  = (float*)d_ws;
    float*    bufB  = bufA + (size_t)n * 64;
    float*    dinv  = bufB + (size_t)n * 64;
    int*      off   = (int*)(dinv + n);
    int*      nbr   = off + (n + 1);
    unsigned* WT2   = (unsigned*)(nbr + E);
    unsigned* W1T2  = WT2 + 32 * 192;
    int*      bdeg  = (int*)(W1T2 + 32 * 64);
    int*      boff  = bdeg + 256;
    int*      gcur  = boff + 257;
    int2*     ebuf  = (int2*)bufA;    // dead until k_lstm_mm1 writes hw1
    __half*   hw1h  = (__half*)bufA;
    __half*   hw2h  = (__half*)bufA;  // hw1 dead by the time mm2 writes
    float*    h1    = bufB;
    __half*   zh    = (__half*)bufB;  // h1 dead by the time pull32 writes

    int nbuck   = (n + (1 << NBSH) - 1) >> NBSH;   // 196 buckets (<=256)
    int eblocks = (E + CH - 1) / CH;               // 391
    dim3 blk(256);

    // --- weight transpose + fp16 pack (8192 elements, one-time per call) ---
    k_tr<<<dim3(32), blk, 0, stream>>>(Wih, W1, WT2, W1T2);

    // --- CSR build: bucket histogram -> scan -> binned partition -> per-
    //     bucket finalize (off/dinv/nbr; LDS atomics only) ---
    hipMemsetAsync(bdeg, 0, 256 * sizeof(int), stream);
    k_bhist<<<dim3(eblocks), blk, 0, stream>>>(col, bdeg, E, nbuck);
    k_bscan<<<dim3(1), blk, 0, stream>>>(bdeg, boff, gcur, nbuck, E);
    k_bin  <<<dim3(eblocks), blk, 0, stream>>>(row, col, gcur, ebuf, E, nbuck);
    k_csr  <<<dim3(nbuck), dim3(512), 0, stream>>>(ebuf, boff, off, dinv, nbr, n, nbuck, E);

    // --- LSTM + first matmul: hw1 (fp16) -> bufA (ebuf dead) ---
    {
        int blocks = (n + 31) / 32;
        k_lstm_mm1<<<dim3(blocks), blk, 0, stream>>>(x, WT2, bih, bhh, W1T2, hw1h, n);
    }

    // --- GCN1: pull + fused epilogue (relu) : h1 (f32) -> bufB ---
    //     2 nodes/wave -> ceil(n/8) blocks of 256
    {
        int blocks = (n + 7) / 8;
        k_pull64<<<dim3(blocks), blk, 0, stream>>>(hw1h, off, nbr, dinv, b1, h1, n);
    }

    // --- second matmul: hw2 (fp16) -> bufA (hw1 dead) ---
    k_mm2<<<dim3((n + 127) / 128), dim3(128), 0, stream>>>(h1, W2, hw2h, n);

    // --- GCN2: pull + fused epilogue : z (fp16) -> bufB (h1 dead) ---
    {
        int blocks = (int)(((size_t)n * 64 + 255) / 256);
        k_pull32<<<dim3(blocks), blk, 0, stream>>>(hw2h, off, nbr, dinv, b2, zh, n);
    }

    // --- edge dot products ---
    k_dot<<<dim3((EL + 255) / 256), blk, 0, stream>>>(zh, lsrc, ldst, out, EL);
}

// Round 17
// 215.745 us; speedup vs baseline: 2.4331x; 1.0965x over previous
//
#include <hip/hip_runtime.h>
#include <hip/hip_bf16.h>
#include <hip/hip_fp16.h>
#include <math.h>
#include <stdint.h>

#define NBSH 9        // 512 destination cols per bucket
#define CH   4096     // edges staged per k_bin block

typedef _Float16 h2v  __attribute__((ext_vector_type(2)));
typedef _Float16 half8 __attribute__((ext_vector_type(8)));
typedef float    f32x4 __attribute__((ext_vector_type(4)));

__device__ __forceinline__ float fdot2_(unsigned a, unsigned b, float c) {
    return __builtin_amdgcn_fdot2(__builtin_bit_cast(h2v, a),
                                  __builtin_bit_cast(h2v, b), c, false);
}

__device__ __forceinline__ float2 h2f2_(unsigned u) {
    return __half22float2(__builtin_bit_cast(__half2, u));
}

// Fast device transcendentals: native v_exp_f32 + v_rcp_f32.
__device__ __forceinline__ float fast_sigmoid(float x) {
    float t = __expf(x);
    return 1.0f - __builtin_amdgcn_rcpf(1.0f + t);
}
__device__ __forceinline__ float fast_tanh(float x) {
    float t = __expf(2.0f * x);
    return 1.0f - 2.0f * __builtin_amdgcn_rcpf(1.0f + t);
}

// ---------------------------------------------------------------------------
// Bucket histogram: per-block LDS histogram of col>>NBSH, then ONE global
// atomic per (bucket, block). bdeg must be zeroed first.
// ---------------------------------------------------------------------------
__global__ __launch_bounds__(256) void k_bhist(const int* __restrict__ col,
        int* __restrict__ bdeg, int E, int nbuck) {
    __shared__ int cnt[256];
    cnt[threadIdx.x] = 0;
    __syncthreads();
    int base = blockIdx.x * CH;
    int end  = base + CH; if (end > E) end = E;
    for (int t = base + (int)threadIdx.x; t < end; t += 256)
        atomicAdd(&cnt[col[t] >> NBSH], 1);
    __syncthreads();
    if ((int)threadIdx.x < nbuck && cnt[threadIdx.x] > 0)
        atomicAdd(&bdeg[threadIdx.x], cnt[threadIdx.x]);
}

// ---------------------------------------------------------------------------
// Single-block scan of bucket sizes -> boff[0..nbuck]; inits padded k_bin
// cursors (gcur[b*16] = boff[b]).
// ---------------------------------------------------------------------------
__global__ __launch_bounds__(256) void k_bscan(const int* __restrict__ bdeg,
        int* __restrict__ boff, int* __restrict__ gcur, int nbuck, int E) {
    __shared__ int tmp[256];
    int tid = threadIdx.x;
    int v = (tid < nbuck) ? bdeg[tid] : 0;
    tmp[tid] = v;
    __syncthreads();
#pragma unroll
    for (int s = 1; s < 256; s <<= 1) {
        int t = (tid >= s) ? tmp[tid - s] : 0;
        __syncthreads();
        tmp[tid] += t;
        __syncthreads();
    }
    if (tid < nbuck) {
        int o = tmp[tid] - v;
        boff[tid] = o;
        gcur[tid * 16] = o;
    }
    if (tid == 0) boff[nbuck] = E;
}

// ---------------------------------------------------------------------------
// Pass 1: LDS-binned partition of edges into 512-col buckets (proven r13/14).
// ---------------------------------------------------------------------------
__global__ __launch_bounds__(256) void k_bin(
    const int* __restrict__ row, const int* __restrict__ col,
    int* __restrict__ gcur, int2* __restrict__ ebuf, int E, int nbuck)
{
    __shared__ int  cnt[256], lofs[256], gbase[256], cur2[256];
    __shared__ int2 stage[CH];
    int tid  = threadIdx.x;
    int base = blockIdx.x * CH;
    int ned  = E - base; if (ned > CH) ned = CH;

    cnt[tid] = 0;
    __syncthreads();

    int r[16], c[16], b[16];
#pragma unroll
    for (int i = 0; i < 16; i++) {
        int idx = i * 256 + tid;
        if (idx < ned) {
            r[i] = row[base + idx];
            c[i] = col[base + idx];
            b[i] = c[i] >> NBSH;
            atomicAdd(&cnt[b[i]], 1);
        } else { r[i] = 0; c[i] = 0; b[i] = -1; }
    }
    __syncthreads();

    int v = cnt[tid];
    lofs[tid] = v;
    __syncthreads();
#pragma unroll
    for (int s = 1; s < 256; s <<= 1) {
        int t = (tid >= s) ? lofs[tid - s] : 0;
        __syncthreads();
        lofs[tid] += t;
        __syncthreads();
    }
    int excl = lofs[tid] - v;
    __syncthreads();
    lofs[tid] = excl;
    cur2[tid] = excl;
    if (tid < nbuck && v > 0)
        gbase[tid] = atomicAdd(&gcur[tid * 16], v);   // padded: no hot line
    __syncthreads();

#pragma unroll
    for (int i = 0; i < 16; i++) {
        if (b[i] >= 0) {
            int p = atomicAdd(&cur2[b[i]], 1);
            stage[p] = make_int2(r[i], c[i]);
        }
    }
    __syncthreads();

    for (int i = tid; i < ned; i += 256) {
        int2 rc = stage[i];
        int bb = rc.y >> NBSH;
        ebuf[gbase[bb] + (i - lofs[bb])] = rc;
    }
}

// ---------------------------------------------------------------------------
// Pass 2: per-bucket CSR finalize (off/dinv/nbr; LDS atomics only).
// ---------------------------------------------------------------------------
__global__ __launch_bounds__(512) void k_csr(
    const int2* __restrict__ ebuf, const int* __restrict__ boff,
    int* __restrict__ off, float* __restrict__ dinv,
    int* __restrict__ nbr, int n, int nbuck, int E)
{
    __shared__ int cnt[512], lofs[512];
    int b   = blockIdx.x;
    int tid = threadIdx.x;
    int c0  = b << NBSH;
    int nn  = n - c0; if (nn > 512) nn = 512; if (nn < 0) nn = 0;
    int lo  = boff[b], hi = boff[b + 1];

    cnt[tid] = 0;
    __syncthreads();
    for (int t = lo + tid; t < hi; t += 512)
        atomicAdd(&cnt[ebuf[t].y & 511], 1);
    __syncthreads();

    int v = cnt[tid];
    lofs[tid] = v;
    __syncthreads();
#pragma unroll
    for (int s = 1; s < 512; s <<= 1) {
        int t = (tid >= s) ? lofs[tid - s] : 0;
        __syncthreads();
        lofs[tid] += t;
        __syncthreads();
    }
    int excl = lofs[tid] - v;
    __syncthreads();

    if (tid < nn) {
        off[c0 + tid]  = lo + excl;
        dinv[c0 + tid] = 1.0f / sqrtf((float)(v + 1));
    }
    if (b == nbuck - 1 && tid == 0) off[n] = E;

    cnt[tid] = excl;                       // reuse as LDS cursors
    __syncthreads();
    for (int t = lo + tid; t < hi; t += 512) {
        int2 rc = ebuf[t];
        int p = atomicAdd(&cnt[rc.y & 511], 1);
        nbr[lo + p] = rc.x;
    }
}

// ---------------------------------------------------------------------------
// One-time MFMA B-fragment tables + combined bias.
// Gate tile order: t = gate*4 + tj (gate 0=i rows j, 1=g rows 128+j, 2=o rows
// 192+j; f dead since c0=0). Fragment layout (16x16x32 f16):
//   lane l holds 8 elems at k = kh*32 + 8*(l>>4)+jj; col/n = 16*tj + (l&15).
//   B1tab[(t*2+kh)*64 + l] = 8 fp16 of WihT[k][col]; B2tab same for W1.
//   bsum[g*64+j] = bih+bhh at that gate row.
// ---------------------------------------------------------------------------
__global__ void k_tr(const float* __restrict__ Wih, const float* __restrict__ W1,
                     const float* __restrict__ bih, const float* __restrict__ bhh,
                     uint4* __restrict__ B1tab, uint4* __restrict__ B2tab,
                     float* __restrict__ bsum) {
    int t = blockIdx.x * 256 + threadIdx.x;
    if (t < 1536) {
        int e = t >> 6, l = t & 63;
        int tt = e >> 1, kh = e & 1;
        int gate = tt >> 2, tj = tt & 3;
        int j = 16 * tj + (l & 15);
        int rowb = (gate == 0) ? j : (gate == 1) ? (128 + j) : (192 + j);
        int kbase = kh * 32 + 8 * (l >> 4);
        _Float16 v[8];
#pragma unroll
        for (int jj = 0; jj < 8; jj++)
            v[jj] = (_Float16)Wih[rowb * 64 + kbase + jj];
        B1tab[t] = *reinterpret_cast<uint4*>(v);
    } else if (t < 2048) {
        int u = t - 1536;
        int e = u >> 6, l = u & 63;
        int tt = e >> 1, kh = e & 1;
        int s = 16 * tt + (l & 15);
        int kbase = kh * 32 + 8 * (l >> 4);
        _Float16 v[8];
#pragma unroll
        for (int jj = 0; jj < 8; jj++)
            v[jj] = (_Float16)W1[(kbase + jj) * 64 + s];
        B2tab[u] = *reinterpret_cast<uint4*>(v);
    } else if (t < 2240) {
        int c = t - 2048;
        int gate = c >> 6, j = c & 63;
        int rowb = (gate == 0) ? j : (gate == 1) ? (128 + j) : (192 + j);
        bsum[c] = bih[rowb] + bhh[rowb];
    }
}

// ---------------------------------------------------------------------------
// Fused LSTM step + (h @ W1) on the MATRIX pipe. Wave = 16 nodes (M-tile).
// GEMM1: gates[16,192] = X16 @ WihT  -> 12 tiles x 2 MFMA (16x16x32 f16).
// Gate tiles [i|g|o]x4 put i/g/o of one (node,j) in the SAME lane+reg ->
// transcendentals lane-local. h round-trips LDS (pad-72 rows) to re-shape
// C-layout (row=(l>>4)*4+r, col=l&15) into A-frag (m=l&15, k=8*(l>>4)+jj).
// GEMM2: hw1[16,64] = H @ W1 -> 4 tiles x 2 MFMA. fp16 in / f32 accum.
// ---------------------------------------------------------------------------
__global__ __launch_bounds__(256) void k_lstm_mm1(
    const float* __restrict__ x, const uint4* __restrict__ B1tab,
    const uint4* __restrict__ B2tab, const float* __restrict__ bsum,
    __half* __restrict__ hw1, int n)
{
    __shared__ _Float16 hs[4][16 * 72];    // per-wave h tile, rows padded to 72
    int wv   = threadIdx.x >> 6;
    int lane = threadIdx.x & 63;
    int nbase = (blockIdx.x * 4 + wv) * 16;
    if (nbase >= n) return;                // wave-uniform
    int m16 = lane & 15, q = lane >> 4;

    // A1 fragments (2 k-halves), clamped node for safe loads
    int node = nbase + m16; if (node >= n) node = n - 1;
    const float* xr = x + (size_t)node * 64 + 8 * q;
    half8 a0, a1;
#pragma unroll
    for (int jj = 0; jj < 8; jj++) a0[jj] = (_Float16)xr[jj];
#pragma unroll
    for (int jj = 0; jj < 8; jj++) a1[jj] = (_Float16)xr[32 + jj];

    // GEMM1: 12 col-tiles (i0..3, g0..3, o0..3), K=64
    f32x4 c1[12];
#pragma unroll
    for (int t = 0; t < 12; t++) {
        f32x4 acc = {0.f, 0.f, 0.f, 0.f};
        half8 b0 = __builtin_bit_cast(half8, B1tab[(t * 2 + 0) * 64 + lane]);
        half8 b1 = __builtin_bit_cast(half8, B1tab[(t * 2 + 1) * 64 + lane]);
        acc = __builtin_amdgcn_mfma_f32_16x16x32_f16(a0, b0, acc, 0, 0, 0);
        acc = __builtin_amdgcn_mfma_f32_16x16x32_f16(a1, b1, acc, 0, 0, 0);
        c1[t] = acc;
    }

    // biases + transcendentals -> h into LDS (C-layout scatter)
#pragma unroll
    for (int tj = 0; tj < 4; tj++) {
        int j = 16 * tj + m16;
        float bi = bsum[j], bg = bsum[64 + j], bo = bsum[128 + j];
#pragma unroll
        for (int r = 0; r < 4; r++) {
            float gi = c1[tj][r]     + bi;
            float gg = c1[4 + tj][r] + bg;
            float go = c1[8 + tj][r] + bo;
            float cc = fast_sigmoid(gi) * fast_tanh(gg);
            float h  = fast_sigmoid(go) * fast_tanh(cc);
            hs[wv][(q * 4 + r) * 72 + j] = (_Float16)h;
        }
    }

    // GEMM2: A2 fragments from LDS (same-wave ds ordering, as r15)
    half8 a20 = __builtin_bit_cast(half8,
        *reinterpret_cast<const uint4*>(&hs[wv][m16 * 72 + 8 * q]));
    half8 a21 = __builtin_bit_cast(half8,
        *reinterpret_cast<const uint4*>(&hs[wv][m16 * 72 + 32 + 8 * q]));

    f32x4 c2[4];
#pragma unroll
    for (int t = 0; t < 4; t++) {
        f32x4 acc = {0.f, 0.f, 0.f, 0.f};
        half8 b0 = __builtin_bit_cast(half8, B2tab[(t * 2 + 0) * 64 + lane]);
        half8 b1 = __builtin_bit_cast(half8, B2tab[(t * 2 + 1) * 64 + lane]);
        acc = __builtin_amdgcn_mfma_f32_16x16x32_f16(a20, b0, acc, 0, 0, 0);
        acc = __builtin_amdgcn_mfma_f32_16x16x32_f16(a21, b1, acc, 0, 0, 0);
        c2[t] = acc;
    }

    // store hw1 (fp16), C-layout: node = nbase + q*4 + r, col = 16t + m16
#pragma unroll
    for (int t = 0; t < 4; t++) {
#pragma unroll
        for (int r = 0; r < 4; r++) {
            int nd = nbase + q * 4 + r;
            if (nd < n)
                hw1[(size_t)nd * 64 + 16 * t + m16] = __float2half(c2[t][r]);
        }
    }
}

// ---------------------------------------------------------------------------
// Pull aggregation, F=64 -- 2 nodes/wave, half2-packed gathers (r16, proven).
// ---------------------------------------------------------------------------
__global__ __launch_bounds__(256) void k_pull64(
    const __half* __restrict__ hw, const int* __restrict__ off,
    const int* __restrict__ nbr, const float* __restrict__ dinv,
    const float* __restrict__ b1, float* __restrict__ h1, int n)
{
    int w    = (blockIdx.x * 256 + threadIdx.x) >> 6;   // wave id
    int lane = threadIdx.x & 63;
    int half = lane >> 5;
    int fp   = lane & 31;              // features 2fp, 2fp+1
    if (w * 2 >= n) return;            // wave-uniform
    int node = w * 2 + half;
    bool alive = node < n;
    int s = 0, e = 0;
    if (alive) { s = off[node]; e = off[node + 1]; }

    float ax0 = 0.f, ay0 = 0.f, ax1 = 0.f, ay1 = 0.f;
    float ax2 = 0.f, ay2 = 0.f, ax3 = 0.f, ay3 = 0.f;

    for (int base = s; base < e; base += 32) {
        int t = base + fp;
        int idx = 0; float wv = 0.f;
        if (t < e) { idx = nbr[t]; wv = dinv[idx]; }
        int cnt = e - base; if (cnt > 32) cnt = 32;

        int k = 0;
        for (; k + 4 <= cnt; k += 4) {
            int   r0 = __shfl(idx, k + 0, 32); float w0 = __shfl(wv, k + 0, 32);
            int   r1 = __shfl(idx, k + 1, 32); float w1 = __shfl(wv, k + 1, 32);
            int   r2 = __shfl(idx, k + 2, 32); float w2 = __shfl(wv, k + 2, 32);
            int   r3 = __shfl(idx, k + 3, 32); float w3 = __shfl(wv, k + 3, 32);
            unsigned u0 = reinterpret_cast<const unsigned*>(hw + (size_t)r0 * 64)[fp];
            unsigned u1 = reinterpret_cast<const unsigned*>(hw + (size_t)r1 * 64)[fp];
            unsigned u2 = reinterpret_cast<const unsigned*>(hw + (size_t)r2 * 64)[fp];
            unsigned u3 = reinterpret_cast<const unsigned*>(hw + (size_t)r3 * 64)[fp];
            float2 f0 = h2f2_(u0), f1 = h2f2_(u1), f2 = h2f2_(u2), f3 = h2f2_(u3);
            ax0 = fmaf(f0.x, w0, ax0); ay0 = fmaf(f0.y, w0, ay0);
            ax1 = fmaf(f1.x, w1, ax1); ay1 = fmaf(f1.y, w1, ay1);
            ax2 = fmaf(f2.x, w2, ax2); ay2 = fmaf(f2.y, w2, ay2);
            ax3 = fmaf(f3.x, w3, ax3); ay3 = fmaf(f3.y, w3, ay3);
        }
        for (; k < cnt; k++) {
            int   r0 = __shfl(idx, k, 32);
            float w0 = __shfl(wv, k, 32);
            unsigned u0 = reinterpret_cast<const unsigned*>(hw + (size_t)r0 * 64)[fp];
            float2 f0 = h2f2_(u0);
            ax0 = fmaf(f0.x, w0, ax0); ay0 = fmaf(f0.y, w0, ay0);
        }
    }

    if (alive) {
        float ax = (ax0 + ax1) + (ax2 + ax3);
        float ay = (ay0 + ay1) + (ay2 + ay3);
        float dc = dinv[node];
        unsigned su = reinterpret_cast<const unsigned*>(hw + (size_t)node * 64)[fp];
        float2 sf = h2f2_(su);
        float2 bb = reinterpret_cast<const float2*>(b1)[fp];
        float vx = fmaxf(ax * dc + sf.x * dc * dc + bb.x, 0.0f);
        float vy = fmaxf(ay * dc + sf.y * dc * dc + bb.y, 0.0f);
        reinterpret_cast<float2*>(h1 + (size_t)node * 64)[fp] = make_float2(vx, vy);
    }
}

// ---------------------------------------------------------------------------
// Pull aggregation, F=32. FP16 source rows (64B/row), f32 accumulation,
// FP16 z output. Halves on alternate neighbors.
// ---------------------------------------------------------------------------
__global__ __launch_bounds__(256) void k_pull32(
    const __half* __restrict__ hw, const int* __restrict__ off,
    const int* __restrict__ nbr, const float* __restrict__ dinv,
    const float* __restrict__ b2, __half* __restrict__ z, int n)
{
    int node = (blockIdx.x * 256 + threadIdx.x) >> 6;
    int lane = threadIdx.x & 63;
    int feat = lane & 31;
    int half = lane >> 5;
    if (node >= n) return;
    int s = off[node], e = off[node + 1];

    float a0 = 0.f, a1 = 0.f;
    for (int base = s; base < e; base += 64) {
        int t = base + lane;
        int idx = 0; float wv = 0.f;
        if (t < e) { idx = nbr[t]; wv = dinv[idx]; }
        int cnt = e - base; if (cnt > 64) cnt = 64;
        int cntp = (cnt + 1) & ~1;         // pad to even (pad lanes are zero)

        int j = half;
        for (; j + 2 < cntp; j += 4) {     // 2 neighbors per half per iter
            int   ra = __shfl(idx, j, 64);
            int   rb = __shfl(idx, j + 2, 64);
            float wa = __shfl(wv, j, 64);
            float wb = __shfl(wv, j + 2, 64);
            float va = __half2float(hw[(size_t)ra * 32 + feat]);
            float vb = __half2float(hw[(size_t)rb * 32 + feat]);
            a0 = fmaf(va, wa, a0);
            a1 = fmaf(vb, wb, a1);
        }
        for (; j < cntp; j += 2) {
            int   r = __shfl(idx, j, 64);
            float w = __shfl(wv, j, 64);
            a0 = fmaf(__half2float(hw[(size_t)r * 32 + feat]), w, a0);
        }
    }

    float acc = a0 + a1;
    acc += __shfl_xor(acc, 32, 64);        // combine even/odd halves
    float dc = dinv[node];
    float v = acc * dc + __half2float(hw[(size_t)node * 32 + feat]) * dc * dc + b2[feat];
    if (half == 0) z[(size_t)node * 32 + feat] = __float2half(v);
}

// ---------------------------------------------------------------------------
// hw2 = h1 @ W2  ([n,64] x [64,32]). f32 compute, FP16 output rows.
// ---------------------------------------------------------------------------
__global__ __launch_bounds__(128) void k_mm2(
    const float* __restrict__ h1, const float* __restrict__ W2,
    __half* __restrict__ hw2, int n)
{
    __shared__ float tile[128 * 65];
    int base  = blockIdx.x * 128;
    int nrows = n - base; if (nrows > 128) nrows = 128;

    for (int idx = threadIdx.x; idx < nrows * 64; idx += 128) {
        int r = idx >> 6, c = idx & 63;
        tile[r * 65 + c] = h1[(size_t)base * 64 + idx];
    }
    __syncthreads();

    int node = base + threadIdx.x;
    if (node >= n) return;

    const float* hrow = &tile[threadIdx.x * 65];
    float acc[32];
#pragma unroll
    for (int s = 0; s < 32; s++) acc[s] = 0.0f;

    for (int k = 0; k < 64; k++) {
        float hk = hrow[k];
        const float* w = W2 + (size_t)k * 32;
#pragma unroll
        for (int s = 0; s < 32; s++) acc[s] = fmaf(hk, w[s], acc[s]);
    }

    uint2* op = reinterpret_cast<uint2*>(hw2 + (size_t)node * 32);
#pragma unroll
    for (int q = 0; q < 8; q++) {
        __half2 lo(__float2half(acc[4*q+0]), __float2half(acc[4*q+1]));
        __half2 hi(__float2half(acc[4*q+2]), __float2half(acc[4*q+3]));
        op[q] = make_uint2(__builtin_bit_cast(unsigned, lo),
                           __builtin_bit_cast(unsigned, hi));
    }
}

// ---------------------------------------------------------------------------
// out[e] = dot(z[src[e]], z[dst[e]]) over 32 features; z is FP16.
// Row = 32 halves = 64B = 4 x uint4.
// ---------------------------------------------------------------------------
__global__ void k_dot(const __half* __restrict__ z, const int* __restrict__ src,
                      const int* __restrict__ dst, float* __restrict__ out, int EL)
{
    int e = blockIdx.x * 256 + threadIdx.x;
    if (e >= EL) return;
    const uint4* a = reinterpret_cast<const uint4*>(z + (size_t)src[e] * 32);
    const uint4* b = reinterpret_cast<const uint4*>(z + (size_t)dst[e] * 32);
    float s = 0.0f;
#pragma unroll
    for (int q = 0; q < 4; q++) {
        uint4 av = a[q], bv = b[q];
        s = fdot2_(av.x, bv.x, s);
        s = fdot2_(av.y, bv.y, s);
        s = fdot2_(av.z, bv.z, s);
        s = fdot2_(av.w, bv.w, s);
    }
    out[e] = s;
}

extern "C" void kernel_launch(void* const* d_in, const int* in_sizes, int n_in,
                              void* d_out, int out_size, void* d_ws, size_t ws_size,
                              hipStream_t stream)
{
    const float* x   = (const float*)d_in[0];
    const int*   ei  = (const int*)d_in[1];
    const int*   eli = (const int*)d_in[2];
    const float* Wih = (const float*)d_in[3];
    // d_in[4] = W_hh: mathematically dead (h0 = c0 = 0)
    const float* bih = (const float*)d_in[5];
    const float* bhh = (const float*)d_in[6];
    const float* W1  = (const float*)d_in[7];
    const float* b1  = (const float*)d_in[8];
    const float* W2  = (const float*)d_in[9];
    const float* b2  = (const float*)d_in[10];

    int n  = in_sizes[0] / 64;
    int E  = in_sizes[1] / 2;
    int EL = in_sizes[2] / 2;

    const int* row  = ei;          // source
    const int* col  = ei + E;      // destination
    const int* lsrc = eli;
    const int* ldst = eli + EL;
    float* out = (float*)d_out;

    // Workspace layout (liveness-aliased):
    //   bufA [n*64 f32 region]: ebuf int2[E] (bin..csr), hw1 FP16
    //                           (lstm..pull64), hw2 FP16 (mm2..pull32)
    //   bufB [n*64 f32 region]: h1 f32 (pull64..mm2), z FP16 (pull32..dot)
    //   dinv [n] | B1tab [1536 uint4] | B2tab [512 uint4] | bsum [192]
    //   off [n+1] | nbr [E] | bdeg [256] | boff [257] | gcur [nbuck*16]
    float*    bufA  = (float*)d_ws;
    float*    bufB  = bufA + (size_t)n * 64;
    float*    dinv  = bufB + (size_t)n * 64;
    uintptr_t pal   = ((uintptr_t)(dinv + n) + 15) & ~(uintptr_t)15;
    uint4*    B1tab = (uint4*)pal;
    uint4*    B2tab = B1tab + 1536;
    float*    bsum  = (float*)(B2tab + 512);
    int*      off   = (int*)(bsum + 192);
    int*      nbr   = off + (n + 1);
    int*      bdeg  = nbr + E;
    int*      boff  = bdeg + 256;
    int*      gcur  = boff + 257;
    int2*     ebuf  = (int2*)bufA;    // dead until k_lstm_mm1 writes hw1
    __half*   hw1h  = (__half*)bufA;
    __half*   hw2h  = (__half*)bufA;  // hw1 dead by the time mm2 writes
    float*    h1    = bufB;
    __half*   zh    = (__half*)bufB;  // h1 dead by the time pull32 writes

    int nbuck   = (n + (1 << NBSH) - 1) >> NBSH;   // 196 buckets (<=256)
    int eblocks = (E + CH - 1) / CH;               // 391
    dim3 blk(256);

    // --- MFMA B-fragment tables + bias pack (2240 threads, one-time) ---
    k_tr<<<dim3(9), blk, 0, stream>>>(Wih, W1, bih, bhh, B1tab, B2tab, bsum);

    // --- CSR build: bucket histogram -> scan -> binned partition -> per-
    //     bucket finalize (off/dinv/nbr; LDS atomics only) ---
    hipMemsetAsync(bdeg, 0, 256 * sizeof(int), stream);
    k_bhist<<<dim3(eblocks), blk, 0, stream>>>(col, bdeg, E, nbuck);
    k_bscan<<<dim3(1), blk, 0, stream>>>(bdeg, boff, gcur, nbuck, E);
    k_bin  <<<dim3(eblocks), blk, 0, stream>>>(row, col, gcur, ebuf, E, nbuck);
    k_csr  <<<dim3(nbuck), dim3(512), 0, stream>>>(ebuf, boff, off, dinv, nbr, n, nbuck, E);

    // --- LSTM + first matmul on MFMA: hw1 (fp16) -> bufA (ebuf dead) ---
    {
        int blocks = (n + 63) / 64;    // 16 nodes/wave, 4 waves/block
        k_lstm_mm1<<<dim3(blocks), blk, 0, stream>>>(x, B1tab, B2tab, bsum, hw1h, n);
    }

    // --- GCN1: pull + fused epilogue (relu) : h1 (f32) -> bufB ---
    {
        int blocks = (n + 7) / 8;
        k_pull64<<<dim3(blocks), blk, 0, stream>>>(hw1h, off, nbr, dinv, b1, h1, n);
    }

    // --- second matmul: hw2 (fp16) -> bufA (hw1 dead) ---
    k_mm2<<<dim3((n + 127) / 128), dim3(128), 0, stream>>>(h1, W2, hw2h, n);

    // --- GCN2: pull + fused epilogue : z (fp16) -> bufB (h1 dead) ---
    {
        int blocks = (int)(((size_t)n * 64 + 255) / 256);
        k_pull32<<<dim3(blocks), blk, 0, stream>>>(hw2h, off, nbr, dinv, b2, zh, n);
    }

    // --- edge dot products ---
    k_dot<<<dim3((EL + 255) / 256), blk, 0, stream>>>(zh, lsrc, ldst, out, EL);
}

// Round 18
// 198.948 us; speedup vs baseline: 2.6386x; 1.0844x over previous
//
#include <hip/hip_runtime.h>
#include <hip/hip_bf16.h>
#include <hip/hip_fp16.h>
#include <math.h>
#include <stdint.h>

#define NBSH 9        // 512 destination cols per bucket
#define CH   4096     // edges staged per k_bin block

typedef _Float16 h2v  __attribute__((ext_vector_type(2)));
typedef _Float16 half8 __attribute__((ext_vector_type(8)));
typedef float    f32x4 __attribute__((ext_vector_type(4)));

__device__ __forceinline__ float fdot2_(unsigned a, unsigned b, float c) {
    return __builtin_amdgcn_fdot2(__builtin_bit_cast(h2v, a),
                                  __builtin_bit_cast(h2v, b), c, false);
}

__device__ __forceinline__ float2 h2f2_(unsigned u) {
    return __half22float2(__builtin_bit_cast(__half2, u));
}

// Fast device transcendentals: native v_exp_f32 + v_rcp_f32.
__device__ __forceinline__ float fast_sigmoid(float x) {
    float t = __expf(x);
    return 1.0f - __builtin_amdgcn_rcpf(1.0f + t);
}
__device__ __forceinline__ float fast_tanh(float x) {
    float t = __expf(2.0f * x);
    return 1.0f - 2.0f * __builtin_amdgcn_rcpf(1.0f + t);
}

// ---------------------------------------------------------------------------
// Bucket histogram: per-block LDS histogram of col>>NBSH, then ONE global
// atomic per (bucket, block). bdeg must be zeroed first.
// ---------------------------------------------------------------------------
__global__ __launch_bounds__(256) void k_bhist(const int* __restrict__ col,
        int* __restrict__ bdeg, int E, int nbuck) {
    __shared__ int cnt[256];
    cnt[threadIdx.x] = 0;
    __syncthreads();
    int base = blockIdx.x * CH;
    int end  = base + CH; if (end > E) end = E;
    for (int t = base + (int)threadIdx.x; t < end; t += 256)
        atomicAdd(&cnt[col[t] >> NBSH], 1);
    __syncthreads();
    if ((int)threadIdx.x < nbuck && cnt[threadIdx.x] > 0)
        atomicAdd(&bdeg[threadIdx.x], cnt[threadIdx.x]);
}

// ---------------------------------------------------------------------------
// Single-block scan of bucket sizes -> boff[0..nbuck]; inits padded k_bin
// cursors (gcur[b*16] = boff[b]).
// ---------------------------------------------------------------------------
__global__ __launch_bounds__(256) void k_bscan(const int* __restrict__ bdeg,
        int* __restrict__ boff, int* __restrict__ gcur, int nbuck, int E) {
    __shared__ int tmp[256];
    int tid = threadIdx.x;
    int v = (tid < nbuck) ? bdeg[tid] : 0;
    tmp[tid] = v;
    __syncthreads();
#pragma unroll
    for (int s = 1; s < 256; s <<= 1) {
        int t = (tid >= s) ? tmp[tid - s] : 0;
        __syncthreads();
        tmp[tid] += t;
        __syncthreads();
    }
    if (tid < nbuck) {
        int o = tmp[tid] - v;
        boff[tid] = o;
        gcur[tid * 16] = o;
    }
    if (tid == 0) boff[nbuck] = E;
}

// ---------------------------------------------------------------------------
// Pass 1: LDS-binned partition of edges into 512-col buckets (proven r13/14).
// ---------------------------------------------------------------------------
__global__ __launch_bounds__(256) void k_bin(
    const int* __restrict__ row, const int* __restrict__ col,
    int* __restrict__ gcur, int2* __restrict__ ebuf, int E, int nbuck)
{
    __shared__ int  cnt[256], lofs[256], gbase[256], cur2[256];
    __shared__ int2 stage[CH];
    int tid  = threadIdx.x;
    int base = blockIdx.x * CH;
    int ned  = E - base; if (ned > CH) ned = CH;

    cnt[tid] = 0;
    __syncthreads();

    int r[16], c[16], b[16];
#pragma unroll
    for (int i = 0; i < 16; i++) {
        int idx = i * 256 + tid;
        if (idx < ned) {
            r[i] = row[base + idx];
            c[i] = col[base + idx];
            b[i] = c[i] >> NBSH;
            atomicAdd(&cnt[b[i]], 1);
        } else { r[i] = 0; c[i] = 0; b[i] = -1; }
    }
    __syncthreads();

    int v = cnt[tid];
    lofs[tid] = v;
    __syncthreads();
#pragma unroll
    for (int s = 1; s < 256; s <<= 1) {
        int t = (tid >= s) ? lofs[tid - s] : 0;
        __syncthreads();
        lofs[tid] += t;
        __syncthreads();
    }
    int excl = lofs[tid] - v;
    __syncthreads();
    lofs[tid] = excl;
    cur2[tid] = excl;
    if (tid < nbuck && v > 0)
        gbase[tid] = atomicAdd(&gcur[tid * 16], v);   // padded: no hot line
    __syncthreads();

#pragma unroll
    for (int i = 0; i < 16; i++) {
        if (b[i] >= 0) {
            int p = atomicAdd(&cur2[b[i]], 1);
            stage[p] = make_int2(r[i], c[i]);
        }
    }
    __syncthreads();

    for (int i = tid; i < ned; i += 256) {
        int2 rc = stage[i];
        int bb = rc.y >> NBSH;
        ebuf[gbase[bb] + (i - lofs[bb])] = rc;
    }
}

// ---------------------------------------------------------------------------
// Pass 2: per-bucket CSR finalize (off/dinv/nbr; LDS atomics only).
// ---------------------------------------------------------------------------
__global__ __launch_bounds__(512) void k_csr(
    const int2* __restrict__ ebuf, const int* __restrict__ boff,
    int* __restrict__ off, float* __restrict__ dinv,
    int* __restrict__ nbr, int n, int nbuck, int E)
{
    __shared__ int cnt[512], lofs[512];
    int b   = blockIdx.x;
    int tid = threadIdx.x;
    int c0  = b << NBSH;
    int nn  = n - c0; if (nn > 512) nn = 512; if (nn < 0) nn = 0;
    int lo  = boff[b], hi = boff[b + 1];

    cnt[tid] = 0;
    __syncthreads();
    for (int t = lo + tid; t < hi; t += 512)
        atomicAdd(&cnt[ebuf[t].y & 511], 1);
    __syncthreads();

    int v = cnt[tid];
    lofs[tid] = v;
    __syncthreads();
#pragma unroll
    for (int s = 1; s < 512; s <<= 1) {
        int t = (tid >= s) ? lofs[tid - s] : 0;
        __syncthreads();
        lofs[tid] += t;
        __syncthreads();
    }
    int excl = lofs[tid] - v;
    __syncthreads();

    if (tid < nn) {
        off[c0 + tid]  = lo + excl;
        dinv[c0 + tid] = 1.0f / sqrtf((float)(v + 1));
    }
    if (b == nbuck - 1 && tid == 0) off[n] = E;

    cnt[tid] = excl;                       // reuse as LDS cursors
    __syncthreads();
    for (int t = lo + tid; t < hi; t += 512) {
        int2 rc = ebuf[t];
        int p = atomicAdd(&cnt[rc.y & 511], 1);
        nbr[lo + p] = rc.x;
    }
}

// ---------------------------------------------------------------------------
// One-time MFMA B-fragment tables + combined bias (r17, proven).
// ---------------------------------------------------------------------------
__global__ void k_tr(const float* __restrict__ Wih, const float* __restrict__ W1,
                     const float* __restrict__ bih, const float* __restrict__ bhh,
                     uint4* __restrict__ B1tab, uint4* __restrict__ B2tab,
                     float* __restrict__ bsum) {
    int t = blockIdx.x * 256 + threadIdx.x;
    if (t < 1536) {
        int e = t >> 6, l = t & 63;
        int tt = e >> 1, kh = e & 1;
        int gate = tt >> 2, tj = tt & 3;
        int j = 16 * tj + (l & 15);
        int rowb = (gate == 0) ? j : (gate == 1) ? (128 + j) : (192 + j);
        int kbase = kh * 32 + 8 * (l >> 4);
        _Float16 v[8];
#pragma unroll
        for (int jj = 0; jj < 8; jj++)
            v[jj] = (_Float16)Wih[rowb * 64 + kbase + jj];
        B1tab[t] = *reinterpret_cast<uint4*>(v);
    } else if (t < 2048) {
        int u = t - 1536;
        int e = u >> 6, l = u & 63;
        int tt = e >> 1, kh = e & 1;
        int s = 16 * tt + (l & 15);
        int kbase = kh * 32 + 8 * (l >> 4);
        _Float16 v[8];
#pragma unroll
        for (int jj = 0; jj < 8; jj++)
            v[jj] = (_Float16)W1[(kbase + jj) * 64 + s];
        B2tab[u] = *reinterpret_cast<uint4*>(v);
    } else if (t < 2240) {
        int c = t - 2048;
        int gate = c >> 6, j = c & 63;
        int rowb = (gate == 0) ? j : (gate == 1) ? (128 + j) : (192 + j);
        bsum[c] = bih[rowb] + bhh[rowb];
    }
}

// ---------------------------------------------------------------------------
// Fused LSTM step + (h @ W1) on the MATRIX pipe (r17, proven).
// ---------------------------------------------------------------------------
__global__ __launch_bounds__(256) void k_lstm_mm1(
    const float* __restrict__ x, const uint4* __restrict__ B1tab,
    const uint4* __restrict__ B2tab, const float* __restrict__ bsum,
    __half* __restrict__ hw1, int n)
{
    __shared__ _Float16 hs[4][16 * 72];    // per-wave h tile, rows padded to 72
    int wv   = threadIdx.x >> 6;
    int lane = threadIdx.x & 63;
    int nbase = (blockIdx.x * 4 + wv) * 16;
    if (nbase >= n) return;                // wave-uniform
    int m16 = lane & 15, q = lane >> 4;

    int node = nbase + m16; if (node >= n) node = n - 1;
    const float* xr = x + (size_t)node * 64 + 8 * q;
    half8 a0, a1;
#pragma unroll
    for (int jj = 0; jj < 8; jj++) a0[jj] = (_Float16)xr[jj];
#pragma unroll
    for (int jj = 0; jj < 8; jj++) a1[jj] = (_Float16)xr[32 + jj];

    f32x4 c1[12];
#pragma unroll
    for (int t = 0; t < 12; t++) {
        f32x4 acc = {0.f, 0.f, 0.f, 0.f};
        half8 b0 = __builtin_bit_cast(half8, B1tab[(t * 2 + 0) * 64 + lane]);
        half8 b1 = __builtin_bit_cast(half8, B1tab[(t * 2 + 1) * 64 + lane]);
        acc = __builtin_amdgcn_mfma_f32_16x16x32_f16(a0, b0, acc, 0, 0, 0);
        acc = __builtin_amdgcn_mfma_f32_16x16x32_f16(a1, b1, acc, 0, 0, 0);
        c1[t] = acc;
    }

#pragma unroll
    for (int tj = 0; tj < 4; tj++) {
        int j = 16 * tj + m16;
        float bi = bsum[j], bg = bsum[64 + j], bo = bsum[128 + j];
#pragma unroll
        for (int r = 0; r < 4; r++) {
            float gi = c1[tj][r]     + bi;
            float gg = c1[4 + tj][r] + bg;
            float go = c1[8 + tj][r] + bo;
            float cc = fast_sigmoid(gi) * fast_tanh(gg);
            float h  = fast_sigmoid(go) * fast_tanh(cc);
            hs[wv][(q * 4 + r) * 72 + j] = (_Float16)h;
        }
    }

    half8 a20 = __builtin_bit_cast(half8,
        *reinterpret_cast<const uint4*>(&hs[wv][m16 * 72 + 8 * q]));
    half8 a21 = __builtin_bit_cast(half8,
        *reinterpret_cast<const uint4*>(&hs[wv][m16 * 72 + 32 + 8 * q]));

    f32x4 c2[4];
#pragma unroll
    for (int t = 0; t < 4; t++) {
        f32x4 acc = {0.f, 0.f, 0.f, 0.f};
        half8 b0 = __builtin_bit_cast(half8, B2tab[(t * 2 + 0) * 64 + lane]);
        half8 b1 = __builtin_bit_cast(half8, B2tab[(t * 2 + 1) * 64 + lane]);
        acc = __builtin_amdgcn_mfma_f32_16x16x32_f16(a20, b0, acc, 0, 0, 0);
        acc = __builtin_amdgcn_mfma_f32_16x16x32_f16(a21, b1, acc, 0, 0, 0);
        c2[t] = acc;
    }

#pragma unroll
    for (int t = 0; t < 4; t++) {
#pragma unroll
        for (int r = 0; r < 4; r++) {
            int nd = nbase + q * 4 + r;
            if (nd < n)
                hw1[(size_t)nd * 64 + 16 * t + m16] = __float2half(c2[t][r]);
        }
    }
}

// ---------------------------------------------------------------------------
// Pull aggregation, F=64 -- 2 nodes/wave, half2-packed gathers (r16, proven).
// ---------------------------------------------------------------------------
__global__ __launch_bounds__(256) void k_pull64(
    const __half* __restrict__ hw, const int* __restrict__ off,
    const int* __restrict__ nbr, const float* __restrict__ dinv,
    const float* __restrict__ b1, float* __restrict__ h1, int n)
{
    int w    = (blockIdx.x * 256 + threadIdx.x) >> 6;   // wave id
    int lane = threadIdx.x & 63;
    int half = lane >> 5;
    int fp   = lane & 31;              // features 2fp, 2fp+1
    if (w * 2 >= n) return;            // wave-uniform
    int node = w * 2 + half;
    bool alive = node < n;
    int s = 0, e = 0;
    if (alive) { s = off[node]; e = off[node + 1]; }

    float ax0 = 0.f, ay0 = 0.f, ax1 = 0.f, ay1 = 0.f;
    float ax2 = 0.f, ay2 = 0.f, ax3 = 0.f, ay3 = 0.f;

    for (int base = s; base < e; base += 32) {
        int t = base + fp;
        int idx = 0; float wv = 0.f;
        if (t < e) { idx = nbr[t]; wv = dinv[idx]; }
        int cnt = e - base; if (cnt > 32) cnt = 32;

        int k = 0;
        for (; k + 4 <= cnt; k += 4) {
            int   r0 = __shfl(idx, k + 0, 32); float w0 = __shfl(wv, k + 0, 32);
            int   r1 = __shfl(idx, k + 1, 32); float w1 = __shfl(wv, k + 1, 32);
            int   r2 = __shfl(idx, k + 2, 32); float w2 = __shfl(wv, k + 2, 32);
            int   r3 = __shfl(idx, k + 3, 32); float w3 = __shfl(wv, k + 3, 32);
            unsigned u0 = reinterpret_cast<const unsigned*>(hw + (size_t)r0 * 64)[fp];
            unsigned u1 = reinterpret_cast<const unsigned*>(hw + (size_t)r1 * 64)[fp];
            unsigned u2 = reinterpret_cast<const unsigned*>(hw + (size_t)r2 * 64)[fp];
            unsigned u3 = reinterpret_cast<const unsigned*>(hw + (size_t)r3 * 64)[fp];
            float2 f0 = h2f2_(u0), f1 = h2f2_(u1), f2 = h2f2_(u2), f3 = h2f2_(u3);
            ax0 = fmaf(f0.x, w0, ax0); ay0 = fmaf(f0.y, w0, ay0);
            ax1 = fmaf(f1.x, w1, ax1); ay1 = fmaf(f1.y, w1, ay1);
            ax2 = fmaf(f2.x, w2, ax2); ay2 = fmaf(f2.y, w2, ay2);
            ax3 = fmaf(f3.x, w3, ax3); ay3 = fmaf(f3.y, w3, ay3);
        }
        for (; k < cnt; k++) {
            int   r0 = __shfl(idx, k, 32);
            float w0 = __shfl(wv, k, 32);
            unsigned u0 = reinterpret_cast<const unsigned*>(hw + (size_t)r0 * 64)[fp];
            float2 f0 = h2f2_(u0);
            ax0 = fmaf(f0.x, w0, ax0); ay0 = fmaf(f0.y, w0, ay0);
        }
    }

    if (alive) {
        float ax = (ax0 + ax1) + (ax2 + ax3);
        float ay = (ay0 + ay1) + (ay2 + ay3);
        float dc = dinv[node];
        unsigned su = reinterpret_cast<const unsigned*>(hw + (size_t)node * 64)[fp];
        float2 sf = h2f2_(su);
        float2 bb = reinterpret_cast<const float2*>(b1)[fp];
        float vx = fmaxf(ax * dc + sf.x * dc * dc + bb.x, 0.0f);
        float vy = fmaxf(ay * dc + sf.y * dc * dc + bb.y, 0.0f);
        reinterpret_cast<float2*>(h1 + (size_t)node * 64)[fp] = make_float2(vx, vy);
    }
}

// ---------------------------------------------------------------------------
// Pull aggregation, F=32 -- 4 NODES PER WAVE, half2-packed gathers (the r16
// pull64 transform applied here). Quarter-wave (16 lanes) per node;
// fp = lane&15 covers features 2fp,2fp+1. One load instruction fetches FOUR
// full 64B rows (256B/instr, was 128B); indices broadcast via width-16 shfl
// (quarter-local). 4-slot unroll -> 16 edges in flight per wave.
// Fused epilogue 2: z = agg*dc + hw2*dc^2 + b2 (fp16 out, coalesced half2).
// ---------------------------------------------------------------------------
__global__ __launch_bounds__(256) void k_pull32(
    const __half* __restrict__ hw, const int* __restrict__ off,
    const int* __restrict__ nbr, const float* __restrict__ dinv,
    const float* __restrict__ b2, __half* __restrict__ z, int n)
{
    int w    = (blockIdx.x * 256 + threadIdx.x) >> 6;   // wave id
    int lane = threadIdx.x & 63;
    int quad = lane >> 4;              // quarter-wave id: node select
    int fp   = lane & 15;              // features 2fp, 2fp+1
    if (w * 4 >= n) return;            // wave-uniform
    int node = w * 4 + quad;
    bool alive = node < n;
    int s = 0, e = 0;
    if (alive) { s = off[node]; e = off[node + 1]; }

    float ax0 = 0.f, ay0 = 0.f, ax1 = 0.f, ay1 = 0.f;
    float ax2 = 0.f, ay2 = 0.f, ax3 = 0.f, ay3 = 0.f;

    for (int base = s; base < e; base += 16) {
        int t = base + fp;
        int idx = 0; float wv = 0.f;
        if (t < e) { idx = nbr[t]; wv = dinv[idx]; }
        int cnt = e - base; if (cnt > 16) cnt = 16;

        int k = 0;
        for (; k + 4 <= cnt; k += 4) {
            int   r0 = __shfl(idx, k + 0, 16); float w0 = __shfl(wv, k + 0, 16);
            int   r1 = __shfl(idx, k + 1, 16); float w1 = __shfl(wv, k + 1, 16);
            int   r2 = __shfl(idx, k + 2, 16); float w2 = __shfl(wv, k + 2, 16);
            int   r3 = __shfl(idx, k + 3, 16); float w3 = __shfl(wv, k + 3, 16);
            unsigned u0 = reinterpret_cast<const unsigned*>(hw + (size_t)r0 * 32)[fp];
            unsigned u1 = reinterpret_cast<const unsigned*>(hw + (size_t)r1 * 32)[fp];
            unsigned u2 = reinterpret_cast<const unsigned*>(hw + (size_t)r2 * 32)[fp];
            unsigned u3 = reinterpret_cast<const unsigned*>(hw + (size_t)r3 * 32)[fp];
            float2 f0 = h2f2_(u0), f1 = h2f2_(u1), f2 = h2f2_(u2), f3 = h2f2_(u3);
            ax0 = fmaf(f0.x, w0, ax0); ay0 = fmaf(f0.y, w0, ay0);
            ax1 = fmaf(f1.x, w1, ax1); ay1 = fmaf(f1.y, w1, ay1);
            ax2 = fmaf(f2.x, w2, ax2); ay2 = fmaf(f2.y, w2, ay2);
            ax3 = fmaf(f3.x, w3, ax3); ay3 = fmaf(f3.y, w3, ay3);
        }
        for (; k < cnt; k++) {
            int   r0 = __shfl(idx, k, 16);
            float w0 = __shfl(wv, k, 16);
            unsigned u0 = reinterpret_cast<const unsigned*>(hw + (size_t)r0 * 32)[fp];
            float2 f0 = h2f2_(u0);
            ax0 = fmaf(f0.x, w0, ax0); ay0 = fmaf(f0.y, w0, ay0);
        }
    }

    if (alive) {
        float ax = (ax0 + ax1) + (ax2 + ax3);
        float ay = (ay0 + ay1) + (ay2 + ay3);
        float dc = dinv[node];
        unsigned su = reinterpret_cast<const unsigned*>(hw + (size_t)node * 32)[fp];
        float2 sf = h2f2_(su);
        float2 bb = reinterpret_cast<const float2*>(b2)[fp];
        float vx = ax * dc + sf.x * dc * dc + bb.x;
        float vy = ay * dc + sf.y * dc * dc + bb.y;
        __half2 pk(__float2half(vx), __float2half(vy));
        reinterpret_cast<__half2*>(z + (size_t)node * 32)[fp] = pk;
    }
}

// ---------------------------------------------------------------------------
// hw2 = h1 @ W2  ([n,64] x [64,32]). f32 compute, FP16 output rows.
// ---------------------------------------------------------------------------
__global__ __launch_bounds__(128) void k_mm2(
    const float* __restrict__ h1, const float* __restrict__ W2,
    __half* __restrict__ hw2, int n)
{
    __shared__ float tile[128 * 65];
    int base  = blockIdx.x * 128;
    int nrows = n - base; if (nrows > 128) nrows = 128;

    for (int idx = threadIdx.x; idx < nrows * 64; idx += 128) {
        int r = idx >> 6, c = idx & 63;
        tile[r * 65 + c] = h1[(size_t)base * 64 + idx];
    }
    __syncthreads();

    int node = base + threadIdx.x;
    if (node >= n) return;

    const float* hrow = &tile[threadIdx.x * 65];
    float acc[32];
#pragma unroll
    for (int s = 0; s < 32; s++) acc[s] = 0.0f;

    for (int k = 0; k < 64; k++) {
        float hk = hrow[k];
        const float* w = W2 + (size_t)k * 32;
#pragma unroll
        for (int s = 0; s < 32; s++) acc[s] = fmaf(hk, w[s], acc[s]);
    }

    uint2* op = reinterpret_cast<uint2*>(hw2 + (size_t)node * 32);
#pragma unroll
    for (int q = 0; q < 8; q++) {
        __half2 lo(__float2half(acc[4*q+0]), __float2half(acc[4*q+1]));
        __half2 hi(__float2half(acc[4*q+2]), __float2half(acc[4*q+3]));
        op[q] = make_uint2(__builtin_bit_cast(unsigned, lo),
                           __builtin_bit_cast(unsigned, hi));
    }
}

// ---------------------------------------------------------------------------
// out[e] = dot(z[src[e]], z[dst[e]]) over 32 features; z is FP16.
// Row = 32 halves = 64B = 4 x uint4.
// ---------------------------------------------------------------------------
__global__ void k_dot(const __half* __restrict__ z, const int* __restrict__ src,
                      const int* __restrict__ dst, float* __restrict__ out, int EL)
{
    int e = blockIdx.x * 256 + threadIdx.x;
    if (e >= EL) return;
    const uint4* a = reinterpret_cast<const uint4*>(z + (size_t)src[e] * 32);
    const uint4* b = reinterpret_cast<const uint4*>(z + (size_t)dst[e] * 32);
    float s = 0.0f;
#pragma unroll
    for (int q = 0; q < 4; q++) {
        uint4 av = a[q], bv = b[q];
        s = fdot2_(av.x, bv.x, s);
        s = fdot2_(av.y, bv.y, s);
        s = fdot2_(av.z, bv.z, s);
        s = fdot2_(av.w, bv.w, s);
    }
    out[e] = s;
}

extern "C" void kernel_launch(void* const* d_in, const int* in_sizes, int n_in,
                              void* d_out, int out_size, void* d_ws, size_t ws_size,
                              hipStream_t stream)
{
    const float* x   = (const float*)d_in[0];
    const int*   ei  = (const int*)d_in[1];
    const int*   eli = (const int*)d_in[2];
    const float* Wih = (const float*)d_in[3];
    // d_in[4] = W_hh: mathematically dead (h0 = c0 = 0)
    const float* bih = (const float*)d_in[5];
    const float* bhh = (const float*)d_in[6];
    const float* W1  = (const float*)d_in[7];
    const float* b1  = (const float*)d_in[8];
    const float* W2  = (const float*)d_in[9];
    const float* b2  = (const float*)d_in[10];

    int n  = in_sizes[0] / 64;
    int E  = in_sizes[1] / 2;
    int EL = in_sizes[2] / 2;

    const int* row  = ei;          // source
    const int* col  = ei + E;      // destination
    const int* lsrc = eli;
    const int* ldst = eli + EL;
    float* out = (float*)d_out;

    // Workspace layout (liveness-aliased):
    //   bufA [n*64 f32 region]: ebuf int2[E] (bin..csr), hw1 FP16
    //                           (lstm..pull64), hw2 FP16 (mm2..pull32)
    //   bufB [n*64 f32 region]: h1 f32 (pull64..mm2), z FP16 (pull32..dot)
    //   dinv [n] | B1tab [1536 uint4] | B2tab [512 uint4] | bsum [192]
    //   off [n+1] | nbr [E] | bdeg [256] | boff [257] | gcur [nbuck*16]
    float*    bufA  = (float*)d_ws;
    float*    bufB  = bufA + (size_t)n * 64;
    float*    dinv  = bufB + (size_t)n * 64;
    uintptr_t pal   = ((uintptr_t)(dinv + n) + 15) & ~(uintptr_t)15;
    uint4*    B1tab = (uint4*)pal;
    uint4*    B2tab = B1tab + 1536;
    float*    bsum  = (float*)(B2tab + 512);
    int*      off   = (int*)(bsum + 192);
    int*      nbr   = off + (n + 1);
    int*      bdeg  = nbr + E;
    int*      boff  = bdeg + 256;
    int*      gcur  = boff + 257;
    int2*     ebuf  = (int2*)bufA;    // dead until k_lstm_mm1 writes hw1
    __half*   hw1h  = (__half*)bufA;
    __half*   hw2h  = (__half*)bufA;  // hw1 dead by the time mm2 writes
    float*    h1    = bufB;
    __half*   zh    = (__half*)bufB;  // h1 dead by the time pull32 writes

    int nbuck   = (n + (1 << NBSH) - 1) >> NBSH;   // 196 buckets (<=256)
    int eblocks = (E + CH - 1) / CH;               // 391
    dim3 blk(256);

    // --- MFMA B-fragment tables + bias pack (2240 threads, one-time) ---
    k_tr<<<dim3(9), blk, 0, stream>>>(Wih, W1, bih, bhh, B1tab, B2tab, bsum);

    // --- CSR build: bucket histogram -> scan -> binned partition -> per-
    //     bucket finalize (off/dinv/nbr; LDS atomics only) ---
    hipMemsetAsync(bdeg, 0, 256 * sizeof(int), stream);
    k_bhist<<<dim3(eblocks), blk, 0, stream>>>(col, bdeg, E, nbuck);
    k_bscan<<<dim3(1), blk, 0, stream>>>(bdeg, boff, gcur, nbuck, E);
    k_bin  <<<dim3(eblocks), blk, 0, stream>>>(row, col, gcur, ebuf, E, nbuck);
    k_csr  <<<dim3(nbuck), dim3(512), 0, stream>>>(ebuf, boff, off, dinv, nbr, n, nbuck, E);

    // --- LSTM + first matmul on MFMA: hw1 (fp16) -> bufA (ebuf dead) ---
    {
        int blocks = (n + 63) / 64;    // 16 nodes/wave, 4 waves/block
        k_lstm_mm1<<<dim3(blocks), blk, 0, stream>>>(x, B1tab, B2tab, bsum, hw1h, n);
    }

    // --- GCN1: pull + fused epilogue (relu) : h1 (f32) -> bufB ---
    {
        int blocks = (n + 7) / 8;      // 2 nodes/wave
        k_pull64<<<dim3(blocks), blk, 0, stream>>>(hw1h, off, nbr, dinv, b1, h1, n);
    }

    // --- second matmul: hw2 (fp16) -> bufA (hw1 dead) ---
    k_mm2<<<dim3((n + 127) / 128), dim3(128), 0, stream>>>(h1, W2, hw2h, n);

    // --- GCN2: pull + fused epilogue : z (fp16) -> bufB (h1 dead) ---
    {
        int blocks = (n + 15) / 16;    // 4 nodes/wave
        k_pull32<<<dim3(blocks), blk, 0, stream>>>(hw2h, off, nbr, dinv, b2, zh, n);
    }

    // --- edge dot products ---
    k_dot<<<dim3((EL + 255) / 256), blk, 0, stream>>>(zh, lsrc, ldst, out, EL);
}

// Round 19
// 198.569 us; speedup vs baseline: 2.6436x; 1.0019x over previous
//
#include <hip/hip_runtime.h>
#include <hip/hip_bf16.h>
#include <hip/hip_fp16.h>
#include <math.h>
#include <stdint.h>

#define NBSH 9        // 512 destination cols per bucket
#define CH   4096     // edges staged per k_bin block

typedef _Float16 h2v  __attribute__((ext_vector_type(2)));
typedef _Float16 half8 __attribute__((ext_vector_type(8)));
typedef float    f32x4 __attribute__((ext_vector_type(4)));

__device__ __forceinline__ float fdot2_(unsigned a, unsigned b, float c) {
    return __builtin_amdgcn_fdot2(__builtin_bit_cast(h2v, a),
                                  __builtin_bit_cast(h2v, b), c, false);
}

__device__ __forceinline__ float2 h2f2_(unsigned u) {
    return __half22float2(__builtin_bit_cast(__half2, u));
}

// Fast device transcendentals: native v_exp_f32 + v_rcp_f32.
__device__ __forceinline__ float fast_sigmoid(float x) {
    float t = __expf(x);
    return 1.0f - __builtin_amdgcn_rcpf(1.0f + t);
}
__device__ __forceinline__ float fast_tanh(float x) {
    float t = __expf(2.0f * x);
    return 1.0f - 2.0f * __builtin_amdgcn_rcpf(1.0f + t);
}

// ---------------------------------------------------------------------------
// Bucket histogram: per-block LDS histogram of col>>NBSH, then ONE global
// atomic per (bucket, block). bdeg must be zeroed first.
// ---------------------------------------------------------------------------
__global__ __launch_bounds__(256) void k_bhist(const int* __restrict__ col,
        int* __restrict__ bdeg, int E, int nbuck) {
    __shared__ int cnt[256];
    cnt[threadIdx.x] = 0;
    __syncthreads();
    int base = blockIdx.x * CH;
    int end  = base + CH; if (end > E) end = E;
    for (int t = base + (int)threadIdx.x; t < end; t += 256)
        atomicAdd(&cnt[col[t] >> NBSH], 1);
    __syncthreads();
    if ((int)threadIdx.x < nbuck && cnt[threadIdx.x] > 0)
        atomicAdd(&bdeg[threadIdx.x], cnt[threadIdx.x]);
}

// ---------------------------------------------------------------------------
// Single-block scan of bucket sizes -> boff[0..nbuck]; inits padded k_bin
// cursors (gcur[b*16] = boff[b]).
// ---------------------------------------------------------------------------
__global__ __launch_bounds__(256) void k_bscan(const int* __restrict__ bdeg,
        int* __restrict__ boff, int* __restrict__ gcur, int nbuck, int E) {
    __shared__ int tmp[256];
    int tid = threadIdx.x;
    int v = (tid < nbuck) ? bdeg[tid] : 0;
    tmp[tid] = v;
    __syncthreads();
#pragma unroll
    for (int s = 1; s < 256; s <<= 1) {
        int t = (tid >= s) ? tmp[tid - s] : 0;
        __syncthreads();
        tmp[tid] += t;
        __syncthreads();
    }
    if (tid < nbuck) {
        int o = tmp[tid] - v;
        boff[tid] = o;
        gcur[tid * 16] = o;
    }
    if (tid == 0) boff[nbuck] = E;
}

// ---------------------------------------------------------------------------
// Pass 1: LDS-binned partition of edges into 512-col buckets (proven r13/14).
// ---------------------------------------------------------------------------
__global__ __launch_bounds__(256) void k_bin(
    const int* __restrict__ row, const int* __restrict__ col,
    int* __restrict__ gcur, int2* __restrict__ ebuf, int E, int nbuck)
{
    __shared__ int  cnt[256], lofs[256], gbase[256], cur2[256];
    __shared__ int2 stage[CH];
    int tid  = threadIdx.x;
    int base = blockIdx.x * CH;
    int ned  = E - base; if (ned > CH) ned = CH;

    cnt[tid] = 0;
    __syncthreads();

    int r[16], c[16], b[16];
#pragma unroll
    for (int i = 0; i < 16; i++) {
        int idx = i * 256 + tid;
        if (idx < ned) {
            r[i] = row[base + idx];
            c[i] = col[base + idx];
            b[i] = c[i] >> NBSH;
            atomicAdd(&cnt[b[i]], 1);
        } else { r[i] = 0; c[i] = 0; b[i] = -1; }
    }
    __syncthreads();

    int v = cnt[tid];
    lofs[tid] = v;
    __syncthreads();
#pragma unroll
    for (int s = 1; s < 256; s <<= 1) {
        int t = (tid >= s) ? lofs[tid - s] : 0;
        __syncthreads();
        lofs[tid] += t;
        __syncthreads();
    }
    int excl = lofs[tid] - v;
    __syncthreads();
    lofs[tid] = excl;
    cur2[tid] = excl;
    if (tid < nbuck && v > 0)
        gbase[tid] = atomicAdd(&gcur[tid * 16], v);   // padded: no hot line
    __syncthreads();

#pragma unroll
    for (int i = 0; i < 16; i++) {
        if (b[i] >= 0) {
            int p = atomicAdd(&cur2[b[i]], 1);
            stage[p] = make_int2(r[i], c[i]);
        }
    }
    __syncthreads();

    for (int i = tid; i < ned; i += 256) {
        int2 rc = stage[i];
        int bb = rc.y >> NBSH;
        ebuf[gbase[bb] + (i - lofs[bb])] = rc;
    }
}

// ---------------------------------------------------------------------------
// Pass 2: per-bucket CSR finalize (off/dinv/nbr; LDS atomics only).
// ---------------------------------------------------------------------------
__global__ __launch_bounds__(512) void k_csr(
    const int2* __restrict__ ebuf, const int* __restrict__ boff,
    int* __restrict__ off, float* __restrict__ dinv,
    int* __restrict__ nbr, int n, int nbuck, int E)
{
    __shared__ int cnt[512], lofs[512];
    int b   = blockIdx.x;
    int tid = threadIdx.x;
    int c0  = b << NBSH;
    int nn  = n - c0; if (nn > 512) nn = 512; if (nn < 0) nn = 0;
    int lo  = boff[b], hi = boff[b + 1];

    cnt[tid] = 0;
    __syncthreads();
    for (int t = lo + tid; t < hi; t += 512)
        atomicAdd(&cnt[ebuf[t].y & 511], 1);
    __syncthreads();

    int v = cnt[tid];
    lofs[tid] = v;
    __syncthreads();
#pragma unroll
    for (int s = 1; s < 512; s <<= 1) {
        int t = (tid >= s) ? lofs[tid - s] : 0;
        __syncthreads();
        lofs[tid] += t;
        __syncthreads();
    }
    int excl = lofs[tid] - v;
    __syncthreads();

    if (tid < nn) {
        off[c0 + tid]  = lo + excl;
        dinv[c0 + tid] = 1.0f / sqrtf((float)(v + 1));
    }
    if (b == nbuck - 1 && tid == 0) off[n] = E;

    cnt[tid] = excl;                       // reuse as LDS cursors
    __syncthreads();
    for (int t = lo + tid; t < hi; t += 512) {
        int2 rc = ebuf[t];
        int p = atomicAdd(&cnt[rc.y & 511], 1);
        nbr[lo + p] = rc.x;
    }
}

// ---------------------------------------------------------------------------
// One-time MFMA B-fragment tables + combined bias (r17, proven).
// ---------------------------------------------------------------------------
__global__ void k_tr(const float* __restrict__ Wih, const float* __restrict__ W1,
                     const float* __restrict__ bih, const float* __restrict__ bhh,
                     uint4* __restrict__ B1tab, uint4* __restrict__ B2tab,
                     float* __restrict__ bsum) {
    int t = blockIdx.x * 256 + threadIdx.x;
    if (t < 1536) {
        int e = t >> 6, l = t & 63;
        int tt = e >> 1, kh = e & 1;
        int gate = tt >> 2, tj = tt & 3;
        int j = 16 * tj + (l & 15);
        int rowb = (gate == 0) ? j : (gate == 1) ? (128 + j) : (192 + j);
        int kbase = kh * 32 + 8 * (l >> 4);
        _Float16 v[8];
#pragma unroll
        for (int jj = 0; jj < 8; jj++)
            v[jj] = (_Float16)Wih[rowb * 64 + kbase + jj];
        B1tab[t] = *reinterpret_cast<uint4*>(v);
    } else if (t < 2048) {
        int u = t - 1536;
        int e = u >> 6, l = u & 63;
        int tt = e >> 1, kh = e & 1;
        int s = 16 * tt + (l & 15);
        int kbase = kh * 32 + 8 * (l >> 4);
        _Float16 v[8];
#pragma unroll
        for (int jj = 0; jj < 8; jj++)
            v[jj] = (_Float16)W1[(kbase + jj) * 64 + s];
        B2tab[u] = *reinterpret_cast<uint4*>(v);
    } else if (t < 2240) {
        int c = t - 2048;
        int gate = c >> 6, j = c & 63;
        int rowb = (gate == 0) ? j : (gate == 1) ? (128 + j) : (192 + j);
        bsum[c] = bih[rowb] + bhh[rowb];
    }
}

// ---------------------------------------------------------------------------
// Fused LSTM step + (h @ W1) on the MATRIX pipe (r17, proven).
// ---------------------------------------------------------------------------
__global__ __launch_bounds__(256) void k_lstm_mm1(
    const float* __restrict__ x, const uint4* __restrict__ B1tab,
    const uint4* __restrict__ B2tab, const float* __restrict__ bsum,
    __half* __restrict__ hw1, int n)
{
    __shared__ _Float16 hs[4][16 * 72];    // per-wave h tile, rows padded to 72
    int wv   = threadIdx.x >> 6;
    int lane = threadIdx.x & 63;
    int nbase = (blockIdx.x * 4 + wv) * 16;
    if (nbase >= n) return;                // wave-uniform
    int m16 = lane & 15, q = lane >> 4;

    int node = nbase + m16; if (node >= n) node = n - 1;
    const float* xr = x + (size_t)node * 64 + 8 * q;
    half8 a0, a1;
#pragma unroll
    for (int jj = 0; jj < 8; jj++) a0[jj] = (_Float16)xr[jj];
#pragma unroll
    for (int jj = 0; jj < 8; jj++) a1[jj] = (_Float16)xr[32 + jj];

    f32x4 c1[12];
#pragma unroll
    for (int t = 0; t < 12; t++) {
        f32x4 acc = {0.f, 0.f, 0.f, 0.f};
        half8 b0 = __builtin_bit_cast(half8, B1tab[(t * 2 + 0) * 64 + lane]);
        half8 b1 = __builtin_bit_cast(half8, B1tab[(t * 2 + 1) * 64 + lane]);
        acc = __builtin_amdgcn_mfma_f32_16x16x32_f16(a0, b0, acc, 0, 0, 0);
        acc = __builtin_amdgcn_mfma_f32_16x16x32_f16(a1, b1, acc, 0, 0, 0);
        c1[t] = acc;
    }

#pragma unroll
    for (int tj = 0; tj < 4; tj++) {
        int j = 16 * tj + m16;
        float bi = bsum[j], bg = bsum[64 + j], bo = bsum[128 + j];
#pragma unroll
        for (int r = 0; r < 4; r++) {
            float gi = c1[tj][r]     + bi;
            float gg = c1[4 + tj][r] + bg;
            float go = c1[8 + tj][r] + bo;
            float cc = fast_sigmoid(gi) * fast_tanh(gg);
            float h  = fast_sigmoid(go) * fast_tanh(cc);
            hs[wv][(q * 4 + r) * 72 + j] = (_Float16)h;
        }
    }

    half8 a20 = __builtin_bit_cast(half8,
        *reinterpret_cast<const uint4*>(&hs[wv][m16 * 72 + 8 * q]));
    half8 a21 = __builtin_bit_cast(half8,
        *reinterpret_cast<const uint4*>(&hs[wv][m16 * 72 + 32 + 8 * q]));

    f32x4 c2[4];
#pragma unroll
    for (int t = 0; t < 4; t++) {
        f32x4 acc = {0.f, 0.f, 0.f, 0.f};
        half8 b0 = __builtin_bit_cast(half8, B2tab[(t * 2 + 0) * 64 + lane]);
        half8 b1 = __builtin_bit_cast(half8, B2tab[(t * 2 + 1) * 64 + lane]);
        acc = __builtin_amdgcn_mfma_f32_16x16x32_f16(a20, b0, acc, 0, 0, 0);
        acc = __builtin_amdgcn_mfma_f32_16x16x32_f16(a21, b1, acc, 0, 0, 0);
        c2[t] = acc;
    }

#pragma unroll
    for (int t = 0; t < 4; t++) {
#pragma unroll
        for (int r = 0; r < 4; r++) {
            int nd = nbase + q * 4 + r;
            if (nd < n)
                hw1[(size_t)nd * 64 + 16 * t + m16] = __float2half(c2[t][r]);
        }
    }
}

// ---------------------------------------------------------------------------
// Pull aggregation, F=64 -- 4 NODES PER WAVE, uint2-packed gathers.
// Quarter-wave (16 lanes) per node; fp = lane&15 owns features 4fp..4fp+3.
// One load instruction fetches FOUR full 128B rows (512B/instr, was 256B);
// indices broadcast via width-16 shfl. 4-slot unroll -> 16 edges in
// flight/wave, ~2.75 VALU/edge (was 3.5).
// Fused epilogue 1: h1 = relu(agg*dc + hw1[node]*dc^2 + b1), float4 writes.
// ---------------------------------------------------------------------------
__global__ __launch_bounds__(256) void k_pull64(
    const __half* __restrict__ hw, const int* __restrict__ off,
    const int* __restrict__ nbr, const float* __restrict__ dinv,
    const float* __restrict__ b1, float* __restrict__ h1, int n)
{
    int w    = (blockIdx.x * 256 + threadIdx.x) >> 6;   // wave id
    int lane = threadIdx.x & 63;
    int quad = lane >> 4;              // quarter-wave id: node select
    int fp   = lane & 15;              // features 4fp .. 4fp+3
    if (w * 4 >= n) return;            // wave-uniform
    int node = w * 4 + quad;
    bool alive = node < n;
    int s = 0, e = 0;
    if (alive) { s = off[node]; e = off[node + 1]; }

    float s0x=0.f,s0y=0.f,s0z=0.f,s0w=0.f;
    float s1x=0.f,s1y=0.f,s1z=0.f,s1w=0.f;
    float s2x=0.f,s2y=0.f,s2z=0.f,s2w=0.f;
    float s3x=0.f,s3y=0.f,s3z=0.f,s3w=0.f;

    for (int base = s; base < e; base += 16) {
        int t = base + fp;
        int idx = 0; float wv = 0.f;
        if (t < e) { idx = nbr[t]; wv = dinv[idx]; }
        int cnt = e - base; if (cnt > 16) cnt = 16;

        int k = 0;
        for (; k + 4 <= cnt; k += 4) {
            int   r0 = __shfl(idx, k + 0, 16); float w0 = __shfl(wv, k + 0, 16);
            int   r1 = __shfl(idx, k + 1, 16); float w1 = __shfl(wv, k + 1, 16);
            int   r2 = __shfl(idx, k + 2, 16); float w2 = __shfl(wv, k + 2, 16);
            int   r3 = __shfl(idx, k + 3, 16); float w3 = __shfl(wv, k + 3, 16);
            uint2 u0 = reinterpret_cast<const uint2*>(hw + (size_t)r0 * 64)[fp];
            uint2 u1 = reinterpret_cast<const uint2*>(hw + (size_t)r1 * 64)[fp];
            uint2 u2 = reinterpret_cast<const uint2*>(hw + (size_t)r2 * 64)[fp];
            uint2 u3 = reinterpret_cast<const uint2*>(hw + (size_t)r3 * 64)[fp];
            float2 l0 = h2f2_(u0.x), h0 = h2f2_(u0.y);
            float2 l1 = h2f2_(u1.x), h1f = h2f2_(u1.y);
            float2 l2 = h2f2_(u2.x), h2 = h2f2_(u2.y);
            float2 l3 = h2f2_(u3.x), h3 = h2f2_(u3.y);
            s0x = fmaf(l0.x, w0, s0x); s0y = fmaf(l0.y, w0, s0y);
            s0z = fmaf(h0.x, w0, s0z); s0w = fmaf(h0.y, w0, s0w);
            s1x = fmaf(l1.x, w1, s1x); s1y = fmaf(l1.y, w1, s1y);
            s1z = fmaf(h1f.x, w1, s1z); s1w = fmaf(h1f.y, w1, s1w);
            s2x = fmaf(l2.x, w2, s2x); s2y = fmaf(l2.y, w2, s2y);
            s2z = fmaf(h2.x, w2, s2z); s2w = fmaf(h2.y, w2, s2w);
            s3x = fmaf(l3.x, w3, s3x); s3y = fmaf(l3.y, w3, s3y);
            s3z = fmaf(h3.x, w3, s3z); s3w = fmaf(h3.y, w3, s3w);
        }
        for (; k < cnt; k++) {
            int   r0 = __shfl(idx, k, 16);
            float w0 = __shfl(wv, k, 16);
            uint2 u0 = reinterpret_cast<const uint2*>(hw + (size_t)r0 * 64)[fp];
            float2 l0 = h2f2_(u0.x), h0 = h2f2_(u0.y);
            s0x = fmaf(l0.x, w0, s0x); s0y = fmaf(l0.y, w0, s0y);
            s0z = fmaf(h0.x, w0, s0z); s0w = fmaf(h0.y, w0, s0w);
        }
    }

    if (alive) {
        float ax = (s0x + s1x) + (s2x + s3x);
        float ay = (s0y + s1y) + (s2y + s3y);
        float az = (s0z + s1z) + (s2z + s3z);
        float aw = (s0w + s1w) + (s2w + s3w);
        float dc = dinv[node];
        uint2 su = reinterpret_cast<const uint2*>(hw + (size_t)node * 64)[fp];
        float2 sl = h2f2_(su.x), sh = h2f2_(su.y);
        float4 bb = reinterpret_cast<const float4*>(b1)[fp];
        float vx = fmaxf(ax * dc + sl.x * dc * dc + bb.x, 0.0f);
        float vy = fmaxf(ay * dc + sl.y * dc * dc + bb.y, 0.0f);
        float vz = fmaxf(az * dc + sh.x * dc * dc + bb.z, 0.0f);
        float vw = fmaxf(aw * dc + sh.y * dc * dc + bb.w, 0.0f);
        reinterpret_cast<float4*>(h1 + (size_t)node * 64)[fp] =
            make_float4(vx, vy, vz, vw);
    }
}

// ---------------------------------------------------------------------------
// Pull aggregation, F=32 -- 4 nodes/wave, half2-packed gathers (r18, proven).
// ---------------------------------------------------------------------------
__global__ __launch_bounds__(256) void k_pull32(
    const __half* __restrict__ hw, const int* __restrict__ off,
    const int* __restrict__ nbr, const float* __restrict__ dinv,
    const float* __restrict__ b2, __half* __restrict__ z, int n)
{
    int w    = (blockIdx.x * 256 + threadIdx.x) >> 6;   // wave id
    int lane = threadIdx.x & 63;
    int quad = lane >> 4;              // quarter-wave id: node select
    int fp   = lane & 15;              // features 2fp, 2fp+1
    if (w * 4 >= n) return;            // wave-uniform
    int node = w * 4 + quad;
    bool alive = node < n;
    int s = 0, e = 0;
    if (alive) { s = off[node]; e = off[node + 1]; }

    float ax0 = 0.f, ay0 = 0.f, ax1 = 0.f, ay1 = 0.f;
    float ax2 = 0.f, ay2 = 0.f, ax3 = 0.f, ay3 = 0.f;

    for (int base = s; base < e; base += 16) {
        int t = base + fp;
        int idx = 0; float wv = 0.f;
        if (t < e) { idx = nbr[t]; wv = dinv[idx]; }
        int cnt = e - base; if (cnt > 16) cnt = 16;

        int k = 0;
        for (; k + 4 <= cnt; k += 4) {
            int   r0 = __shfl(idx, k + 0, 16); float w0 = __shfl(wv, k + 0, 16);
            int   r1 = __shfl(idx, k + 1, 16); float w1 = __shfl(wv, k + 1, 16);
            int   r2 = __shfl(idx, k + 2, 16); float w2 = __shfl(wv, k + 2, 16);
            int   r3 = __shfl(idx, k + 3, 16); float w3 = __shfl(wv, k + 3, 16);
            unsigned u0 = reinterpret_cast<const unsigned*>(hw + (size_t)r0 * 32)[fp];
            unsigned u1 = reinterpret_cast<const unsigned*>(hw + (size_t)r1 * 32)[fp];
            unsigned u2 = reinterpret_cast<const unsigned*>(hw + (size_t)r2 * 32)[fp];
            unsigned u3 = reinterpret_cast<const unsigned*>(hw + (size_t)r3 * 32)[fp];
            float2 f0 = h2f2_(u0), f1 = h2f2_(u1), f2 = h2f2_(u2), f3 = h2f2_(u3);
            ax0 = fmaf(f0.x, w0, ax0); ay0 = fmaf(f0.y, w0, ay0);
            ax1 = fmaf(f1.x, w1, ax1); ay1 = fmaf(f1.y, w1, ay1);
            ax2 = fmaf(f2.x, w2, ax2); ay2 = fmaf(f2.y, w2, ay2);
            ax3 = fmaf(f3.x, w3, ax3); ay3 = fmaf(f3.y, w3, ay3);
        }
        for (; k < cnt; k++) {
            int   r0 = __shfl(idx, k, 16);
            float w0 = __shfl(wv, k, 16);
            unsigned u0 = reinterpret_cast<const unsigned*>(hw + (size_t)r0 * 32)[fp];
            float2 f0 = h2f2_(u0);
            ax0 = fmaf(f0.x, w0, ax0); ay0 = fmaf(f0.y, w0, ay0);
        }
    }

    if (alive) {
        float ax = (ax0 + ax1) + (ax2 + ax3);
        float ay = (ay0 + ay1) + (ay2 + ay3);
        float dc = dinv[node];
        unsigned su = reinterpret_cast<const unsigned*>(hw + (size_t)node * 32)[fp];
        float2 sf = h2f2_(su);
        float2 bb = reinterpret_cast<const float2*>(b2)[fp];
        float vx = ax * dc + sf.x * dc * dc + bb.x;
        float vy = ay * dc + sf.y * dc * dc + bb.y;
        __half2 pk(__float2half(vx), __float2half(vy));
        reinterpret_cast<__half2*>(z + (size_t)node * 32)[fp] = pk;
    }
}

// ---------------------------------------------------------------------------
// hw2 = h1 @ W2  ([n,64] x [64,32]). f32 compute, FP16 output rows.
// ---------------------------------------------------------------------------
__global__ __launch_bounds__(128) void k_mm2(
    const float* __restrict__ h1, const float* __restrict__ W2,
    __half* __restrict__ hw2, int n)
{
    __shared__ float tile[128 * 65];
    int base  = blockIdx.x * 128;
    int nrows = n - base; if (nrows > 128) nrows = 128;

    for (int idx = threadIdx.x; idx < nrows * 64; idx += 128) {
        int r = idx >> 6, c = idx & 63;
        tile[r * 65 + c] = h1[(size_t)base * 64 + idx];
    }
    __syncthreads();

    int node = base + threadIdx.x;
    if (node >= n) return;

    const float* hrow = &tile[threadIdx.x * 65];
    float acc[32];
#pragma unroll
    for (int s = 0; s < 32; s++) acc[s] = 0.0f;

    for (int k = 0; k < 64; k++) {
        float hk = hrow[k];
        const float* w = W2 + (size_t)k * 32;
#pragma unroll
        for (int s = 0; s < 32; s++) acc[s] = fmaf(hk, w[s], acc[s]);
    }

    uint2* op = reinterpret_cast<uint2*>(hw2 + (size_t)node * 32);
#pragma unroll
    for (int q = 0; q < 8; q++) {
        __half2 lo(__float2half(acc[4*q+0]), __float2half(acc[4*q+1]));
        __half2 hi(__float2half(acc[4*q+2]), __float2half(acc[4*q+3]));
        op[q] = make_uint2(__builtin_bit_cast(unsigned, lo),
                           __builtin_bit_cast(unsigned, hi));
    }
}

// ---------------------------------------------------------------------------
// out[e] = dot(z[src[e]], z[dst[e]]) over 32 features; z is FP16.
// Row = 32 halves = 64B = 4 x uint4.
// ---------------------------------------------------------------------------
__global__ void k_dot(const __half* __restrict__ z, const int* __restrict__ src,
                      const int* __restrict__ dst, float* __restrict__ out, int EL)
{
    int e = blockIdx.x * 256 + threadIdx.x;
    if (e >= EL) return;
    const uint4* a = reinterpret_cast<const uint4*>(z + (size_t)src[e] * 32);
    const uint4* b = reinterpret_cast<const uint4*>(z + (size_t)dst[e] * 32);
    float s = 0.0f;
#pragma unroll
    for (int q = 0; q < 4; q++) {
        uint4 av = a[q], bv = b[q];
        s = fdot2_(av.x, bv.x, s);
        s = fdot2_(av.y, bv.y, s);
        s = fdot2_(av.z, bv.z, s);
        s = fdot2_(av.w, bv.w, s);
    }
    out[e] = s;
}

extern "C" void kernel_launch(void* const* d_in, const int* in_sizes, int n_in,
                              void* d_out, int out_size, void* d_ws, size_t ws_size,
                              hipStream_t stream)
{
    const float* x   = (const float*)d_in[0];
    const int*   ei  = (const int*)d_in[1];
    const int*   eli = (const int*)d_in[2];
    const float* Wih = (const float*)d_in[3];
    // d_in[4] = W_hh: mathematically dead (h0 = c0 = 0)
    const float* bih = (const float*)d_in[5];
    const float* bhh = (const float*)d_in[6];
    const float* W1  = (const float*)d_in[7];
    const float* b1  = (const float*)d_in[8];
    const float* W2  = (const float*)d_in[9];
    const float* b2  = (const float*)d_in[10];

    int n  = in_sizes[0] / 64;
    int E  = in_sizes[1] / 2;
    int EL = in_sizes[2] / 2;

    const int* row  = ei;          // source
    const int* col  = ei + E;      // destination
    const int* lsrc = eli;
    const int* ldst = eli + EL;
    float* out = (float*)d_out;

    // Workspace layout (liveness-aliased):
    //   bufA [n*64 f32 region]: ebuf int2[E] (bin..csr), hw1 FP16
    //                           (lstm..pull64), hw2 FP16 (mm2..pull32)
    //   bufB [n*64 f32 region]: h1 f32 (pull64..mm2), z FP16 (pull32..dot)
    //   dinv [n] | B1tab [1536 uint4] | B2tab [512 uint4] | bsum [192]
    //   off [n+1] | nbr [E] | bdeg [256] | boff [257] | gcur [nbuck*16]
    float*    bufA  = (float*)d_ws;
    float*    bufB  = bufA + (size_t)n * 64;
    float*    dinv  = bufB + (size_t)n * 64;
    uintptr_t pal   = ((uintptr_t)(dinv + n) + 15) & ~(uintptr_t)15;
    uint4*    B1tab = (uint4*)pal;
    uint4*    B2tab = B1tab + 1536;
    float*    bsum  = (float*)(B2tab + 512);
    int*      off   = (int*)(bsum + 192);
    int*      nbr   = off + (n + 1);
    int*      bdeg  = nbr + E;
    int*      boff  = bdeg + 256;
    int*      gcur  = boff + 257;
    int2*     ebuf  = (int2*)bufA;    // dead until k_lstm_mm1 writes hw1
    __half*   hw1h  = (__half*)bufA;
    __half*   hw2h  = (__half*)bufA;  // hw1 dead by the time mm2 writes
    float*    h1    = bufB;
    __half*   zh    = (__half*)bufB;  // h1 dead by the time pull32 writes

    int nbuck   = (n + (1 << NBSH) - 1) >> NBSH;   // 196 buckets (<=256)
    int eblocks = (E + CH - 1) / CH;               // 391
    dim3 blk(256);

    // --- MFMA B-fragment tables + bias pack (2240 threads, one-time) ---
    k_tr<<<dim3(9), blk, 0, stream>>>(Wih, W1, bih, bhh, B1tab, B2tab, bsum);

    // --- CSR build: bucket histogram -> scan -> binned partition -> per-
    //     bucket finalize (off/dinv/nbr; LDS atomics only) ---
    hipMemsetAsync(bdeg, 0, 256 * sizeof(int), stream);
    k_bhist<<<dim3(eblocks), blk, 0, stream>>>(col, bdeg, E, nbuck);
    k_bscan<<<dim3(1), blk, 0, stream>>>(bdeg, boff, gcur, nbuck, E);
    k_bin  <<<dim3(eblocks), blk, 0, stream>>>(row, col, gcur, ebuf, E, nbuck);
    k_csr  <<<dim3(nbuck), dim3(512), 0, stream>>>(ebuf, boff, off, dinv, nbr, n, nbuck, E);

    // --- LSTM + first matmul on MFMA: hw1 (fp16) -> bufA (ebuf dead) ---
    {
        int blocks = (n + 63) / 64;    // 16 nodes/wave, 4 waves/block
        k_lstm_mm1<<<dim3(blocks), blk, 0, stream>>>(x, B1tab, B2tab, bsum, hw1h, n);
    }

    // --- GCN1: pull + fused epilogue (relu) : h1 (f32) -> bufB ---
    {
        int blocks = (n + 15) / 16;    // 4 nodes/wave
        k_pull64<<<dim3(blocks), blk, 0, stream>>>(hw1h, off, nbr, dinv, b1, h1, n);
    }

    // --- second matmul: hw2 (fp16) -> bufA (hw1 dead) ---
    k_mm2<<<dim3((n + 127) / 128), dim3(128), 0, stream>>>(h1, W2, hw2h, n);

    // --- GCN2: pull + fused epilogue : z (fp16) -> bufB (h1 dead) ---
    {
        int blocks = (n + 15) / 16;    // 4 nodes/wave
        k_pull32<<<dim3(blocks), blk, 0, stream>>>(hw2h, off, nbr, dinv, b2, zh, n);
    }

    // --- edge dot products ---
    k_dot<<<dim3((EL + 255) / 256), blk, 0, stream>>>(zh, lsrc, ldst, out, EL);
}

// Round 20
// 179.989 us; speedup vs baseline: 2.9165x; 1.1032x over previous
//
#include <hip/hip_runtime.h>
#include <hip/hip_bf16.h>
#include <hip/hip_fp16.h>
#include <math.h>
#include <stdint.h>

#define NBSH 9        // 512 destination cols per bucket
#define CH   4096     // edges staged per k_bin block

typedef _Float16 h2v  __attribute__((ext_vector_type(2)));
typedef _Float16 half8 __attribute__((ext_vector_type(8)));
typedef float    f32x4 __attribute__((ext_vector_type(4)));

__device__ __forceinline__ float fdot2_(unsigned a, unsigned b, float c) {
    return __builtin_amdgcn_fdot2(__builtin_bit_cast(h2v, a),
                                  __builtin_bit_cast(h2v, b), c, false);
}

__device__ __forceinline__ float2 h2f2_(unsigned u) {
    return __half22float2(__builtin_bit_cast(__half2, u));
}

// Fast device transcendentals: native v_exp_f32 + v_rcp_f32.
__device__ __forceinline__ float fast_sigmoid(float x) {
    float t = __expf(x);
    return 1.0f - __builtin_amdgcn_rcpf(1.0f + t);
}
__device__ __forceinline__ float fast_tanh(float x) {
    float t = __expf(2.0f * x);
    return 1.0f - 2.0f * __builtin_amdgcn_rcpf(1.0f + t);
}

// ---------------------------------------------------------------------------
// Fused one-time prep + bucket histogram.
// Blocks 0..8: MFMA B-fragment tables + combined bias (2240 work items).
// Blocks 9.. : per-block LDS histogram of col>>NBSH -> ONE global atomic per
//              (bucket, block). bdeg must be zeroed first.
// ---------------------------------------------------------------------------
__global__ __launch_bounds__(256) void k_trh(
    const float* __restrict__ Wih, const float* __restrict__ W1,
    const float* __restrict__ bih, const float* __restrict__ bhh,
    uint4* __restrict__ B1tab, uint4* __restrict__ B2tab,
    float* __restrict__ bsum,
    const int* __restrict__ col, int* __restrict__ bdeg, int E, int nbuck)
{
    if (blockIdx.x < 9) {
        int t = blockIdx.x * 256 + threadIdx.x;
        if (t < 1536) {
            int e = t >> 6, l = t & 63;
            int tt = e >> 1, kh = e & 1;
            int gate = tt >> 2, tj = tt & 3;
            int j = 16 * tj + (l & 15);
            int rowb = (gate == 0) ? j : (gate == 1) ? (128 + j) : (192 + j);
            int kbase = kh * 32 + 8 * (l >> 4);
            _Float16 v[8];
#pragma unroll
            for (int jj = 0; jj < 8; jj++)
                v[jj] = (_Float16)Wih[rowb * 64 + kbase + jj];
            B1tab[t] = *reinterpret_cast<uint4*>(v);
        } else if (t < 2048) {
            int u = t - 1536;
            int e = u >> 6, l = u & 63;
            int tt = e >> 1, kh = e & 1;
            int s = 16 * tt + (l & 15);
            int kbase = kh * 32 + 8 * (l >> 4);
            _Float16 v[8];
#pragma unroll
            for (int jj = 0; jj < 8; jj++)
                v[jj] = (_Float16)W1[(kbase + jj) * 64 + s];
            B2tab[u] = *reinterpret_cast<uint4*>(v);
        } else if (t < 2240) {
            int c = t - 2048;
            int gate = c >> 6, j = c & 63;
            int rowb = (gate == 0) ? j : (gate == 1) ? (128 + j) : (192 + j);
            bsum[c] = bih[rowb] + bhh[rowb];
        }
        return;
    }
    __shared__ int cnt[256];
    cnt[threadIdx.x] = 0;
    __syncthreads();
    int base = (blockIdx.x - 9) * CH;
    int end  = base + CH; if (end > E) end = E;
    for (int t = base + (int)threadIdx.x; t < end; t += 256)
        atomicAdd(&cnt[col[t] >> NBSH], 1);
    __syncthreads();
    if ((int)threadIdx.x < nbuck && cnt[threadIdx.x] > 0)
        atomicAdd(&bdeg[threadIdx.x], cnt[threadIdx.x]);
}

// ---------------------------------------------------------------------------
// Single-block scan of bucket sizes -> boff[0..nbuck]; inits padded k_bin
// cursors (gcur[b*16] = boff[b]).
// ---------------------------------------------------------------------------
__global__ __launch_bounds__(256) void k_bscan(const int* __restrict__ bdeg,
        int* __restrict__ boff, int* __restrict__ gcur, int nbuck, int E) {
    __shared__ int tmp[256];
    int tid = threadIdx.x;
    int v = (tid < nbuck) ? bdeg[tid] : 0;
    tmp[tid] = v;
    __syncthreads();
#pragma unroll
    for (int s = 1; s < 256; s <<= 1) {
        int t = (tid >= s) ? tmp[tid - s] : 0;
        __syncthreads();
        tmp[tid] += t;
        __syncthreads();
    }
    if (tid < nbuck) {
        int o = tmp[tid] - v;
        boff[tid] = o;
        gcur[tid * 16] = o;
    }
    if (tid == 0) boff[nbuck] = E;
}

// ---------------------------------------------------------------------------
// FUSED: bin partition (blocks < eblocks) || LSTM+mm1 on MFMA (rest).
// The two halves are data-independent (ebuf vs hw1 now DISJOINT regions,
// enabled by fp16 h1 freeing 12.8MB) and use different pipes (bin: memory+
// LDS, lstm: MFMA) -> concurrent execution hides the lstm entirely.
// Shared-LDS pool (36KB) reused per branch (branch is block-uniform).
// ---------------------------------------------------------------------------
__global__ __launch_bounds__(256) void k_binl(
    const int* __restrict__ row, const int* __restrict__ col,
    int* __restrict__ gcur, int2* __restrict__ ebuf, int E, int nbuck,
    int eblocks,
    const float* __restrict__ x, const uint4* __restrict__ B1tab,
    const uint4* __restrict__ B2tab, const float* __restrict__ bsum,
    __half* __restrict__ hw1, int n)
{
    __shared__ int pool[9216];             // 36KB: bin ctrl(4KB)+stage(32KB)
    if ((int)blockIdx.x < eblocks) {
        // ================= bin body (r13, proven) =================
        int* cnt  = pool;
        int* lofs = pool + 256;
        int* gbase = pool + 512;
        int* cur2 = pool + 768;
        int2* stage = (int2*)(pool + 1024);
        int tid  = threadIdx.x;
        int base = blockIdx.x * CH;
        int ned  = E - base; if (ned > CH) ned = CH;

        cnt[tid] = 0;
        __syncthreads();

        int r[16], c[16], b[16];
#pragma unroll
        for (int i = 0; i < 16; i++) {
            int idx = i * 256 + tid;
            if (idx < ned) {
                r[i] = row[base + idx];
                c[i] = col[base + idx];
                b[i] = c[i] >> NBSH;
                atomicAdd(&cnt[b[i]], 1);
            } else { r[i] = 0; c[i] = 0; b[i] = -1; }
        }
        __syncthreads();

        int v = cnt[tid];
        lofs[tid] = v;
        __syncthreads();
#pragma unroll
        for (int s = 1; s < 256; s <<= 1) {
            int t = (tid >= s) ? lofs[tid - s] : 0;
            __syncthreads();
            lofs[tid] += t;
            __syncthreads();
        }
        int excl = lofs[tid] - v;
        __syncthreads();
        lofs[tid] = excl;
        cur2[tid] = excl;
        if (tid < nbuck && v > 0)
            gbase[tid] = atomicAdd(&gcur[tid * 16], v);   // padded cursor
        __syncthreads();

#pragma unroll
        for (int i = 0; i < 16; i++) {
            if (b[i] >= 0) {
                int p = atomicAdd(&cur2[b[i]], 1);
                stage[p] = make_int2(r[i], c[i]);
            }
        }
        __syncthreads();

        for (int i = tid; i < ned; i += 256) {
            int2 rc = stage[i];
            int bb = rc.y >> NBSH;
            ebuf[gbase[bb] + (i - lofs[bb])] = rc;
        }
        return;
    }

    // ================= LSTM + mm1 body (r17, proven) =================
    _Float16* hsp = (_Float16*)pool;       // per-wave 1152 halves, pad-72 rows
    int wv   = threadIdx.x >> 6;
    int lane = threadIdx.x & 63;
    int nbase = (((int)blockIdx.x - eblocks) * 4 + wv) * 16;
    if (nbase >= n) return;                // wave-uniform
    int m16 = lane & 15, q = lane >> 4;
    _Float16* hs = hsp + wv * 1152;

    int node = nbase + m16; if (node >= n) node = n - 1;
    const float* xr = x + (size_t)node * 64 + 8 * q;
    half8 a0, a1;
#pragma unroll
    for (int jj = 0; jj < 8; jj++) a0[jj] = (_Float16)xr[jj];
#pragma unroll
    for (int jj = 0; jj < 8; jj++) a1[jj] = (_Float16)xr[32 + jj];

    f32x4 c1[12];
#pragma unroll
    for (int t = 0; t < 12; t++) {
        f32x4 acc = {0.f, 0.f, 0.f, 0.f};
        half8 b0 = __builtin_bit_cast(half8, B1tab[(t * 2 + 0) * 64 + lane]);
        half8 b1 = __builtin_bit_cast(half8, B1tab[(t * 2 + 1) * 64 + lane]);
        acc = __builtin_amdgcn_mfma_f32_16x16x32_f16(a0, b0, acc, 0, 0, 0);
        acc = __builtin_amdgcn_mfma_f32_16x16x32_f16(a1, b1, acc, 0, 0, 0);
        c1[t] = acc;
    }

#pragma unroll
    for (int tj = 0; tj < 4; tj++) {
        int j = 16 * tj + m16;
        float bi = bsum[j], bg = bsum[64 + j], bo = bsum[128 + j];
#pragma unroll
        for (int r = 0; r < 4; r++) {
            float gi = c1[tj][r]     + bi;
            float gg = c1[4 + tj][r] + bg;
            float go = c1[8 + tj][r] + bo;
            float cc = fast_sigmoid(gi) * fast_tanh(gg);
            float h  = fast_sigmoid(go) * fast_tanh(cc);
            hs[(q * 4 + r) * 72 + j] = (_Float16)h;
        }
    }

    half8 a20 = __builtin_bit_cast(half8,
        *reinterpret_cast<const uint4*>(&hs[m16 * 72 + 8 * q]));
    half8 a21 = __builtin_bit_cast(half8,
        *reinterpret_cast<const uint4*>(&hs[m16 * 72 + 32 + 8 * q]));

    f32x4 c2[4];
#pragma unroll
    for (int t = 0; t < 4; t++) {
        f32x4 acc = {0.f, 0.f, 0.f, 0.f};
        half8 b0 = __builtin_bit_cast(half8, B2tab[(t * 2 + 0) * 64 + lane]);
        half8 b1 = __builtin_bit_cast(half8, B2tab[(t * 2 + 1) * 64 + lane]);
        acc = __builtin_amdgcn_mfma_f32_16x16x32_f16(a20, b0, acc, 0, 0, 0);
        acc = __builtin_amdgcn_mfma_f32_16x16x32_f16(a21, b1, acc, 0, 0, 0);
        c2[t] = acc;
    }

#pragma unroll
    for (int t = 0; t < 4; t++) {
#pragma unroll
        for (int r = 0; r < 4; r++) {
            int nd = nbase + q * 4 + r;
            if (nd < n)
                hw1[(size_t)nd * 64 + 16 * t + m16] = __float2half(c2[t][r]);
        }
    }
}

// ---------------------------------------------------------------------------
// Pass 2: per-bucket CSR finalize (off/dinv/nbr; LDS atomics only).
// ---------------------------------------------------------------------------
__global__ __launch_bounds__(512) void k_csr(
    const int2* __restrict__ ebuf, const int* __restrict__ boff,
    int* __restrict__ off, float* __restrict__ dinv,
    int* __restrict__ nbr, int n, int nbuck, int E)
{
    __shared__ int cnt[512], lofs[512];
    int b   = blockIdx.x;
    int tid = threadIdx.x;
    int c0  = b << NBSH;
    int nn  = n - c0; if (nn > 512) nn = 512; if (nn < 0) nn = 0;
    int lo  = boff[b], hi = boff[b + 1];

    cnt[tid] = 0;
    __syncthreads();
    for (int t = lo + tid; t < hi; t += 512)
        atomicAdd(&cnt[ebuf[t].y & 511], 1);
    __syncthreads();

    int v = cnt[tid];
    lofs[tid] = v;
    __syncthreads();
#pragma unroll
    for (int s = 1; s < 512; s <<= 1) {
        int t = (tid >= s) ? lofs[tid - s] : 0;
        __syncthreads();
        lofs[tid] += t;
        __syncthreads();
    }
    int excl = lofs[tid] - v;
    __syncthreads();

    if (tid < nn) {
        off[c0 + tid]  = lo + excl;
        dinv[c0 + tid] = 1.0f / sqrtf((float)(v + 1));
    }
    if (b == nbuck - 1 && tid == 0) off[n] = E;

    cnt[tid] = excl;                       // reuse as LDS cursors
    __syncthreads();
    for (int t = lo + tid; t < hi; t += 512) {
        int2 rc = ebuf[t];
        int p = atomicAdd(&cnt[rc.y & 511], 1);
        nbr[lo + p] = rc.x;
    }
}

// ---------------------------------------------------------------------------
// Pull aggregation, F=64 -- 4 nodes/wave, uint2-packed gathers (r19).
// h1 output now FP16 (uint2 = 4 halves per lane, coalesced).
// ---------------------------------------------------------------------------
__global__ __launch_bounds__(256) void k_pull64(
    const __half* __restrict__ hw, const int* __restrict__ off,
    const int* __restrict__ nbr, const float* __restrict__ dinv,
    const float* __restrict__ b1, __half* __restrict__ h1, int n)
{
    int w    = (blockIdx.x * 256 + threadIdx.x) >> 6;   // wave id
    int lane = threadIdx.x & 63;
    int quad = lane >> 4;              // quarter-wave id: node select
    int fp   = lane & 15;              // features 4fp .. 4fp+3
    if (w * 4 >= n) return;            // wave-uniform
    int node = w * 4 + quad;
    bool alive = node < n;
    int s = 0, e = 0;
    if (alive) { s = off[node]; e = off[node + 1]; }

    float s0x=0.f,s0y=0.f,s0z=0.f,s0w=0.f;
    float s1x=0.f,s1y=0.f,s1z=0.f,s1w=0.f;
    float s2x=0.f,s2y=0.f,s2z=0.f,s2w=0.f;
    float s3x=0.f,s3y=0.f,s3z=0.f,s3w=0.f;

    for (int base = s; base < e; base += 16) {
        int t = base + fp;
        int idx = 0; float wv = 0.f;
        if (t < e) { idx = nbr[t]; wv = dinv[idx]; }
        int cnt = e - base; if (cnt > 16) cnt = 16;

        int k = 0;
        for (; k + 4 <= cnt; k += 4) {
            int   r0 = __shfl(idx, k + 0, 16); float w0 = __shfl(wv, k + 0, 16);
            int   r1 = __shfl(idx, k + 1, 16); float w1 = __shfl(wv, k + 1, 16);
            int   r2 = __shfl(idx, k + 2, 16); float w2 = __shfl(wv, k + 2, 16);
            int   r3 = __shfl(idx, k + 3, 16); float w3 = __shfl(wv, k + 3, 16);
            uint2 u0 = reinterpret_cast<const uint2*>(hw + (size_t)r0 * 64)[fp];
            uint2 u1 = reinterpret_cast<const uint2*>(hw + (size_t)r1 * 64)[fp];
            uint2 u2 = reinterpret_cast<const uint2*>(hw + (size_t)r2 * 64)[fp];
            uint2 u3 = reinterpret_cast<const uint2*>(hw + (size_t)r3 * 64)[fp];
            float2 l0 = h2f2_(u0.x), h0 = h2f2_(u0.y);
            float2 l1 = h2f2_(u1.x), h1f = h2f2_(u1.y);
            float2 l2 = h2f2_(u2.x), h2 = h2f2_(u2.y);
            float2 l3 = h2f2_(u3.x), h3 = h2f2_(u3.y);
            s0x = fmaf(l0.x, w0, s0x); s0y = fmaf(l0.y, w0, s0y);
            s0z = fmaf(h0.x, w0, s0z); s0w = fmaf(h0.y, w0, s0w);
            s1x = fmaf(l1.x, w1, s1x); s1y = fmaf(l1.y, w1, s1y);
            s1z = fmaf(h1f.x, w1, s1z); s1w = fmaf(h1f.y, w1, s1w);
            s2x = fmaf(l2.x, w2, s2x); s2y = fmaf(l2.y, w2, s2y);
            s2z = fmaf(h2.x, w2, s2z); s2w = fmaf(h2.y, w2, s2w);
            s3x = fmaf(l3.x, w3, s3x); s3y = fmaf(l3.y, w3, s3y);
            s3z = fmaf(h3.x, w3, s3z); s3w = fmaf(h3.y, w3, s3w);
        }
        for (; k < cnt; k++) {
            int   r0 = __shfl(idx, k, 16);
            float w0 = __shfl(wv, k, 16);
            uint2 u0 = reinterpret_cast<const uint2*>(hw + (size_t)r0 * 64)[fp];
            float2 l0 = h2f2_(u0.x), h0 = h2f2_(u0.y);
            s0x = fmaf(l0.x, w0, s0x); s0y = fmaf(l0.y, w0, s0y);
            s0z = fmaf(h0.x, w0, s0z); s0w = fmaf(h0.y, w0, s0w);
        }
    }

    if (alive) {
        float ax = (s0x + s1x) + (s2x + s3x);
        float ay = (s0y + s1y) + (s2y + s3y);
        float az = (s0z + s1z) + (s2z + s3z);
        float aw = (s0w + s1w) + (s2w + s3w);
        float dc = dinv[node];
        uint2 su = reinterpret_cast<const uint2*>(hw + (size_t)node * 64)[fp];
        float2 sl = h2f2_(su.x), sh = h2f2_(su.y);
        float4 bb = reinterpret_cast<const float4*>(b1)[fp];
        float vx = fmaxf(ax * dc + sl.x * dc * dc + bb.x, 0.0f);
        float vy = fmaxf(ay * dc + sl.y * dc * dc + bb.y, 0.0f);
        float vz = fmaxf(az * dc + sh.x * dc * dc + bb.z, 0.0f);
        float vw = fmaxf(aw * dc + sh.y * dc * dc + bb.w, 0.0f);
        __half2 p0(__float2half(vx), __float2half(vy));
        __half2 p1(__float2half(vz), __float2half(vw));
        uint2 pk = make_uint2(__builtin_bit_cast(unsigned, p0),
                              __builtin_bit_cast(unsigned, p1));
        reinterpret_cast<uint2*>(h1 + (size_t)node * 64)[fp] = pk;
    }
}

// ---------------------------------------------------------------------------
// Pull aggregation, F=32 -- 4 nodes/wave, half2-packed gathers (r18, proven).
// ---------------------------------------------------------------------------
__global__ __launch_bounds__(256) void k_pull32(
    const __half* __restrict__ hw, const int* __restrict__ off,
    const int* __restrict__ nbr, const float* __restrict__ dinv,
    const float* __restrict__ b2, __half* __restrict__ z, int n)
{
    int w    = (blockIdx.x * 256 + threadIdx.x) >> 6;   // wave id
    int lane = threadIdx.x & 63;
    int quad = lane >> 4;              // quarter-wave id: node select
    int fp   = lane & 15;              // features 2fp, 2fp+1
    if (w * 4 >= n) return;            // wave-uniform
    int node = w * 4 + quad;
    bool alive = node < n;
    int s = 0, e = 0;
    if (alive) { s = off[node]; e = off[node + 1]; }

    float ax0 = 0.f, ay0 = 0.f, ax1 = 0.f, ay1 = 0.f;
    float ax2 = 0.f, ay2 = 0.f, ax3 = 0.f, ay3 = 0.f;

    for (int base = s; base < e; base += 16) {
        int t = base + fp;
        int idx = 0; float wv = 0.f;
        if (t < e) { idx = nbr[t]; wv = dinv[idx]; }
        int cnt = e - base; if (cnt > 16) cnt = 16;

        int k = 0;
        for (; k + 4 <= cnt; k += 4) {
            int   r0 = __shfl(idx, k + 0, 16); float w0 = __shfl(wv, k + 0, 16);
            int   r1 = __shfl(idx, k + 1, 16); float w1 = __shfl(wv, k + 1, 16);
            int   r2 = __shfl(idx, k + 2, 16); float w2 = __shfl(wv, k + 2, 16);
            int   r3 = __shfl(idx, k + 3, 16); float w3 = __shfl(wv, k + 3, 16);
            unsigned u0 = reinterpret_cast<const unsigned*>(hw + (size_t)r0 * 32)[fp];
            unsigned u1 = reinterpret_cast<const unsigned*>(hw + (size_t)r1 * 32)[fp];
            unsigned u2 = reinterpret_cast<const unsigned*>(hw + (size_t)r2 * 32)[fp];
            unsigned u3 = reinterpret_cast<const unsigned*>(hw + (size_t)r3 * 32)[fp];
            float2 f0 = h2f2_(u0), f1 = h2f2_(u1), f2 = h2f2_(u2), f3 = h2f2_(u3);
            ax0 = fmaf(f0.x, w0, ax0); ay0 = fmaf(f0.y, w0, ay0);
            ax1 = fmaf(f1.x, w1, ax1); ay1 = fmaf(f1.y, w1, ay1);
            ax2 = fmaf(f2.x, w2, ax2); ay2 = fmaf(f2.y, w2, ay2);
            ax3 = fmaf(f3.x, w3, ax3); ay3 = fmaf(f3.y, w3, ay3);
        }
        for (; k < cnt; k++) {
            int   r0 = __shfl(idx, k, 16);
            float w0 = __shfl(wv, k, 16);
            unsigned u0 = reinterpret_cast<const unsigned*>(hw + (size_t)r0 * 32)[fp];
            float2 f0 = h2f2_(u0);
            ax0 = fmaf(f0.x, w0, ax0); ay0 = fmaf(f0.y, w0, ay0);
        }
    }

    if (alive) {
        float ax = (ax0 + ax1) + (ax2 + ax3);
        float ay = (ay0 + ay1) + (ay2 + ay3);
        float dc = dinv[node];
        unsigned su = reinterpret_cast<const unsigned*>(hw + (size_t)node * 32)[fp];
        float2 sf = h2f2_(su);
        float2 bb = reinterpret_cast<const float2*>(b2)[fp];
        float vx = ax * dc + sf.x * dc * dc + bb.x;
        float vy = ay * dc + sf.y * dc * dc + bb.y;
        __half2 pk(__float2half(vx), __float2half(vy));
        reinterpret_cast<__half2*>(z + (size_t)node * 32)[fp] = pk;
    }
}

// ---------------------------------------------------------------------------
// hw2 = h1 @ W2  ([n,64] x [64,32]). h1 now FP16 (half the staging traffic);
// f32 compute in LDS tile, FP16 output rows.
// ---------------------------------------------------------------------------
__global__ __launch_bounds__(128) void k_mm2(
    const __half* __restrict__ h1, const float* __restrict__ W2,
    __half* __restrict__ hw2, int n)
{
    __shared__ float tile[128 * 65];
    int base  = blockIdx.x * 128;
    int nrows = n - base; if (nrows > 128) nrows = 128;

    for (int idx = threadIdx.x; idx < nrows * 32; idx += 128) {
        int r = idx >> 5, c = idx & 31;
        __half2 hv = reinterpret_cast<const __half2*>(h1 + (size_t)(base + r) * 64)[c];
        float2 f = __half22float2(hv);
        tile[r * 65 + 2 * c]     = f.x;
        tile[r * 65 + 2 * c + 1] = f.y;
    }
    __syncthreads();

    int node = base + threadIdx.x;
    if (node >= n) return;

    const float* hrow = &tile[threadIdx.x * 65];
    float acc[32];
#pragma unroll
    for (int s = 0; s < 32; s++) acc[s] = 0.0f;

    for (int k = 0; k < 64; k++) {
        float hk = hrow[k];
        const float* w = W2 + (size_t)k * 32;
#pragma unroll
        for (int s = 0; s < 32; s++) acc[s] = fmaf(hk, w[s], acc[s]);
    }

    uint2* op = reinterpret_cast<uint2*>(hw2 + (size_t)node * 32);
#pragma unroll
    for (int q = 0; q < 8; q++) {
        __half2 lo(__float2half(acc[4*q+0]), __float2half(acc[4*q+1]));
        __half2 hi(__float2half(acc[4*q+2]), __float2half(acc[4*q+3]));
        op[q] = make_uint2(__builtin_bit_cast(unsigned, lo),
                           __builtin_bit_cast(unsigned, hi));
    }
}

// ---------------------------------------------------------------------------
// out[e] = dot(z[src[e]], z[dst[e]]) over 32 features; z is FP16.
// ---------------------------------------------------------------------------
__global__ void k_dot(const __half* __restrict__ z, const int* __restrict__ src,
                      const int* __restrict__ dst, float* __restrict__ out, int EL)
{
    int e = blockIdx.x * 256 + threadIdx.x;
    if (e >= EL) return;
    const uint4* a = reinterpret_cast<const uint4*>(z + (size_t)src[e] * 32);
    const uint4* b = reinterpret_cast<const uint4*>(z + (size_t)dst[e] * 32);
    float s = 0.0f;
#pragma unroll
    for (int q = 0; q < 4; q++) {
        uint4 av = a[q], bv = b[q];
        s = fdot2_(av.x, bv.x, s);
        s = fdot2_(av.y, bv.y, s);
        s = fdot2_(av.z, bv.z, s);
        s = fdot2_(av.w, bv.w, s);
    }
    out[e] = s;
}

extern "C" void kernel_launch(void* const* d_in, const int* in_sizes, int n_in,
                              void* d_out, int out_size, void* d_ws, size_t ws_size,
                              hipStream_t stream)
{
    const float* x   = (const float*)d_in[0];
    const int*   ei  = (const int*)d_in[1];
    const int*   eli = (const int*)d_in[2];
    const float* Wih = (const float*)d_in[3];
    // d_in[4] = W_hh: mathematically dead (h0 = c0 = 0)
    const float* bih = (const float*)d_in[5];
    const float* bhh = (const float*)d_in[6];
    const float* W1  = (const float*)d_in[7];
    const float* b1  = (const float*)d_in[8];
    const float* W2  = (const float*)d_in[9];
    const float* b2  = (const float*)d_in[10];

    int n  = in_sizes[0] / 64;
    int E  = in_sizes[1] / 2;
    int EL = in_sizes[2] / 2;

    const int* row  = ei;          // source
    const int* col  = ei + E;      // destination
    const int* lsrc = eli;
    const int* ldst = eli + EL;
    float* out = (float*)d_out;

    // Workspace layout (4B units), hw1 DISJOINT from ebuf (enables bin||lstm):
    //   regA [E*2]: ebuf int2[E] (binl..csr), then hw2 FP16 [n*32 halves]
    //   hw1  [n*32]: hw1 FP16 [n*64 halves] (binl..pull64)
    //   regB [n*32]: h1 FP16 (pull64..mm2), z FP16 (pull32..dot)
    //   dinv [n] | off [n+1] | nbr [E] | B1tab/B2tab/bsum | bdeg/boff/gcur
    //   Total ~= 45.7 MB.
    float*    base  = (float*)d_ws;
    int2*     ebuf  = (int2*)base;
    __half*   hw2h  = (__half*)base;          // ebuf dead by mm2
    float*    p1    = base + (size_t)E * 2;
    __half*   hw1h  = (__half*)p1;
    float*    p2    = p1 + (size_t)n * 32;
    __half*   h1h   = (__half*)p2;
    __half*   zh    = (__half*)p2;            // h1 dead by pull32
    float*    dinv  = p2 + (size_t)n * 32;
    int*      off   = (int*)(dinv + n);
    int*      nbr   = off + (n + 1);
    uintptr_t pal   = ((uintptr_t)(nbr + E) + 15) & ~(uintptr_t)15;
    uint4*    B1tab = (uint4*)pal;
    uint4*    B2tab = B1tab + 1536;
    float*    bsum  = (float*)(B2tab + 512);
    int*      bdeg  = (int*)(bsum + 192);
    int*      boff  = bdeg + 256;
    int*      gcur  = boff + 257;

    int nbuck   = (n + (1 << NBSH) - 1) >> NBSH;   // 196 buckets (<=256)
    int eblocks = (E + CH - 1) / CH;               // 391
    int lblocks = (n + 63) / 64;                   // lstm: 16 nodes/wave
    dim3 blk(256);

    // --- prep: tables+bias (blocks 0-8) || bucket histogram (rest) ---
    hipMemsetAsync(bdeg, 0, 256 * sizeof(int), stream);
    k_trh<<<dim3(9 + eblocks), blk, 0, stream>>>(
        Wih, W1, bih, bhh, B1tab, B2tab, bsum, col, bdeg, E, nbuck);
    k_bscan<<<dim3(1), blk, 0, stream>>>(bdeg, boff, gcur, nbuck, E);

    // --- FUSED: bin partition || LSTM+mm1 (independent pipes+memory) ---
    k_binl<<<dim3(eblocks + lblocks), blk, 0, stream>>>(
        row, col, gcur, ebuf, E, nbuck, eblocks,
        x, B1tab, B2tab, bsum, hw1h, n);

    // --- per-bucket CSR finalize ---
    k_csr<<<dim3(nbuck), dim3(512), 0, stream>>>(ebuf, boff, off, dinv, nbr, n, nbuck, E);

    // --- GCN1: pull + fused epilogue (relu) : h1 (fp16) ---
    {
        int blocks = (n + 15) / 16;    // 4 nodes/wave
        k_pull64<<<dim3(blocks), blk, 0, stream>>>(hw1h, off, nbr, dinv, b1, h1h, n);
    }

    // --- second matmul: hw2 (fp16) -> regA (ebuf dead) ---
    k_mm2<<<dim3((n + 127) / 128), dim3(128), 0, stream>>>(h1h, W2, hw2h, n);

    // --- GCN2: pull + fused epilogue : z (fp16) -> regB (h1 dead) ---
    {
        int blocks = (n + 15) / 16;    // 4 nodes/wave
        k_pull32<<<dim3(blocks), blk, 0, stream>>>(hw2h, off, nbr, dinv, b2, zh, n);
    }

    // --- edge dot products ---
    k_dot<<<dim3((EL + 255) / 256), blk, 0, stream>>>(zh, lsrc, ldst, out, EL);
}

// Round 21
// 167.553 us; speedup vs baseline: 3.1330x; 1.0742x over previous
//
#include <hip/hip_runtime.h>
#include <hip/hip_bf16.h>
#include <hip/hip_fp16.h>
#include <math.h>
#include <stdint.h>

#define NBSH 9        // 512 destination cols per bucket
#define CH   4096     // edges staged per k_bin block

typedef _Float16 h2v  __attribute__((ext_vector_type(2)));
typedef _Float16 half8 __attribute__((ext_vector_type(8)));
typedef float    f32x4 __attribute__((ext_vector_type(4)));

__device__ __forceinline__ float fdot2_(unsigned a, unsigned b, float c) {
    return __builtin_amdgcn_fdot2(__builtin_bit_cast(h2v, a),
                                  __builtin_bit_cast(h2v, b), c, false);
}

__device__ __forceinline__ float2 h2f2_(unsigned u) {
    return __half22float2(__builtin_bit_cast(__half2, u));
}

// Fast device transcendentals: native v_exp_f32 + v_rcp_f32.
__device__ __forceinline__ float fast_sigmoid(float x) {
    float t = __expf(x);
    return 1.0f - __builtin_amdgcn_rcpf(1.0f + t);
}
__device__ __forceinline__ float fast_tanh(float x) {
    float t = __expf(2.0f * x);
    return 1.0f - 2.0f * __builtin_amdgcn_rcpf(1.0f + t);
}

// ---------------------------------------------------------------------------
// Fused one-time prep + bucket histogram.
// Blocks 0..12: MFMA B-fragment tables + bias + W2 half2-pair pack (3264 items)
// Blocks 13.. : per-block LDS histogram of col>>NBSH -> ONE global atomic per
//               (bucket, block). bdeg must be zeroed first.
// ---------------------------------------------------------------------------
__global__ __launch_bounds__(256) void k_trh(
    const float* __restrict__ Wih, const float* __restrict__ W1,
    const float* __restrict__ W2,
    const float* __restrict__ bih, const float* __restrict__ bhh,
    uint4* __restrict__ B1tab, uint4* __restrict__ B2tab,
    float* __restrict__ bsum, unsigned* __restrict__ W2P,
    const int* __restrict__ col, int* __restrict__ bdeg, int E, int nbuck)
{
    if (blockIdx.x < 13) {
        int t = blockIdx.x * 256 + threadIdx.x;
        if (t < 1536) {
            int e = t >> 6, l = t & 63;
            int tt = e >> 1, kh = e & 1;
            int gate = tt >> 2, tj = tt & 3;
            int j = 16 * tj + (l & 15);
            int rowb = (gate == 0) ? j : (gate == 1) ? (128 + j) : (192 + j);
            int kbase = kh * 32 + 8 * (l >> 4);
            _Float16 v[8];
#pragma unroll
            for (int jj = 0; jj < 8; jj++)
                v[jj] = (_Float16)Wih[rowb * 64 + kbase + jj];
            B1tab[t] = *reinterpret_cast<uint4*>(v);
        } else if (t < 2048) {
            int u = t - 1536;
            int e = u >> 6, l = u & 63;
            int tt = e >> 1, kh = e & 1;
            int s = 16 * tt + (l & 15);
            int kbase = kh * 32 + 8 * (l >> 4);
            _Float16 v[8];
#pragma unroll
            for (int jj = 0; jj < 8; jj++)
                v[jj] = (_Float16)W1[(kbase + jj) * 64 + s];
            B2tab[u] = *reinterpret_cast<uint4*>(v);
        } else if (t < 2240) {
            int c = t - 2048;
            int gate = c >> 6, j = c & 63;
            int rowb = (gate == 0) ? j : (gate == 1) ? (128 + j) : (192 + j);
            bsum[c] = bih[rowb] + bhh[rowb];
        } else if (t < 3264) {
            int u = t - 2240;            // W2P[kk*32+s] = half2(W2[2kk][s], W2[2kk+1][s])
            int kk = u >> 5, s = u & 31;
            h2v p;
            p.x = (_Float16)W2[(2 * kk)     * 32 + s];
            p.y = (_Float16)W2[(2 * kk + 1) * 32 + s];
            W2P[u] = __builtin_bit_cast(unsigned, p);
        }
        return;
    }
    __shared__ int cnt[256];
    cnt[threadIdx.x] = 0;
    __syncthreads();
    int base = (blockIdx.x - 13) * CH;
    int end  = base + CH; if (end > E) end = E;
    for (int t = base + (int)threadIdx.x; t < end; t += 256)
        atomicAdd(&cnt[col[t] >> NBSH], 1);
    __syncthreads();
    if ((int)threadIdx.x < nbuck && cnt[threadIdx.x] > 0)
        atomicAdd(&bdeg[threadIdx.x], cnt[threadIdx.x]);
}

// ---------------------------------------------------------------------------
// Single-block scan of bucket sizes -> boff[0..nbuck]; inits padded k_bin
// cursors (gcur[b*16] = boff[b]).
// ---------------------------------------------------------------------------
__global__ __launch_bounds__(256) void k_bscan(const int* __restrict__ bdeg,
        int* __restrict__ boff, int* __restrict__ gcur, int nbuck, int E) {
    __shared__ int tmp[256];
    int tid = threadIdx.x;
    int v = (tid < nbuck) ? bdeg[tid] : 0;
    tmp[tid] = v;
    __syncthreads();
#pragma unroll
    for (int s = 1; s < 256; s <<= 1) {
        int t = (tid >= s) ? tmp[tid - s] : 0;
        __syncthreads();
        tmp[tid] += t;
        __syncthreads();
    }
    if (tid < nbuck) {
        int o = tmp[tid] - v;
        boff[tid] = o;
        gcur[tid * 16] = o;
    }
    if (tid == 0) boff[nbuck] = E;
}

// ---------------------------------------------------------------------------
// FUSED: bin partition (blocks < eblocks) || LSTM+mm1 on MFMA (rest).
// (r20, proven: disjoint memory, different pipes -> concurrent.)
// ---------------------------------------------------------------------------
__global__ __launch_bounds__(256) void k_binl(
    const int* __restrict__ row, const int* __restrict__ col,
    int* __restrict__ gcur, int2* __restrict__ ebuf, int E, int nbuck,
    int eblocks,
    const float* __restrict__ x, const uint4* __restrict__ B1tab,
    const uint4* __restrict__ B2tab, const float* __restrict__ bsum,
    __half* __restrict__ hw1, int n)
{
    __shared__ int pool[9216];             // 36KB: bin ctrl(4KB)+stage(32KB)
    if ((int)blockIdx.x < eblocks) {
        // ================= bin body (r13, proven) =================
        int* cnt  = pool;
        int* lofs = pool + 256;
        int* gbase = pool + 512;
        int* cur2 = pool + 768;
        int2* stage = (int2*)(pool + 1024);
        int tid  = threadIdx.x;
        int base = blockIdx.x * CH;
        int ned  = E - base; if (ned > CH) ned = CH;

        cnt[tid] = 0;
        __syncthreads();

        int r[16], c[16], b[16];
#pragma unroll
        for (int i = 0; i < 16; i++) {
            int idx = i * 256 + tid;
            if (idx < ned) {
                r[i] = row[base + idx];
                c[i] = col[base + idx];
                b[i] = c[i] >> NBSH;
                atomicAdd(&cnt[b[i]], 1);
            } else { r[i] = 0; c[i] = 0; b[i] = -1; }
        }
        __syncthreads();

        int v = cnt[tid];
        lofs[tid] = v;
        __syncthreads();
#pragma unroll
        for (int s = 1; s < 256; s <<= 1) {
            int t = (tid >= s) ? lofs[tid - s] : 0;
            __syncthreads();
            lofs[tid] += t;
            __syncthreads();
        }
        int excl = lofs[tid] - v;
        __syncthreads();
        lofs[tid] = excl;
        cur2[tid] = excl;
        if (tid < nbuck && v > 0)
            gbase[tid] = atomicAdd(&gcur[tid * 16], v);   // padded cursor
        __syncthreads();

#pragma unroll
        for (int i = 0; i < 16; i++) {
            if (b[i] >= 0) {
                int p = atomicAdd(&cur2[b[i]], 1);
                stage[p] = make_int2(r[i], c[i]);
            }
        }
        __syncthreads();

        for (int i = tid; i < ned; i += 256) {
            int2 rc = stage[i];
            int bb = rc.y >> NBSH;
            ebuf[gbase[bb] + (i - lofs[bb])] = rc;
        }
        return;
    }

    // ================= LSTM + mm1 body (r17, proven) =================
    _Float16* hsp = (_Float16*)pool;       // per-wave 1152 halves, pad-72 rows
    int wv   = threadIdx.x >> 6;
    int lane = threadIdx.x & 63;
    int nbase = (((int)blockIdx.x - eblocks) * 4 + wv) * 16;
    if (nbase >= n) return;                // wave-uniform
    int m16 = lane & 15, q = lane >> 4;
    _Float16* hs = hsp + wv * 1152;

    int node = nbase + m16; if (node >= n) node = n - 1;
    const float* xr = x + (size_t)node * 64 + 8 * q;
    half8 a0, a1;
#pragma unroll
    for (int jj = 0; jj < 8; jj++) a0[jj] = (_Float16)xr[jj];
#pragma unroll
    for (int jj = 0; jj < 8; jj++) a1[jj] = (_Float16)xr[32 + jj];

    f32x4 c1[12];
#pragma unroll
    for (int t = 0; t < 12; t++) {
        f32x4 acc = {0.f, 0.f, 0.f, 0.f};
        half8 b0 = __builtin_bit_cast(half8, B1tab[(t * 2 + 0) * 64 + lane]);
        half8 b1 = __builtin_bit_cast(half8, B1tab[(t * 2 + 1) * 64 + lane]);
        acc = __builtin_amdgcn_mfma_f32_16x16x32_f16(a0, b0, acc, 0, 0, 0);
        acc = __builtin_amdgcn_mfma_f32_16x16x32_f16(a1, b1, acc, 0, 0, 0);
        c1[t] = acc;
    }

#pragma unroll
    for (int tj = 0; tj < 4; tj++) {
        int j = 16 * tj + m16;
        float bi = bsum[j], bg = bsum[64 + j], bo = bsum[128 + j];
#pragma unroll
        for (int r = 0; r < 4; r++) {
            float gi = c1[tj][r]     + bi;
            float gg = c1[4 + tj][r] + bg;
            float go = c1[8 + tj][r] + bo;
            float cc = fast_sigmoid(gi) * fast_tanh(gg);
            float h  = fast_sigmoid(go) * fast_tanh(cc);
            hs[(q * 4 + r) * 72 + j] = (_Float16)h;
        }
    }

    half8 a20 = __builtin_bit_cast(half8,
        *reinterpret_cast<const uint4*>(&hs[m16 * 72 + 8 * q]));
    half8 a21 = __builtin_bit_cast(half8,
        *reinterpret_cast<const uint4*>(&hs[m16 * 72 + 32 + 8 * q]));

    f32x4 c2[4];
#pragma unroll
    for (int t = 0; t < 4; t++) {
        f32x4 acc = {0.f, 0.f, 0.f, 0.f};
        half8 b0 = __builtin_bit_cast(half8, B2tab[(t * 2 + 0) * 64 + lane]);
        half8 b1 = __builtin_bit_cast(half8, B2tab[(t * 2 + 1) * 64 + lane]);
        acc = __builtin_amdgcn_mfma_f32_16x16x32_f16(a20, b0, acc, 0, 0, 0);
        acc = __builtin_amdgcn_mfma_f32_16x16x32_f16(a21, b1, acc, 0, 0, 0);
        c2[t] = acc;
    }

#pragma unroll
    for (int t = 0; t < 4; t++) {
#pragma unroll
        for (int r = 0; r < 4; r++) {
            int nd = nbase + q * 4 + r;
            if (nd < n)
                hw1[(size_t)nd * 64 + 16 * t + m16] = __float2half(c2[t][r]);
        }
    }
}

// ---------------------------------------------------------------------------
// Pass 2: per-bucket CSR finalize (off/dinv/nbr; LDS atomics only).
// ---------------------------------------------------------------------------
__global__ __launch_bounds__(512) void k_csr(
    const int2* __restrict__ ebuf, const int* __restrict__ boff,
    int* __restrict__ off, float* __restrict__ dinv,
    int* __restrict__ nbr, int n, int nbuck, int E)
{
    __shared__ int cnt[512], lofs[512];
    int b   = blockIdx.x;
    int tid = threadIdx.x;
    int c0  = b << NBSH;
    int nn  = n - c0; if (nn > 512) nn = 512; if (nn < 0) nn = 0;
    int lo  = boff[b], hi = boff[b + 1];

    cnt[tid] = 0;
    __syncthreads();
    for (int t = lo + tid; t < hi; t += 512)
        atomicAdd(&cnt[ebuf[t].y & 511], 1);
    __syncthreads();

    int v = cnt[tid];
    lofs[tid] = v;
    __syncthreads();
#pragma unroll
    for (int s = 1; s < 512; s <<= 1) {
        int t = (tid >= s) ? lofs[tid - s] : 0;
        __syncthreads();
        lofs[tid] += t;
        __syncthreads();
    }
    int excl = lofs[tid] - v;
    __syncthreads();

    if (tid < nn) {
        off[c0 + tid]  = lo + excl;
        dinv[c0 + tid] = 1.0f / sqrtf((float)(v + 1));
    }
    if (b == nbuck - 1 && tid == 0) off[n] = E;

    cnt[tid] = excl;                       // reuse as LDS cursors
    __syncthreads();
    for (int t = lo + tid; t < hi; t += 512) {
        int2 rc = ebuf[t];
        int p = atomicAdd(&cnt[rc.y & 511], 1);
        nbr[lo + p] = rc.x;
    }
}

// ---------------------------------------------------------------------------
// FUSED pull64 + mm2. Gather phase identical to r19 (4 nodes/wave, uint2).
// Epilogue: h1 row (post-ReLU) staged in per-wave LDS (same-wave ds order),
// then a 16-lane GEMV vs W2 (packed half2 k-pairs, 4KB LDS): lane handles
// (node = lane>>4, cols 2c/2c+1), 32x {ds_read_b32 + ds_read_b64 + 2 fdot2}.
// Writes hw2 fp16 DIRECTLY -- kills the mm2 dispatch and the 25.6MB h1
// round-trip; the GEMV rides in the gather's latency slack (VALUBusy 37%).
// ---------------------------------------------------------------------------
__global__ __launch_bounds__(256) void k_pull64mm(
    const __half* __restrict__ hw, const int* __restrict__ off,
    const int* __restrict__ nbr, const float* __restrict__ dinv,
    const float* __restrict__ b1, const unsigned* __restrict__ W2P,
    __half* __restrict__ hw2, int n)
{
    __shared__ unsigned w2p[1024];         // 4KB: W2 packed half2 k-pairs
    __shared__ _Float16 hrow[4][256];      // per wave: 4 nodes x 64 halves

    for (int i = threadIdx.x; i < 1024; i += 256) w2p[i] = W2P[i];
    __syncthreads();

    int w    = (blockIdx.x * 256 + threadIdx.x) >> 6;   // wave id
    int lane = threadIdx.x & 63;
    int wv   = threadIdx.x >> 6;
    int quad = lane >> 4;              // quarter-wave id: node select
    int fp   = lane & 15;              // features 4fp .. 4fp+3
    if (w * 4 >= n) return;            // wave-uniform (after barrier: safe)
    int node = w * 4 + quad;
    bool alive = node < n;
    int s = 0, e = 0;
    if (alive) { s = off[node]; e = off[node + 1]; }

    float s0x=0.f,s0y=0.f,s0z=0.f,s0w=0.f;
    float s1x=0.f,s1y=0.f,s1z=0.f,s1w=0.f;
    float s2x=0.f,s2y=0.f,s2z=0.f,s2w=0.f;
    float s3x=0.f,s3y=0.f,s3z=0.f,s3w=0.f;

    for (int base = s; base < e; base += 16) {
        int t = base + fp;
        int idx = 0; float wv2 = 0.f;
        if (t < e) { idx = nbr[t]; wv2 = dinv[idx]; }
        int cnt = e - base; if (cnt > 16) cnt = 16;

        int k = 0;
        for (; k + 4 <= cnt; k += 4) {
            int   r0 = __shfl(idx, k + 0, 16); float w0 = __shfl(wv2, k + 0, 16);
            int   r1 = __shfl(idx, k + 1, 16); float w1 = __shfl(wv2, k + 1, 16);
            int   r2 = __shfl(idx, k + 2, 16); float w2 = __shfl(wv2, k + 2, 16);
            int   r3 = __shfl(idx, k + 3, 16); float w3 = __shfl(wv2, k + 3, 16);
            uint2 u0 = reinterpret_cast<const uint2*>(hw + (size_t)r0 * 64)[fp];
            uint2 u1 = reinterpret_cast<const uint2*>(hw + (size_t)r1 * 64)[fp];
            uint2 u2 = reinterpret_cast<const uint2*>(hw + (size_t)r2 * 64)[fp];
            uint2 u3 = reinterpret_cast<const uint2*>(hw + (size_t)r3 * 64)[fp];
            float2 l0 = h2f2_(u0.x), h0 = h2f2_(u0.y);
            float2 l1 = h2f2_(u1.x), h1f = h2f2_(u1.y);
            float2 l2 = h2f2_(u2.x), h2 = h2f2_(u2.y);
            float2 l3 = h2f2_(u3.x), h3 = h2f2_(u3.y);
            s0x = fmaf(l0.x, w0, s0x); s0y = fmaf(l0.y, w0, s0y);
            s0z = fmaf(h0.x, w0, s0z); s0w = fmaf(h0.y, w0, s0w);
            s1x = fmaf(l1.x, w1, s1x); s1y = fmaf(l1.y, w1, s1y);
            s1z = fmaf(h1f.x, w1, s1z); s1w = fmaf(h1f.y, w1, s1w);
            s2x = fmaf(l2.x, w2, s2x); s2y = fmaf(l2.y, w2, s2y);
            s2z = fmaf(h2.x, w2, s2z); s2w = fmaf(h2.y, w2, s2w);
            s3x = fmaf(l3.x, w3, s3x); s3y = fmaf(l3.y, w3, s3y);
            s3z = fmaf(h3.x, w3, s3z); s3w = fmaf(h3.y, w3, s3w);
        }
        for (; k < cnt; k++) {
            int   r0 = __shfl(idx, k, 16);
            float w0 = __shfl(wv2, k, 16);
            uint2 u0 = reinterpret_cast<const uint2*>(hw + (size_t)r0 * 64)[fp];
            float2 l0 = h2f2_(u0.x), h0 = h2f2_(u0.y);
            s0x = fmaf(l0.x, w0, s0x); s0y = fmaf(l0.y, w0, s0y);
            s0z = fmaf(h0.x, w0, s0z); s0w = fmaf(h0.y, w0, s0w);
        }
    }

    // h1 (relu'd) -> per-wave LDS row (fp16); same-wave ds ordering
    {
        float ax = (s0x + s1x) + (s2x + s3x);
        float ay = (s0y + s1y) + (s2y + s3y);
        float az = (s0z + s1z) + (s2z + s3z);
        float aw = (s0w + s1w) + (s2w + s3w);
        float dc = alive ? dinv[node] : 0.f;
        uint2 su = alive ? reinterpret_cast<const uint2*>(hw + (size_t)node * 64)[fp]
                         : make_uint2(0u, 0u);
        float2 sl = h2f2_(su.x), sh = h2f2_(su.y);
        float4 bb = reinterpret_cast<const float4*>(b1)[fp];
        float vx = fmaxf(ax * dc + sl.x * dc * dc + bb.x, 0.0f);
        float vy = fmaxf(ay * dc + sl.y * dc * dc + bb.y, 0.0f);
        float vz = fmaxf(az * dc + sh.x * dc * dc + bb.z, 0.0f);
        float vw = fmaxf(aw * dc + sh.y * dc * dc + bb.w, 0.0f);
        __half2 p0(__float2half(vx), __float2half(vy));
        __half2 p1(__float2half(vz), __float2half(vw));
        uint2 pk = make_uint2(__builtin_bit_cast(unsigned, p0),
                              __builtin_bit_cast(unsigned, p1));
        *reinterpret_cast<uint2*>(&hrow[wv][quad * 64 + 4 * fp]) = pk;
    }

    // GEMV: lane handles node nd4 = lane>>4 (same as quad), cols 2fp, 2fp+1
    float acc0 = 0.f, acc1 = 0.f;
#pragma unroll 8
    for (int kk = 0; kk < 32; kk++) {
        unsigned a = *reinterpret_cast<const unsigned*>(&hrow[wv][quad * 64 + 2 * kk]);
        uint2 wp = *reinterpret_cast<const uint2*>(&w2p[kk * 32 + 2 * fp]);
        acc0 = fdot2_(a, wp.x, acc0);
        acc1 = fdot2_(a, wp.y, acc1);
    }
    if (alive) {
        __half2 pk(__float2half(acc0), __float2half(acc1));
        reinterpret_cast<__half2*>(hw2 + (size_t)node * 32)[fp] = pk;
    }
}

// ---------------------------------------------------------------------------
// Pull aggregation, F=32 -- 4 nodes/wave, half2-packed gathers (r18, proven).
// ---------------------------------------------------------------------------
__global__ __launch_bounds__(256) void k_pull32(
    const __half* __restrict__ hw, const int* __restrict__ off,
    const int* __restrict__ nbr, const float* __restrict__ dinv,
    const float* __restrict__ b2, __half* __restrict__ z, int n)
{
    int w    = (blockIdx.x * 256 + threadIdx.x) >> 6;   // wave id
    int lane = threadIdx.x & 63;
    int quad = lane >> 4;              // quarter-wave id: node select
    int fp   = lane & 15;              // features 2fp, 2fp+1
    if (w * 4 >= n) return;            // wave-uniform
    int node = w * 4 + quad;
    bool alive = node < n;
    int s = 0, e = 0;
    if (alive) { s = off[node]; e = off[node + 1]; }

    float ax0 = 0.f, ay0 = 0.f, ax1 = 0.f, ay1 = 0.f;
    float ax2 = 0.f, ay2 = 0.f, ax3 = 0.f, ay3 = 0.f;

    for (int base = s; base < e; base += 16) {
        int t = base + fp;
        int idx = 0; float wv = 0.f;
        if (t < e) { idx = nbr[t]; wv = dinv[idx]; }
        int cnt = e - base; if (cnt > 16) cnt = 16;

        int k = 0;
        for (; k + 4 <= cnt; k += 4) {
            int   r0 = __shfl(idx, k + 0, 16); float w0 = __shfl(wv, k + 0, 16);
            int   r1 = __shfl(idx, k + 1, 16); float w1 = __shfl(wv, k + 1, 16);
            int   r2 = __shfl(idx, k + 2, 16); float w2 = __shfl(wv, k + 2, 16);
            int   r3 = __shfl(idx, k + 3, 16); float w3 = __shfl(wv, k + 3, 16);
            unsigned u0 = reinterpret_cast<const unsigned*>(hw + (size_t)r0 * 32)[fp];
            unsigned u1 = reinterpret_cast<const unsigned*>(hw + (size_t)r1 * 32)[fp];
            unsigned u2 = reinterpret_cast<const unsigned*>(hw + (size_t)r2 * 32)[fp];
            unsigned u3 = reinterpret_cast<const unsigned*>(hw + (size_t)r3 * 32)[fp];
            float2 f0 = h2f2_(u0), f1 = h2f2_(u1), f2 = h2f2_(u2), f3 = h2f2_(u3);
            ax0 = fmaf(f0.x, w0, ax0); ay0 = fmaf(f0.y, w0, ay0);
            ax1 = fmaf(f1.x, w1, ax1); ay1 = fmaf(f1.y, w1, ay1);
            ax2 = fmaf(f2.x, w2, ax2); ay2 = fmaf(f2.y, w2, ay2);
            ax3 = fmaf(f3.x, w3, ax3); ay3 = fmaf(f3.y, w3, ay3);
        }
        for (; k < cnt; k++) {
            int   r0 = __shfl(idx, k, 16);
            float w0 = __shfl(wv, k, 16);
            unsigned u0 = reinterpret_cast<const unsigned*>(hw + (size_t)r0 * 32)[fp];
            float2 f0 = h2f2_(u0);
            ax0 = fmaf(f0.x, w0, ax0); ay0 = fmaf(f0.y, w0, ay0);
        }
    }

    if (alive) {
        float ax = (ax0 + ax1) + (ax2 + ax3);
        float ay = (ay0 + ay1) + (ay2 + ay3);
        float dc = dinv[node];
        unsigned su = reinterpret_cast<const unsigned*>(hw + (size_t)node * 32)[fp];
        float2 sf = h2f2_(su);
        float2 bb = reinterpret_cast<const float2*>(b2)[fp];
        float vx = ax * dc + sf.x * dc * dc + bb.x;
        float vy = ay * dc + sf.y * dc * dc + bb.y;
        __half2 pk(__float2half(vx), __float2half(vy));
        reinterpret_cast<__half2*>(z + (size_t)node * 32)[fp] = pk;
    }
}

// ---------------------------------------------------------------------------
// out[e] = dot(z[src[e]], z[dst[e]]) over 32 features; z is FP16.
// ---------------------------------------------------------------------------
__global__ void k_dot(const __half* __restrict__ z, const int* __restrict__ src,
                      const int* __restrict__ dst, float* __restrict__ out, int EL)
{
    int e = blockIdx.x * 256 + threadIdx.x;
    if (e >= EL) return;
    const uint4* a = reinterpret_cast<const uint4*>(z + (size_t)src[e] * 32);
    const uint4* b = reinterpret_cast<const uint4*>(z + (size_t)dst[e] * 32);
    float s = 0.0f;
#pragma unroll
    for (int q = 0; q < 4; q++) {
        uint4 av = a[q], bv = b[q];
        s = fdot2_(av.x, bv.x, s);
        s = fdot2_(av.y, bv.y, s);
        s = fdot2_(av.z, bv.z, s);
        s = fdot2_(av.w, bv.w, s);
    }
    out[e] = s;
}

extern "C" void kernel_launch(void* const* d_in, const int* in_sizes, int n_in,
                              void* d_out, int out_size, void* d_ws, size_t ws_size,
                              hipStream_t stream)
{
    const float* x   = (const float*)d_in[0];
    const int*   ei  = (const int*)d_in[1];
    const int*   eli = (const int*)d_in[2];
    const float* Wih = (const float*)d_in[3];
    // d_in[4] = W_hh: mathematically dead (h0 = c0 = 0)
    const float* bih = (const float*)d_in[5];
    const float* bhh = (const float*)d_in[6];
    const float* W1  = (const float*)d_in[7];
    const float* b1  = (const float*)d_in[8];
    const float* W2  = (const float*)d_in[9];
    const float* b2  = (const float*)d_in[10];

    int n  = in_sizes[0] / 64;
    int E  = in_sizes[1] / 2;
    int EL = in_sizes[2] / 2;

    const int* row  = ei;          // source
    const int* col  = ei + E;      // destination
    const int* lsrc = eli;
    const int* ldst = eli + EL;
    float* out = (float*)d_out;

    // Workspace layout (4B units):
    //   regA [E*2]: ebuf int2[E] (binl..csr)
    //   p1 [n*32]: hw1 FP16 [n*64 halves] (binl..pull64mm), then z FP16
    //              [n*32 halves] (pull32..dot)  -- hw1 dead before z written
    //   p2 [n*16]: hw2 FP16 [n*32 halves] (pull64mm..pull32)
    //   dinv [n] | off [n+1] | nbr [E] | B1tab/B2tab/bsum/W2P | bdeg/boff/gcur
    float*    base  = (float*)d_ws;
    int2*     ebuf  = (int2*)base;
    float*    p1    = base + (size_t)E * 2;
    __half*   hw1h  = (__half*)p1;
    __half*   zh    = (__half*)p1;            // hw1 dead by pull32
    float*    p2    = p1 + (size_t)n * 32;
    __half*   hw2h  = (__half*)p2;
    float*    dinv  = p2 + (size_t)n * 16;
    int*      off   = (int*)(dinv + n);
    int*      nbr   = off + (n + 1);
    uintptr_t pal   = ((uintptr_t)(nbr + E) + 15) & ~(uintptr_t)15;
    uint4*    B1tab = (uint4*)pal;
    uint4*    B2tab = B1tab + 1536;
    float*    bsum  = (float*)(B2tab + 512);
    unsigned* W2P   = (unsigned*)(bsum + 192);
    int*      bdeg  = (int*)(W2P + 1024);
    int*      boff  = bdeg + 256;
    int*      gcur  = boff + 257;

    int nbuck   = (n + (1 << NBSH) - 1) >> NBSH;   // 196 buckets (<=256)
    int eblocks = (E + CH - 1) / CH;               // 391
    int lblocks = (n + 63) / 64;                   // lstm: 16 nodes/wave
    dim3 blk(256);

    // --- prep: tables+bias+W2pack (blocks 0-12) || bucket histogram (rest) ---
    hipMemsetAsync(bdeg, 0, 256 * sizeof(int), stream);
    k_trh<<<dim3(13 + eblocks), blk, 0, stream>>>(
        Wih, W1, W2, bih, bhh, B1tab, B2tab, bsum, W2P, col, bdeg, E, nbuck);
    k_bscan<<<dim3(1), blk, 0, stream>>>(bdeg, boff, gcur, nbuck, E);

    // --- FUSED: bin partition || LSTM+mm1 (independent pipes+memory) ---
    k_binl<<<dim3(eblocks + lblocks), blk, 0, stream>>>(
        row, col, gcur, ebuf, E, nbuck, eblocks,
        x, B1tab, B2tab, bsum, hw1h, n);

    // --- per-bucket CSR finalize ---
    k_csr<<<dim3(nbuck), dim3(512), 0, stream>>>(ebuf, boff, off, dinv, nbr, n, nbuck, E);

    // --- GCN1 pull + relu + FUSED mm2: hw2 (fp16) -> p2 ---
    {
        int blocks = (n + 15) / 16;    // 4 nodes/wave
        k_pull64mm<<<dim3(blocks), blk, 0, stream>>>(
            hw1h, off, nbr, dinv, b1, W2P, hw2h, n);
    }

    // --- GCN2: pull + fused epilogue : z (fp16) -> p1 (hw1 dead) ---
    {
        int blocks = (n + 15) / 16;    // 4 nodes/wave
        k_pull32<<<dim3(blocks), blk, 0, stream>>>(hw2h, off, nbr, dinv, b2, zh, n);
    }

    // --- edge dot products ---
    k_dot<<<dim3((EL + 255) / 256), blk, 0, stream>>>(zh, lsrc, ldst, out, EL);
}